// Round 17
// baseline (338.615 us; speedup 1.0000x reference)
//
#include <hip/hip_runtime.h>
#include <math.h>

#define C 256
#define DH 32
#define NH 8
#define NL 4
#define NP 4
#define BQ 4
#define LQ 900
#define LVTOT 17821
#define DFFN 2048
#define NTOK (BQ*LQ)          // 3600 token rows, token index t = lq*B + b

typedef __attribute__((ext_vector_type(8))) short bf8_t;    // 8 bf16 (4 VGPRs)
typedef __attribute__((ext_vector_type(4))) float f4_t;     // MFMA acc
typedef __attribute__((ext_vector_type(8))) unsigned short us8_t;
typedef __attribute__((ext_vector_type(4))) unsigned short us4_t;

union U8 { us8_t v; unsigned int u[4]; };
union U4 { us4_t v; unsigned int u[2]; };

// ---------------- helpers ----------------
__device__ __forceinline__ unsigned short f2bf(float f) {
    unsigned int u = __float_as_uint(f);
    u += 0x7fffu + ((u >> 16) & 1u);   // round-to-nearest-even
    return (unsigned short)(u >> 16);
}
__device__ __forceinline__ float b2f(unsigned short u) {
    return __uint_as_float(((unsigned int)u) << 16);
}
// packed fp32x2 -> bf16x2 (RNE), 1 instruction
__device__ __forceinline__ unsigned int cvtpk(float lo, float hi) {
    unsigned int r;
    asm("v_cvt_pk_bf16_f32 %0, %1, %2" : "=v"(r) : "v"(lo), "v"(hi));
    return r;
}

// ---------------- one-time conversions: weights fp32->bf16, tgt fp32->bf16 ----------------
#define WOFF_OFFAW   0         // off_w 65536 | aw_w 32768  (fused 384x256)
#define WOFF_VPROJ   98304
#define WOFF_OPROJ   163840
#define WOFF_SAIN    229376
#define WOFF_SAOUT   425984
#define WOFF_L1      491520
#define WOFF_L2      1015808
#define WOFF_SA3IN   1540096
#define WOFF_SA3OUT  1736704
#define WOFF_L31     1802240
#define WOFF_L32     2326528
#define WTOT         2850816
#define PTOT         (WTOT + 921600)   // + tgt

__global__ void k_prep(const float* __restrict__ off_w, const float* __restrict__ aw_w,
                       const float* __restrict__ vproj_w, const float* __restrict__ oproj_w,
                       const float* __restrict__ sa_in_w, const float* __restrict__ sa_out_w,
                       const float* __restrict__ l1_w, const float* __restrict__ l2_w,
                       const float* __restrict__ sa3_in_w, const float* __restrict__ sa3_out_w,
                       const float* __restrict__ l31_w, const float* __restrict__ l32_w,
                       const float* __restrict__ off_b, const float* __restrict__ aw_b,
                       const float* __restrict__ tgt,
                       unsigned short* __restrict__ Wbf, float* __restrict__ bias384,
                       unsigned short* __restrict__ tgtU) {
    int i = blockIdx.x * 256 + threadIdx.x;
    if (i < 384) bias384[i] = (i < 256) ? off_b[i] : aw_b[i - 256];
    if (i >= PTOT) return;
    if (i >= WTOT) { int j = i - WTOT; tgtU[j] = f2bf(tgt[j]); return; }
    const float* src; int rel;
    if      (i < WOFF_VPROJ)  { if (i < 65536) { src = off_w; rel = i; } else { src = aw_w; rel = i - 65536; } }
    else if (i < WOFF_OPROJ)  { src = vproj_w;  rel = i - WOFF_VPROJ; }
    else if (i < WOFF_SAIN)   { src = oproj_w;  rel = i - WOFF_OPROJ; }
    else if (i < WOFF_SAOUT)  { src = sa_in_w;  rel = i - WOFF_SAIN; }
    else if (i < WOFF_L1)     { src = sa_out_w; rel = i - WOFF_SAOUT; }
    else if (i < WOFF_L2)     { src = l1_w;     rel = i - WOFF_L1; }
    else if (i < WOFF_SA3IN)  { src = l2_w;     rel = i - WOFF_L2; }
    else if (i < WOFF_SA3OUT) { src = sa3_in_w; rel = i - WOFF_SA3IN; }
    else if (i < WOFF_L31)    { src = sa3_out_w; rel = i - WOFF_SA3OUT; }
    else if (i < WOFF_L32)    { src = l31_w;    rel = i - WOFF_L31; }
    else                      { src = l32_w;    rel = i - WOFF_L32; }
    Wbf[i] = f2bf(src[rel]);
}

// ---------------- bf16 MFMA GEMM: Y = act(A @ W^T + b) ----------------
// A: [nrows][KS] fp32 (AB=0) or bf16 (AB=1); W: bf16. Output f32/bf16 per OB.
// Tile 128x64, 4 waves 2x2, K-step 32, double-buffered LDS, ONE barrier per
// 32-K phase, PREFETCH DEPTH 4 (named sets A..D, 128-K loop): issue->consume
// spans ~4 compute phases ~ HBM latency. STORE_X(buf) is separated from every
// wave's last COMPUTE(buf) by >=1 barrier (phase parity).
// XCDG=4: blk=32G+8cb+x -> rb=8G+x (4 col-tiles of a row-slab share an XCD).
// SPLITK=1: both K-halves of FFN2 in ONE dispatch (half 1 -> Y2, no bias).
enum { MODE_NORMAL = 0, MODE_RELU = 1, MODE_VALUE = 2, MODE_QKV = 3 };

#define LDP 40   // 80B row stride: frag reads 2-way (free), 16B-aligned

template<int K, int KS, int NTOT, int MODE, int AB, int OB, int XCDG, int SPLITK>
__global__ void k_mgemm(const void* __restrict__ A_, const unsigned short* __restrict__ Wbf,
                        const float* __restrict__ bias, void* __restrict__ Y_,
                        void* __restrict__ Y2_, int nrows) {
    __shared__ unsigned short Ash[2][128 * LDP];
    __shared__ unsigned short Bsh[2][64 * LDP];
    int t = threadIdx.x;
    int lane = t & 63, w = t >> 6;
    int wm = w & 1, wn = w >> 1;
    int rbx, cbx, khoff = 0;
    if (SPLITK) {
        int blk = blockIdx.x;
        rbx = (blk >> 6) * 8 + (blk & 7);
        cbx = (blk >> 3) & 3;
        int half = (blk >> 5) & 1;
        khoff = half * K;             // K = 1024, KS = 2048
        if (half) { Y_ = Y2_; bias = nullptr; }
        if (rbx * 128 >= nrows) return;
    } else if (XCDG) {
        int blk = blockIdx.x;
        rbx = (blk >> 5) * 8 + (blk & 7);
        cbx = (blk >> 3) & 3;
        if (rbx * 128 >= nrows) return;
    } else {
        rbx = blockIdx.x;
        cbx = blockIdx.y;
    }
    int r0 = rbx * 128;
    int c0 = cbx * 64;

    f4_t acc[4][2];
#pragma unroll
    for (int mt = 0; mt < 4; ++mt)
#pragma unroll
        for (int nt = 0; nt < 2; ++nt) acc[mt][nt] = (f4_t)0.f;

    int arow = t >> 1;
    int akoff = (t & 1) * 16;
    int asrc = min(r0 + arow, nrows - 1);
    const float* aptrf = (const float*)A_ + (size_t)asrc * KS + akoff + khoff;
    const unsigned short* aptrh = (const unsigned short*)A_ + (size_t)asrc * KS + akoff + khoff;
    unsigned short* adst0 = &Ash[0][arow * LDP + akoff];
    unsigned short* adst1 = &Ash[1][arow * LDP + akoff];

    int brow = t >> 2;
    int bkoff = (t & 3) * 8;
    const unsigned short* bptr = Wbf + (size_t)(c0 + brow) * KS + bkoff + khoff;
    unsigned short* bdst0 = &Bsh[0][brow * LDP + bkoff];
    unsigned short* bdst1 = &Bsh[1][brow * LDP + bkoff];

    int lr = lane & 15, kg = lane >> 4;

    // four named prefetch sets (depth 4); underscore names avoid pp-number pasting
    float4 fA_0, fA_1, fA_2, fA_3, fB_0, fB_1, fB_2, fB_3;
    float4 fC_0, fC_1, fC_2, fC_3, fD_0, fD_1, fD_2, fD_3;
    us8_t hA_0, hA_1, hB_0, hB_1, hC_0, hC_1, hD_0, hD_1;
    us8_t wA, wB, wC, wD;

#define ISSUE(S, k0) do { \
        if (AB) { h##S##_0 = *(const us8_t*)(aptrh + (k0)); h##S##_1 = *(const us8_t*)(aptrh + (k0) + 8); } \
        else { f##S##_0 = *(const float4*)(aptrf + (k0)); f##S##_1 = *(const float4*)(aptrf + (k0) + 4); \
               f##S##_2 = *(const float4*)(aptrf + (k0) + 8); f##S##_3 = *(const float4*)(aptrf + (k0) + 12); } \
        w##S = *(const us8_t*)(bptr + (k0)); } while (0)
#define STORE(S, buf) do { \
        if (AB) { *(us8_t*)(adst##buf) = h##S##_0; *(us8_t*)(adst##buf + 8) = h##S##_1; } \
        else { U8 x, y; \
               x.u[0] = cvtpk(f##S##_0.x, f##S##_0.y); x.u[1] = cvtpk(f##S##_0.z, f##S##_0.w); \
               x.u[2] = cvtpk(f##S##_1.x, f##S##_1.y); x.u[3] = cvtpk(f##S##_1.z, f##S##_1.w); \
               y.u[0] = cvtpk(f##S##_2.x, f##S##_2.y); y.u[1] = cvtpk(f##S##_2.z, f##S##_2.w); \
               y.u[2] = cvtpk(f##S##_3.x, f##S##_3.y); y.u[3] = cvtpk(f##S##_3.z, f##S##_3.w); \
               *(us8_t*)(adst##buf) = x.v; *(us8_t*)(adst##buf + 8) = y.v; } \
        *(us8_t*)(bdst##buf) = w##S; } while (0)
#define COMPUTE(buf) do { \
        bf8_t afr[4], bfr[2]; \
        _Pragma("unroll") \
        for (int mt = 0; mt < 4; ++mt) \
            afr[mt] = *(const bf8_t*)&Ash[buf][(wm * 64 + mt * 16 + lr) * LDP + kg * 8]; \
        _Pragma("unroll") \
        for (int nt = 0; nt < 2; ++nt) \
            bfr[nt] = *(const bf8_t*)&Bsh[buf][(wn * 32 + nt * 16 + lr) * LDP + kg * 8]; \
        _Pragma("unroll") \
        for (int mt = 0; mt < 4; ++mt) \
            _Pragma("unroll") \
            for (int nt = 0; nt < 2; ++nt) \
                acc[mt][nt] = __builtin_amdgcn_mfma_f32_16x16x32_bf16(afr[mt], bfr[nt], acc[mt][nt], 0, 0, 0); \
    } while (0)

    // K is a multiple of 128 for every instantiation (256, 1024)
    ISSUE(A, 0); ISSUE(B, 32); ISSUE(C, 64); ISSUE(D, 96);
#pragma unroll 1
    for (int k0 = 0; k0 < K; k0 += 128) {
        STORE(A, 0);
        __syncthreads();
        COMPUTE(0);
        if (k0 + 128 < K) ISSUE(A, k0 + 128);
        STORE(B, 1);
        __syncthreads();
        COMPUTE(1);
        if (k0 + 160 < K) ISSUE(B, k0 + 160);
        STORE(C, 0);
        __syncthreads();
        COMPUTE(0);
        if (k0 + 192 < K) ISSUE(C, k0 + 192);
        STORE(D, 1);
        __syncthreads();
        COMPUTE(1);
        if (k0 + 224 < K) ISSUE(D, k0 + 224);
    }
#undef ISSUE
#undef STORE
#undef COMPUTE

#pragma unroll
    for (int mt = 0; mt < 4; ++mt) {
#pragma unroll
        for (int nt = 0; nt < 2; ++nt) {
            int col = c0 + wn * 32 + nt * 16 + lr;
            float b0s = bias ? bias[col] : 0.f;
#pragma unroll
            for (int rr = 0; rr < 4; ++rr) {
                int row = r0 + wm * 64 + mt * 16 + kg * 4 + rr;
                if (row >= nrows) continue;
                float v = acc[mt][nt][rr] + b0s;
                size_t idx;
                if (MODE == MODE_NORMAL) {
                    idx = (size_t)row * NTOT + col;
                } else if (MODE == MODE_RELU) {
                    v = fmaxf(v, 0.f);
                    idx = (size_t)row * NTOT + col;
                } else if (MODE == MODE_VALUE) {
                    int lv = row >> 2, b = row & 3;
                    int h = col >> 5, d = col & 31;
                    idx = (((size_t)b * NH + h) * LVTOT + lv) * DH + d;
                } else { // MODE_QKV
                    int lq = row >> 2, b = row & 3;
                    int part = col >> 8, cc = col & 255;
                    int h = cc >> 5, d = cc & 31;
                    if (part == 0) v *= 0.17677669529663687f;  // 1/sqrt(32)
                    idx = (size_t)part * (BQ * NH * LQ * DH) + (((size_t)b * NH + h) * LQ + lq) * DH + d;
                }
                if (OB) ((unsigned short*)Y_)[idx] = f2bf(v);
                else    ((float*)Y_)[idx] = v;
            }
        }
    }
}

// ---------------- deformable sampling ----------------
__global__ void k_sample(const float* __restrict__ trp, const float* __restrict__ offaw,
                         const unsigned short* __restrict__ value,
                         unsigned short* __restrict__ accU) {
    int r = blockIdx.x;
    int b = r & 3;
    int t = threadIdx.x;
    int h = t >> 5;
    int lane32 = t & 31;
    int l = lane32 >> 3;               // level-group
    int dl = lane32 & 7;               // d-quad: d0 = dl*4
    int d0 = dl * 4;
    const unsigned short* vb = value + ((size_t)b * NH + h) * (size_t)LVTOT * DH;

    const float* lg = offaw + (size_t)r * 384 + 256 + h * 16;
    float e0,e1,e2,e3,e4,e5,e6,e7,e8,e9,e10,e11,e12,e13,e14,e15;
    {
        float4 q0 = *(const float4*)(lg);
        float4 q1 = *(const float4*)(lg + 4);
        float4 q2 = *(const float4*)(lg + 8);
        float4 q3 = *(const float4*)(lg + 12);
        float mx = fmaxf(fmaxf(fmaxf(q0.x,q0.y),fmaxf(q0.z,q0.w)),
                   fmaxf(fmaxf(fmaxf(q1.x,q1.y),fmaxf(q1.z,q1.w)),
                   fmaxf(fmaxf(fmaxf(q2.x,q2.y),fmaxf(q2.z,q2.w)),
                         fmaxf(fmaxf(q3.x,q3.y),fmaxf(q3.z,q3.w)))));
        e0=__expf(q0.x-mx); e1=__expf(q0.y-mx); e2=__expf(q0.z-mx); e3=__expf(q0.w-mx);
        e4=__expf(q1.x-mx); e5=__expf(q1.y-mx); e6=__expf(q1.z-mx); e7=__expf(q1.w-mx);
        e8=__expf(q2.x-mx); e9=__expf(q2.y-mx); e10=__expf(q2.z-mx); e11=__expf(q2.w-mx);
        e12=__expf(q3.x-mx); e13=__expf(q3.y-mx); e14=__expf(q3.z-mx); e15=__expf(q3.w-mx);
    }
    float ssum = ((e0+e1)+(e2+e3)) + ((e4+e5)+(e6+e7)) + ((e8+e9)+(e10+e11)) + ((e12+e13)+(e14+e15));
    float sinv = 1.0f / ssum;
    float w0 = (l==0) ? e0 : (l==1) ? e4 : (l==2) ? e8  : e12;
    float w1 = (l==0) ? e1 : (l==1) ? e5 : (l==2) ? e9  : e13;
    float w2 = (l==0) ? e2 : (l==1) ? e6 : (l==2) ? e10 : e14;
    float w3 = (l==0) ? e3 : (l==1) ? e7 : (l==2) ? e11 : e15;
    w0 *= sinv; w1 *= sinv; w2 *= sinv; w3 *= sinv;

    int Hl = (l==0) ? 100 : (l==1) ? 50 : (l==2) ? 25 : 13;
    int Wl = (l==0) ? 134 : (l==1) ? 67 : (l==2) ? 34 : 17;
    int s  = (l==0) ? 0 : (l==1) ? 13400 : (l==2) ? 16750 : 17600;
    float fW = (float)Wl, fH = (float)Hl;

    float rx = trp[((size_t)r * NL + l) * 2 + 0];
    float ry = trp[((size_t)r * NL + l) * 2 + 1];
    const float* offr = offaw + (size_t)r * 384 + h * 32 + l * 8;

    float o0 = 0.f, o1 = 0.f, o2 = 0.f, o3 = 0.f;
#pragma unroll
    for (int p = 0; p < 4; ++p) {
        float ox = offr[p * 2 + 0];
        float oy = offr[p * 2 + 1];
        float wq = (p==0) ? w0 : (p==1) ? w1 : (p==2) ? w2 : w3;
        float x = (rx + ox / fW) * fW - 0.5f;
        float y = (ry + oy / fH) * fH - 0.5f;
        float x0 = floorf(x), y0 = floorf(y);
#pragma unroll
        for (int dy = 0; dy < 2; ++dy) {
#pragma unroll
            for (int dx = 0; dx < 2; ++dx) {
                float xi = x0 + dx, yi = y0 + dy;
                float wgt = (1.0f - fabsf(x - xi)) * (1.0f - fabsf(y - yi));
                bool valid = (xi >= 0.f) && (xi < fW) && (yi >= 0.f) && (yi < fH);
                int xic = min(max((int)xi, 0), Wl - 1);
                int yic = min(max((int)yi, 0), Hl - 1);
                float cw = (valid ? wgt : 0.f) * wq;
                us4_t v4 = *(const us4_t*)&vb[((size_t)(s + yic * Wl + xic)) * DH + d0];
                o0 += cw * b2f(v4[0]);
                o1 += cw * b2f(v4[1]);
                o2 += cw * b2f(v4[2]);
                o3 += cw * b2f(v4[3]);
            }
        }
    }
    o0 += __shfl_xor(o0, 8, 32); o0 += __shfl_xor(o0, 16, 32);
    o1 += __shfl_xor(o1, 8, 32); o1 += __shfl_xor(o1, 16, 32);
    o2 += __shfl_xor(o2, 8, 32); o2 += __shfl_xor(o2, 16, 32);
    o3 += __shfl_xor(o3, 8, 32); o3 += __shfl_xor(o3, 16, 32);
    if (l == 0) {
        U4 u;
        u.u[0] = cvtpk(o0, o1);
        u.u[1] = cvtpk(o2, o3);
        *(us4_t*)&accU[(size_t)r * C + h * 32 + d0] = u.v;
    }
}

// ---------------- residual + LN: wave-per-row; dual f32 + bf16 output ----------------
__global__ void k_res_ln(const float* __restrict__ Y0, const float* __restrict__ Y1,
                         const float* __restrict__ Xres, const float* __restrict__ g,
                         const float* __restrict__ be, float* __restrict__ out,
                         unsigned short* __restrict__ outU) {
    int t = threadIdx.x, wv = t >> 6, lane = t & 63;
    int r = blockIdx.x * 4 + wv;
    float4 v = ((const float4*)(Y0 + (size_t)r * C))[lane];
    float4 x = ((const float4*)(Xres + (size_t)r * C))[lane];
    v.x += x.x; v.y += x.y; v.z += x.z; v.w += x.w;
    if (Y1) {
        float4 y1 = ((const float4*)(Y1 + (size_t)r * C))[lane];
        v.x += y1.x; v.y += y1.y; v.z += y1.z; v.w += y1.w;
    }
    float s = (v.x + v.y) + (v.z + v.w);
#pragma unroll
    for (int o = 32; o > 0; o >>= 1) s += __shfl_xor(s, o, 64);
    float mean = s * (1.0f / C);
    float4 dv = make_float4(v.x - mean, v.y - mean, v.z - mean, v.w - mean);
    float q = (dv.x * dv.x + dv.y * dv.y) + (dv.z * dv.z + dv.w * dv.w);
#pragma unroll
    for (int o = 32; o > 0; o >>= 1) q += __shfl_xor(q, o, 64);
    float rstd = rsqrtf(q * (1.0f / C) + 1e-5f);
    float4 g4 = ((const float4*)g)[lane];
    float4 b4 = ((const float4*)be)[lane];
    float4 o4 = make_float4(dv.x * rstd * g4.x + b4.x, dv.y * rstd * g4.y + b4.y,
                            dv.z * rstd * g4.z + b4.z, dv.w * rstd * g4.w + b4.w);
    ((float4*)(out + (size_t)r * C))[lane] = o4;
    if (outU) {
        U4 u;
        u.u[0] = cvtpk(o4.x, o4.y);
        u.u[1] = cvtpk(o4.z, o4.w);
        *(us4_t*)(outU + (size_t)r * C + lane * 4) = u.v;
    }
}

// ---------------- MFMA flash attention (bf16 Q/K/V/O) ----------------
#define NQC3 15   // ceil(900/64)

__global__ __launch_bounds__(256, 1)
void k_attn3(const unsigned short* __restrict__ Q, const unsigned short* __restrict__ K,
             const unsigned short* __restrict__ V, unsigned short* __restrict__ O) {
    __shared__ unsigned short sK[4][64 * 72];   // K rows [key][d]
    __shared__ unsigned short sV[4][32 * 72];   // V^T [d][key]
    __shared__ float sPO[4][64 * 36];           // P bf16 [64q][72k] overlaid, then Obuf f32 [64q][36d]
    __shared__ float sWm[4][64], sWl[4][64];

    int blk = blockIdx.x;
    int bh = blk & 31;                 // XCD locality
    int qc = blk >> 5;
    int b = bh >> 3, h = bh & 7;
    int t = threadIdx.x;
    int w = t >> 6, lane = t & 63;
    int lr = lane & 15, g = lane >> 4;

    const unsigned short* Qb = Q + (size_t)bh * LQ * DH;
    const unsigned short* Kb = K + (size_t)bh * LQ * DH;
    const unsigned short* Vb = V + (size_t)bh * LQ * DH;

    unsigned short* Ks = sK[w];
    unsigned short* Vt = sV[w];
    unsigned short* Ps = (unsigned short*)sPO[w];

    bf8_t qf[4];
#pragma unroll
    for (int nt = 0; nt < 4; ++nt) {
        int qg = min(qc * 64 + nt * 16 + lr, LQ - 1);
        qf[nt] = *(const bf8_t*)(Qb + (size_t)qg * DH + g * 8);
    }

    float m[4], l[4];
    f4_t acc[2][4];
#pragma unroll
    for (int nt = 0; nt < 4; ++nt) {
        m[nt] = -3e38f; l[nt] = 0.f;
        acc[0][nt] = (f4_t)0.f; acc[1][nt] = (f4_t)0.f;
    }

    for (int ci = 0; ci < 4; ++ci) {
        int k0 = ci * 256 + w * 64;
        if (k0 >= LQ) break;
        int kgl = min(k0 + lane, LQ - 1);
        const unsigned short* kr = Kb + (size_t)kgl * DH;
        const unsigned short* vr = Vb + (size_t)kgl * DH;
#pragma unroll
        for (int i = 0; i < 4; ++i)
            *(us8_t*)&Ks[lane * 72 + i * 8] = *(const us8_t*)(kr + i * 8);
#pragma unroll
        for (int i = 0; i < 4; ++i) {
            us8_t v8 = *(const us8_t*)(vr + i * 8);
#pragma unroll
            for (int j = 0; j < 8; ++j)
                Vt[(i * 8 + j) * 72 + lane] = v8[j];
        }
        // ---- QK^T: S^T[64k][64q] ----
        bf8_t ka[4];
#pragma unroll
        for (int mt = 0; mt < 4; ++mt)
            ka[mt] = *(const bf8_t*)&Ks[(mt * 16 + lr) * 72 + g * 8];
        f4_t st[4][4];
#pragma unroll
        for (int mt = 0; mt < 4; ++mt)
#pragma unroll
            for (int nt = 0; nt < 4; ++nt)
                st[mt][nt] = __builtin_amdgcn_mfma_f32_16x16x32_bf16(ka[mt], qf[nt], (f4_t)0.f, 0, 0, 0);
        // ---- online softmax + P write ----
#pragma unroll
        for (int nt = 0; nt < 4; ++nt) {
            float sv[4][4];
            float cm = -3e38f;
#pragma unroll
            for (int mt = 0; mt < 4; ++mt)
#pragma unroll
                for (int rr = 0; rr < 4; ++rr) {
                    bool valid = (k0 + mt * 16 + g * 4 + rr) < LQ;
                    float s = valid ? st[mt][nt][rr] : -3e38f;
                    sv[mt][rr] = s;
                    cm = fmaxf(cm, s);
                }
            cm = fmaxf(cm, __shfl_xor(cm, 16, 64));
            cm = fmaxf(cm, __shfl_xor(cm, 32, 64));
            float mn = fmaxf(m[nt], cm);
            float sc = __expf(m[nt] - mn);
            float cs = 0.f;
#pragma unroll
            for (int mt = 0; mt < 4; ++mt) {
                float pv0 = (sv[mt][0] > -1e37f) ? __expf(sv[mt][0] - mn) : 0.f;
                float pv1 = (sv[mt][1] > -1e37f) ? __expf(sv[mt][1] - mn) : 0.f;
                float pv2 = (sv[mt][2] > -1e37f) ? __expf(sv[mt][2] - mn) : 0.f;
                float pv3 = (sv[mt][3] > -1e37f) ? __expf(sv[mt][3] - mn) : 0.f;
                cs += (pv0 + pv1) + (pv2 + pv3);
                U4 pk;
                pk.u[0] = cvtpk(pv0, pv1);
                pk.u[1] = cvtpk(pv2, pv3);
                *(us4_t*)&Ps[(nt * 16 + lr) * 72 + mt * 16 + g * 4] = pk.v;
            }
            cs += __shfl_xor(cs, 16, 64);
            cs += __shfl_xor(cs, 32, 64);
            l[nt] = l[nt] * sc + cs;
            m[nt] = mn;
            acc[0][nt] *= sc;
            acc[1][nt] *= sc;
        }
        // ---- PV: O^T[32d][64q] ----
        bf8_t va[2][2];
#pragma unroll
        for (int md = 0; md < 2; ++md)
#pragma unroll
            for (int kt = 0; kt < 2; ++kt)
                va[md][kt] = *(const bf8_t*)&Vt[(md * 16 + lr) * 72 + kt * 32 + g * 8];
#pragma unroll
        for (int nt = 0; nt < 4; ++nt)
#pragma unroll
            for (int kt = 0; kt < 2; ++kt) {
                bf8_t pb = *(const bf8_t*)&Ps[(nt * 16 + lr) * 72 + kt * 32 + g * 8];
                acc[0][nt] = __builtin_amdgcn_mfma_f32_16x16x32_bf16(va[0][kt], pb, acc[0][nt], 0, 0, 0);
                acc[1][nt] = __builtin_amdgcn_mfma_f32_16x16x32_bf16(va[1][kt], pb, acc[1][nt], 0, 0, 0);
            }
    }

    // ---- wave combine ----
    if (g == 0) {
#pragma unroll
        for (int nt = 0; nt < 4; ++nt) {
            sWm[w][nt * 16 + lr] = m[nt];
            sWl[w][nt * 16 + lr] = l[nt];
        }
    }
    __syncthreads();
    float* ob = sPO[w];
#pragma unroll
    for (int nt = 0; nt < 4; ++nt) {
        int q = nt * 16 + lr;
        float M = fmaxf(fmaxf(sWm[0][q], sWm[1][q]), fmaxf(sWm[2][q], sWm[3][q]));
        float fac = __expf(m[nt] - M);
        f4_t v0 = acc[0][nt] * fac;
        f4_t v1 = acc[1][nt] * fac;
        *(f4_t*)&ob[q * 36 + g * 4] = v0;
        *(f4_t*)&ob[q * 36 + 16 + g * 4] = v1;
    }
    __syncthreads();
    {
        int q = t >> 2, d0 = (t & 3) * 8;
        int qglob = qc * 64 + q;
        if (qglob < LQ) {
            float M = fmaxf(fmaxf(sWm[0][q], sWm[1][q]), fmaxf(sWm[2][q], sWm[3][q]));
            float L = 0.f;
#pragma unroll
            for (int w2 = 0; w2 < 4; ++w2) L += sWl[w2][q] * __expf(sWm[w2][q] - M);
            float inv = 1.0f / L;
            f4_t r0 = (f4_t)0.f, r1 = (f4_t)0.f;
#pragma unroll
            for (int w2 = 0; w2 < 4; ++w2) {
                r0 += *(f4_t*)&sPO[w2][q * 36 + d0];
                r1 += *(f4_t*)&sPO[w2][q * 36 + d0 + 4];
            }
            r0 *= inv; r1 *= inv;
            U8 u;
            u.u[0] = cvtpk(r0[0], r0[1]);
            u.u[1] = cvtpk(r0[2], r0[3]);
            u.u[2] = cvtpk(r1[0], r1[1]);
            u.u[3] = cvtpk(r1[2], r1[3]);
            *(us8_t*)(O + ((size_t)(qglob * BQ + b)) * C + h * 32 + d0) = u.v;
        }
    }
}

// ---------------- launch ----------------
extern "C" void kernel_launch(void* const* d_in, const int* in_sizes, int n_in,
                              void* d_out, int out_size, void* d_ws, size_t ws_size,
                              hipStream_t stream) {
    const float* tgt      = (const float*)d_in[0];
    const float* trp      = (const float*)d_in[1];
    const float* memory   = (const float*)d_in[2];
    const float* vproj_w  = (const float*)d_in[5];  const float* vproj_b  = (const float*)d_in[6];
    const float* off_w    = (const float*)d_in[7];  const float* off_b    = (const float*)d_in[8];
    const float* aw_w     = (const float*)d_in[9];  const float* aw_b     = (const float*)d_in[10];
    const float* oproj_w  = (const float*)d_in[11]; const float* oproj_b  = (const float*)d_in[12];
    const float* ln1_g    = (const float*)d_in[13]; const float* ln1_b    = (const float*)d_in[14];
    const float* sa_in_w  = (const float*)d_in[15]; const float* sa_in_b  = (const float*)d_in[16];
    const float* sa_out_w = (const float*)d_in[17]; const float* sa_out_b = (const float*)d_in[18];
    const float* ln2_g    = (const float*)d_in[19]; const float* ln2_b    = (const float*)d_in[20];
    const float* l1_w     = (const float*)d_in[21]; const float* l1_b     = (const float*)d_in[22];
    const float* l2_w     = (const float*)d_in[23]; const float* l2_b     = (const float*)d_in[24];
    const float* ln3_g    = (const float*)d_in[25]; const float* ln3_b    = (const float*)d_in[26];
    const float* sa3_in_w = (const float*)d_in[27]; const float* sa3_in_b = (const float*)d_in[28];
    const float* sa3_out_w= (const float*)d_in[29]; const float* sa3_out_b= (const float*)d_in[30];
    const float* ln5_g    = (const float*)d_in[31]; const float* ln5_b    = (const float*)d_in[32];
    const float* l31_w    = (const float*)d_in[33]; const float* l31_b    = (const float*)d_in[34];
    const float* l32_w    = (const float*)d_in[35]; const float* l32_b    = (const float*)d_in[36];
    const float* ln33_g   = (const float*)d_in[37]; const float* ln33_b   = (const float*)d_in[38];

    float* ws = (float*)d_ws;
    float* X              = ws;                                    // 921,600 f32
    unsigned short* valueU= (unsigned short*)(ws + 921600);        // 18,248,704 bf16
    float* offaw          = ws + 10045952;                         // 1,382,400 f32 [3600][384]
    unsigned short* accU  = (unsigned short*)(ws + 11428352);      // 921,600 bf16
    unsigned short* QKVu  = (unsigned short*)(ws + 12349952);      // 2,764,800 bf16
    unsigned short* Ou    = (unsigned short*)(ws + 13732352);      // 921,600 bf16
    unsigned short* H1u   = (unsigned short*)(ws + 14193152);      // 7,372,800 bf16
    float* Y              = ws + 17879552;                         // 921,600 f32
    float* Y2             = ws + 18801152;                         // 921,600 f32
    float* T1             = ws + 19722752;                         // 921,600 f32
    unsigned short* Wbf   = (unsigned short*)(ws + 20644352);      // 2,850,816 bf16
    float* bias384        = ws + 22069760;                         // 384 f32
    unsigned short* XU    = (unsigned short*)(ws + 22070144);      // 921,600 bf16
    unsigned short* tgtU  = (unsigned short*)(ws + 22530944);      // 921,600 bf16

    const int NVROWS = BQ * LVTOT;           // 71,284 -> 558 row-blocks -> 70 supergroups
    dim3 blk(256);
    dim3 gTok(29, 4);
    void* nullv = nullptr;

    // ---- pre-conversions (weights + tgt) ----
    k_prep<<<(PTOT + 255) / 256, blk, 0, stream>>>(off_w, aw_w, vproj_w, oproj_w, sa_in_w, sa_out_w,
                                                   l1_w, l2_w, sa3_in_w, sa3_out_w, l31_w, l32_w,
                                                   off_b, aw_b, tgt, Wbf, bias384, tgtU);

    // ---- ca: MSDeformAttn ----
    k_mgemm<256, 256, 256, MODE_VALUE, 0, 1, 4, 0><<<70 * 32, blk, 0, stream>>>(memory, Wbf + WOFF_VPROJ, vproj_b, valueU, nullv, NVROWS);
    k_mgemm<256, 256, 384, MODE_NORMAL, 1, 0, 0, 0><<<dim3(29, 6), blk, 0, stream>>>(tgtU, Wbf + WOFF_OFFAW, bias384, offaw, nullv, NTOK);
    k_sample<<<NTOK, blk, 0, stream>>>(trp, offaw, valueU, accU);
    k_mgemm<256, 256, 256, MODE_NORMAL, 1, 0, 0, 0><<<gTok, blk, 0, stream>>>(accU, Wbf + WOFF_OPROJ, oproj_b, T1, nullv, NTOK);
    k_res_ln<<<NTOK / 4, blk, 0, stream>>>(T1, nullptr, tgt, ln1_g, ln1_b, X, XU);

    // ---- sa ----
    k_mgemm<256, 256, 768, MODE_QKV, 1, 1, 0, 0><<<dim3(29, 12), blk, 0, stream>>>(XU, Wbf + WOFF_SAIN, sa_in_b, QKVu, nullv, NTOK);
    k_attn3<<<32 * NQC3, blk, 0, stream>>>(QKVu, QKVu + 921600, QKVu + 1843200, Ou);
    k_mgemm<256, 256, 256, MODE_NORMAL, 1, 0, 0, 0><<<gTok, blk, 0, stream>>>(Ou, Wbf + WOFF_SAOUT, sa_out_b, T1, nullv, NTOK);
    k_res_ln<<<NTOK / 4, blk, 0, stream>>>(T1, nullptr, X, ln2_g, ln2_b, X, XU);

    // ---- ffn ----
    k_mgemm<256, 256, 2048, MODE_RELU, 1, 1, 0, 0><<<dim3(29, 32), blk, 0, stream>>>(XU, Wbf + WOFF_L1, l1_b, H1u, nullv, NTOK);
    k_mgemm<1024, 2048, 256, MODE_NORMAL, 1, 0, 0, 1><<<4 * 64, blk, 0, stream>>>(H1u, Wbf + WOFF_L2, l2_b, Y, Y2, NTOK);
    k_res_ln<<<NTOK / 4, blk, 0, stream>>>(Y, Y2, X, ln3_g, ln3_b, X, XU);

    // ---- sa3 ----
    k_mgemm<256, 256, 768, MODE_QKV, 1, 1, 0, 0><<<dim3(29, 12), blk, 0, stream>>>(XU, Wbf + WOFF_SA3IN, sa3_in_b, QKVu, nullv, NTOK);
    k_attn3<<<32 * NQC3, blk, 0, stream>>>(QKVu, QKVu + 921600, QKVu + 1843200, Ou);
    k_mgemm<256, 256, 256, MODE_NORMAL, 1, 0, 0, 0><<<gTok, blk, 0, stream>>>(Ou, Wbf + WOFF_SA3OUT, sa3_out_b, T1, nullv, NTOK);
    k_res_ln<<<NTOK / 4, blk, 0, stream>>>(T1, nullptr, X, ln5_g, ln5_b, X, XU);

    // ---- ffn3 ----
    k_mgemm<256, 256, 2048, MODE_RELU, 1, 1, 0, 0><<<dim3(29, 32), blk, 0, stream>>>(XU, Wbf + WOFF_L31, l31_b, H1u, nullv, NTOK);
    k_mgemm<1024, 2048, 256, MODE_NORMAL, 1, 0, 0, 1><<<4 * 64, blk, 0, stream>>>(H1u, Wbf + WOFF_L32, l32_b, Y, Y2, NTOK);
    k_res_ln<<<NTOK / 4, blk, 0, stream>>>(Y, Y2, X, ln33_g, ln33_b, (float*)d_out, nullptr);
}

// Round 18
// 264.577 us; speedup vs baseline: 1.2798x; 1.2798x over previous
//
#include <hip/hip_runtime.h>
#include <math.h>

#define C 256
#define DH 32
#define NH 8
#define NL 4
#define NP 4
#define BQ 4
#define LQ 900
#define LVTOT 17821
#define DFFN 2048
#define NTOK (BQ*LQ)          // 3600 token rows, token index t = lq*B + b

typedef __attribute__((ext_vector_type(8))) short bf8_t;    // 8 bf16 (4 VGPRs)
typedef __attribute__((ext_vector_type(4))) float f4_t;     // MFMA acc
typedef __attribute__((ext_vector_type(8))) unsigned short us8_t;
typedef __attribute__((ext_vector_type(4))) unsigned short us4_t;

union U8 { us8_t v; unsigned int u[4]; };
union U4 { us4_t v; unsigned int u[2]; };

// ---------------- helpers ----------------
__device__ __forceinline__ unsigned short f2bf(float f) {
    unsigned int u = __float_as_uint(f);
    u += 0x7fffu + ((u >> 16) & 1u);   // round-to-nearest-even
    return (unsigned short)(u >> 16);
}
__device__ __forceinline__ float b2f(unsigned short u) {
    return __uint_as_float(((unsigned int)u) << 16);
}
// packed fp32x2 -> bf16x2 (RNE), 1 instruction
__device__ __forceinline__ unsigned int cvtpk(float lo, float hi) {
    unsigned int r;
    asm("v_cvt_pk_bf16_f32 %0, %1, %2" : "=v"(r) : "v"(lo), "v"(hi));
    return r;
}

// ---------------- one-time conversions: weights fp32->bf16, tgt fp32->bf16 ----------------
#define WOFF_OFFAW   0         // off_w 65536 | aw_w 32768  (fused 384x256)
#define WOFF_VPROJ   98304
#define WOFF_OPROJ   163840
#define WOFF_SAIN    229376
#define WOFF_SAOUT   425984
#define WOFF_L1      491520
#define WOFF_L2      1015808
#define WOFF_SA3IN   1540096
#define WOFF_SA3OUT  1736704
#define WOFF_L31     1802240
#define WOFF_L32     2326528
#define WTOT         2850816
#define PTOT         (WTOT + 921600)   // + tgt

__global__ void k_prep(const float* __restrict__ off_w, const float* __restrict__ aw_w,
                       const float* __restrict__ vproj_w, const float* __restrict__ oproj_w,
                       const float* __restrict__ sa_in_w, const float* __restrict__ sa_out_w,
                       const float* __restrict__ l1_w, const float* __restrict__ l2_w,
                       const float* __restrict__ sa3_in_w, const float* __restrict__ sa3_out_w,
                       const float* __restrict__ l31_w, const float* __restrict__ l32_w,
                       const float* __restrict__ off_b, const float* __restrict__ aw_b,
                       const float* __restrict__ tgt,
                       unsigned short* __restrict__ Wbf, float* __restrict__ bias384,
                       unsigned short* __restrict__ tgtU) {
    int i = blockIdx.x * 256 + threadIdx.x;
    if (i < 384) bias384[i] = (i < 256) ? off_b[i] : aw_b[i - 256];
    if (i >= PTOT) return;
    if (i >= WTOT) { int j = i - WTOT; tgtU[j] = f2bf(tgt[j]); return; }
    const float* src; int rel;
    if      (i < WOFF_VPROJ)  { if (i < 65536) { src = off_w; rel = i; } else { src = aw_w; rel = i - 65536; } }
    else if (i < WOFF_OPROJ)  { src = vproj_w;  rel = i - WOFF_VPROJ; }
    else if (i < WOFF_SAIN)   { src = oproj_w;  rel = i - WOFF_OPROJ; }
    else if (i < WOFF_SAOUT)  { src = sa_in_w;  rel = i - WOFF_SAIN; }
    else if (i < WOFF_L1)     { src = sa_out_w; rel = i - WOFF_SAOUT; }
    else if (i < WOFF_L2)     { src = l1_w;     rel = i - WOFF_L1; }
    else if (i < WOFF_SA3IN)  { src = l2_w;     rel = i - WOFF_L2; }
    else if (i < WOFF_SA3OUT) { src = sa3_in_w; rel = i - WOFF_SA3IN; }
    else if (i < WOFF_L31)    { src = sa3_out_w; rel = i - WOFF_SA3OUT; }
    else if (i < WOFF_L32)    { src = l31_w;    rel = i - WOFF_L31; }
    else                      { src = l32_w;    rel = i - WOFF_L32; }
    Wbf[i] = f2bf(src[rel]);
}

// ---------------- bf16 MFMA GEMM: Y = act(A @ W^T + b) ----------------
// A: [nrows][KS] fp32 (AB=0) or bf16 (AB=1); W: bf16. Output f32/bf16 per OB.
// Tile 128x64, 4 waves 2x2, K-step 32, DOUBLE-buffered LDS, ONE barrier/step.
// Prefetch depth 2 (named sets; depth 4 spills to scratch: R17 WRITE 37->147MB).
// XCDG=4: blk=32G+8cb+x -> rb=8G+x (4 col-tiles of a row-slab share an XCD).
// SPLITK=1: both K-halves of FFN2 in ONE dispatch (half 1 -> Y2, no bias).
enum { MODE_NORMAL = 0, MODE_RELU = 1, MODE_VALUE = 2, MODE_QKV = 3 };

#define LDP 40   // 80B row stride: frag reads 2-way (free), 16B-aligned

template<int K, int KS, int NTOT, int MODE, int AB, int OB, int XCDG, int SPLITK>
__global__ void k_mgemm(const void* __restrict__ A_, const unsigned short* __restrict__ Wbf,
                        const float* __restrict__ bias, void* __restrict__ Y_,
                        void* __restrict__ Y2_, int nrows) {
    __shared__ unsigned short Ash[2][128 * LDP];
    __shared__ unsigned short Bsh[2][64 * LDP];
    int t = threadIdx.x;
    int lane = t & 63, w = t >> 6;
    int wm = w & 1, wn = w >> 1;
    int rbx, cbx, khoff = 0;
    if (SPLITK) {
        int blk = blockIdx.x;
        rbx = (blk >> 6) * 8 + (blk & 7);
        cbx = (blk >> 3) & 3;
        int half = (blk >> 5) & 1;
        khoff = half * K;             // K = 1024, KS = 2048
        if (half) { Y_ = Y2_; bias = nullptr; }
        if (rbx * 128 >= nrows) return;
    } else if (XCDG) {
        int blk = blockIdx.x;
        rbx = (blk >> 5) * 8 + (blk & 7);
        cbx = (blk >> 3) & 3;
        if (rbx * 128 >= nrows) return;
    } else {
        rbx = blockIdx.x;
        cbx = blockIdx.y;
    }
    int r0 = rbx * 128;
    int c0 = cbx * 64;

    f4_t acc[4][2];
#pragma unroll
    for (int mt = 0; mt < 4; ++mt)
#pragma unroll
        for (int nt = 0; nt < 2; ++nt) acc[mt][nt] = (f4_t)0.f;

    int arow = t >> 1;
    int akoff = (t & 1) * 16;
    int asrc = min(r0 + arow, nrows - 1);
    const float* aptrf = (const float*)A_ + (size_t)asrc * KS + akoff + khoff;
    const unsigned short* aptrh = (const unsigned short*)A_ + (size_t)asrc * KS + akoff + khoff;
    unsigned short* adst0 = &Ash[0][arow * LDP + akoff];
    unsigned short* adst1 = &Ash[1][arow * LDP + akoff];

    int brow = t >> 2;
    int bkoff = (t & 3) * 8;
    const unsigned short* bptr = Wbf + (size_t)(c0 + brow) * KS + bkoff + khoff;
    unsigned short* bdst0 = &Bsh[0][brow * LDP + bkoff];
    unsigned short* bdst1 = &Bsh[1][brow * LDP + bkoff];

    int lr = lane & 15, kg = lane >> 4;

    float4 fA_0, fA_1, fA_2, fA_3, gA_0, gA_1, gA_2, gA_3;  // fp32 A sets (AB=0)
    us8_t hA_0, hA_1, hB_0, hB_1;                            // bf16 A sets (AB=1)
    us8_t wA, wB;

#define ISSUE_A(k0) do { \
        if (AB) { hA_0 = *(const us8_t*)(aptrh + (k0)); hA_1 = *(const us8_t*)(aptrh + (k0) + 8); } \
        else { fA_0 = *(const float4*)(aptrf + (k0)); fA_1 = *(const float4*)(aptrf + (k0) + 4); \
               fA_2 = *(const float4*)(aptrf + (k0) + 8); fA_3 = *(const float4*)(aptrf + (k0) + 12); } \
        wA = *(const us8_t*)(bptr + (k0)); } while (0)
#define ISSUE_B(k0) do { \
        if (AB) { hB_0 = *(const us8_t*)(aptrh + (k0)); hB_1 = *(const us8_t*)(aptrh + (k0) + 8); } \
        else { gA_0 = *(const float4*)(aptrf + (k0)); gA_1 = *(const float4*)(aptrf + (k0) + 4); \
               gA_2 = *(const float4*)(aptrf + (k0) + 8); gA_3 = *(const float4*)(aptrf + (k0) + 12); } \
        wB = *(const us8_t*)(bptr + (k0)); } while (0)
#define STORE_A(buf) do { \
        if (AB) { *(us8_t*)(adst##buf) = hA_0; *(us8_t*)(adst##buf + 8) = hA_1; } \
        else { U8 x, y; \
               x.u[0] = cvtpk(fA_0.x, fA_0.y); x.u[1] = cvtpk(fA_0.z, fA_0.w); \
               x.u[2] = cvtpk(fA_1.x, fA_1.y); x.u[3] = cvtpk(fA_1.z, fA_1.w); \
               y.u[0] = cvtpk(fA_2.x, fA_2.y); y.u[1] = cvtpk(fA_2.z, fA_2.w); \
               y.u[2] = cvtpk(fA_3.x, fA_3.y); y.u[3] = cvtpk(fA_3.z, fA_3.w); \
               *(us8_t*)(adst##buf) = x.v; *(us8_t*)(adst##buf + 8) = y.v; } \
        *(us8_t*)(bdst##buf) = wA; } while (0)
#define STORE_B(buf) do { \
        if (AB) { *(us8_t*)(adst##buf) = hB_0; *(us8_t*)(adst##buf + 8) = hB_1; } \
        else { U8 x, y; \
               x.u[0] = cvtpk(gA_0.x, gA_0.y); x.u[1] = cvtpk(gA_0.z, gA_0.w); \
               x.u[2] = cvtpk(gA_1.x, gA_1.y); x.u[3] = cvtpk(gA_1.z, gA_1.w); \
               y.u[0] = cvtpk(gA_2.x, gA_2.y); y.u[1] = cvtpk(gA_2.z, gA_2.w); \
               y.u[2] = cvtpk(gA_3.x, gA_3.y); y.u[3] = cvtpk(gA_3.z, gA_3.w); \
               *(us8_t*)(adst##buf) = x.v; *(us8_t*)(adst##buf + 8) = y.v; } \
        *(us8_t*)(bdst##buf) = wB; } while (0)
#define COMPUTE(buf) do { \
        bf8_t afr[4], bfr[2]; \
        _Pragma("unroll") \
        for (int mt = 0; mt < 4; ++mt) \
            afr[mt] = *(const bf8_t*)&Ash[buf][(wm * 64 + mt * 16 + lr) * LDP + kg * 8]; \
        _Pragma("unroll") \
        for (int nt = 0; nt < 2; ++nt) \
            bfr[nt] = *(const bf8_t*)&Bsh[buf][(wn * 32 + nt * 16 + lr) * LDP + kg * 8]; \
        _Pragma("unroll") \
        for (int mt = 0; mt < 4; ++mt) \
            _Pragma("unroll") \
            for (int nt = 0; nt < 2; ++nt) \
                acc[mt][nt] = __builtin_amdgcn_mfma_f32_16x16x32_bf16(afr[mt], bfr[nt], acc[mt][nt], 0, 0, 0); \
    } while (0)

    ISSUE_A(0);
#pragma unroll 1
    for (int k0 = 0; k0 < K; k0 += 64) {
        STORE_A(0);
        ISSUE_B(k0 + 32);           // K multiple of 64 -> always valid
        __syncthreads();
        COMPUTE(0);
        STORE_B(1);
        if (k0 + 64 < K) ISSUE_A(k0 + 64);
        __syncthreads();
        COMPUTE(1);
    }
#undef ISSUE_A
#undef ISSUE_B
#undef STORE_A
#undef STORE_B
#undef COMPUTE

#pragma unroll
    for (int mt = 0; mt < 4; ++mt) {
#pragma unroll
        for (int nt = 0; nt < 2; ++nt) {
            int col = c0 + wn * 32 + nt * 16 + lr;
            float b0s = bias ? bias[col] : 0.f;
#pragma unroll
            for (int rr = 0; rr < 4; ++rr) {
                int row = r0 + wm * 64 + mt * 16 + kg * 4 + rr;
                if (row >= nrows) continue;
                float v = acc[mt][nt][rr] + b0s;
                size_t idx;
                if (MODE == MODE_NORMAL) {
                    idx = (size_t)row * NTOT + col;
                } else if (MODE == MODE_RELU) {
                    v = fmaxf(v, 0.f);
                    idx = (size_t)row * NTOT + col;
                } else if (MODE == MODE_VALUE) {
                    int lv = row >> 2, b = row & 3;
                    int h = col >> 5, d = col & 31;
                    idx = (((size_t)b * NH + h) * LVTOT + lv) * DH + d;
                } else { // MODE_QKV
                    int lq = row >> 2, b = row & 3;
                    int part = col >> 8, cc = col & 255;
                    int h = cc >> 5, d = cc & 31;
                    if (part == 0) v *= 0.17677669529663687f;  // 1/sqrt(32)
                    idx = (size_t)part * (BQ * NH * LQ * DH) + (((size_t)b * NH + h) * LQ + lq) * DH + d;
                }
                if (OB) ((unsigned short*)Y_)[idx] = f2bf(v);
                else    ((float*)Y_)[idx] = v;
            }
        }
    }
}

// ---------------- deformable sampling ----------------
__global__ void k_sample(const float* __restrict__ trp, const float* __restrict__ offaw,
                         const unsigned short* __restrict__ value,
                         unsigned short* __restrict__ accU) {
    int r = blockIdx.x;
    int b = r & 3;
    int t = threadIdx.x;
    int h = t >> 5;
    int lane32 = t & 31;
    int l = lane32 >> 3;               // level-group
    int dl = lane32 & 7;               // d-quad: d0 = dl*4
    int d0 = dl * 4;
    const unsigned short* vb = value + ((size_t)b * NH + h) * (size_t)LVTOT * DH;

    const float* lg = offaw + (size_t)r * 384 + 256 + h * 16;
    float e0,e1,e2,e3,e4,e5,e6,e7,e8,e9,e10,e11,e12,e13,e14,e15;
    {
        float4 q0 = *(const float4*)(lg);
        float4 q1 = *(const float4*)(lg + 4);
        float4 q2 = *(const float4*)(lg + 8);
        float4 q3 = *(const float4*)(lg + 12);
        float mx = fmaxf(fmaxf(fmaxf(q0.x,q0.y),fmaxf(q0.z,q0.w)),
                   fmaxf(fmaxf(fmaxf(q1.x,q1.y),fmaxf(q1.z,q1.w)),
                   fmaxf(fmaxf(fmaxf(q2.x,q2.y),fmaxf(q2.z,q2.w)),
                         fmaxf(fmaxf(q3.x,q3.y),fmaxf(q3.z,q3.w)))));
        e0=__expf(q0.x-mx); e1=__expf(q0.y-mx); e2=__expf(q0.z-mx); e3=__expf(q0.w-mx);
        e4=__expf(q1.x-mx); e5=__expf(q1.y-mx); e6=__expf(q1.z-mx); e7=__expf(q1.w-mx);
        e8=__expf(q2.x-mx); e9=__expf(q2.y-mx); e10=__expf(q2.z-mx); e11=__expf(q2.w-mx);
        e12=__expf(q3.x-mx); e13=__expf(q3.y-mx); e14=__expf(q3.z-mx); e15=__expf(q3.w-mx);
    }
    float ssum = ((e0+e1)+(e2+e3)) + ((e4+e5)+(e6+e7)) + ((e8+e9)+(e10+e11)) + ((e12+e13)+(e14+e15));
    float sinv = 1.0f / ssum;
    float w0 = (l==0) ? e0 : (l==1) ? e4 : (l==2) ? e8  : e12;
    float w1 = (l==0) ? e1 : (l==1) ? e5 : (l==2) ? e9  : e13;
    float w2 = (l==0) ? e2 : (l==1) ? e6 : (l==2) ? e10 : e14;
    float w3 = (l==0) ? e3 : (l==1) ? e7 : (l==2) ? e11 : e15;
    w0 *= sinv; w1 *= sinv; w2 *= sinv; w3 *= sinv;

    int Hl = (l==0) ? 100 : (l==1) ? 50 : (l==2) ? 25 : 13;
    int Wl = (l==0) ? 134 : (l==1) ? 67 : (l==2) ? 34 : 17;
    int s  = (l==0) ? 0 : (l==1) ? 13400 : (l==2) ? 16750 : 17600;
    float fW = (float)Wl, fH = (float)Hl;

    float rx = trp[((size_t)r * NL + l) * 2 + 0];
    float ry = trp[((size_t)r * NL + l) * 2 + 1];
    const float* offr = offaw + (size_t)r * 384 + h * 32 + l * 8;

    float o0 = 0.f, o1 = 0.f, o2 = 0.f, o3 = 0.f;
#pragma unroll
    for (int p = 0; p < 4; ++p) {
        float ox = offr[p * 2 + 0];
        float oy = offr[p * 2 + 1];
        float wq = (p==0) ? w0 : (p==1) ? w1 : (p==2) ? w2 : w3;
        float x = (rx + ox / fW) * fW - 0.5f;
        float y = (ry + oy / fH) * fH - 0.5f;
        float x0 = floorf(x), y0 = floorf(y);
#pragma unroll
        for (int dy = 0; dy < 2; ++dy) {
#pragma unroll
            for (int dx = 0; dx < 2; ++dx) {
                float xi = x0 + dx, yi = y0 + dy;
                float wgt = (1.0f - fabsf(x - xi)) * (1.0f - fabsf(y - yi));
                bool valid = (xi >= 0.f) && (xi < fW) && (yi >= 0.f) && (yi < fH);
                int xic = min(max((int)xi, 0), Wl - 1);
                int yic = min(max((int)yi, 0), Hl - 1);
                float cw = (valid ? wgt : 0.f) * wq;
                us4_t v4 = *(const us4_t*)&vb[((size_t)(s + yic * Wl + xic)) * DH + d0];
                o0 += cw * b2f(v4[0]);
                o1 += cw * b2f(v4[1]);
                o2 += cw * b2f(v4[2]);
                o3 += cw * b2f(v4[3]);
            }
        }
    }
    o0 += __shfl_xor(o0, 8, 32); o0 += __shfl_xor(o0, 16, 32);
    o1 += __shfl_xor(o1, 8, 32); o1 += __shfl_xor(o1, 16, 32);
    o2 += __shfl_xor(o2, 8, 32); o2 += __shfl_xor(o2, 16, 32);
    o3 += __shfl_xor(o3, 8, 32); o3 += __shfl_xor(o3, 16, 32);
    if (l == 0) {
        U4 u;
        u.u[0] = cvtpk(o0, o1);
        u.u[1] = cvtpk(o2, o3);
        *(us4_t*)&accU[(size_t)r * C + h * 32 + d0] = u.v;
    }
}

// ---------------- residual + LN: wave-per-row; dual f32 + bf16 output ----------------
__global__ void k_res_ln(const float* __restrict__ Y0, const float* __restrict__ Y1,
                         const float* __restrict__ Xres, const float* __restrict__ g,
                         const float* __restrict__ be, float* __restrict__ out,
                         unsigned short* __restrict__ outU) {
    int t = threadIdx.x, wv = t >> 6, lane = t & 63;
    int r = blockIdx.x * 4 + wv;
    float4 v = ((const float4*)(Y0 + (size_t)r * C))[lane];
    float4 x = ((const float4*)(Xres + (size_t)r * C))[lane];
    v.x += x.x; v.y += x.y; v.z += x.z; v.w += x.w;
    if (Y1) {
        float4 y1 = ((const float4*)(Y1 + (size_t)r * C))[lane];
        v.x += y1.x; v.y += y1.y; v.z += y1.z; v.w += y1.w;
    }
    float s = (v.x + v.y) + (v.z + v.w);
#pragma unroll
    for (int o = 32; o > 0; o >>= 1) s += __shfl_xor(s, o, 64);
    float mean = s * (1.0f / C);
    float4 dv = make_float4(v.x - mean, v.y - mean, v.z - mean, v.w - mean);
    float q = (dv.x * dv.x + dv.y * dv.y) + (dv.z * dv.z + dv.w * dv.w);
#pragma unroll
    for (int o = 32; o > 0; o >>= 1) q += __shfl_xor(q, o, 64);
    float rstd = rsqrtf(q * (1.0f / C) + 1e-5f);
    float4 g4 = ((const float4*)g)[lane];
    float4 b4 = ((const float4*)be)[lane];
    float4 o4 = make_float4(dv.x * rstd * g4.x + b4.x, dv.y * rstd * g4.y + b4.y,
                            dv.z * rstd * g4.z + b4.z, dv.w * rstd * g4.w + b4.w);
    ((float4*)(out + (size_t)r * C))[lane] = o4;
    if (outU) {
        U4 u;
        u.u[0] = cvtpk(o4.x, o4.y);
        u.u[1] = cvtpk(o4.z, o4.w);
        *(us4_t*)(outU + (size_t)r * C + lane * 4) = u.v;
    }
}

// ---------------- MFMA flash attention (bf16 Q/K/V/O) ----------------
#define NQC3 15   // ceil(900/64)

__global__ __launch_bounds__(256, 1)
void k_attn3(const unsigned short* __restrict__ Q, const unsigned short* __restrict__ K,
             const unsigned short* __restrict__ V, unsigned short* __restrict__ O) {
    __shared__ unsigned short sK[4][64 * 72];   // K rows [key][d]
    __shared__ unsigned short sV[4][32 * 72];   // V^T [d][key]
    __shared__ float sPO[4][64 * 36];           // P bf16 [64q][72k] overlaid, then Obuf f32 [64q][36d]
    __shared__ float sWm[4][64], sWl[4][64];

    int blk = blockIdx.x;
    int bh = blk & 31;                 // XCD locality
    int qc = blk >> 5;
    int b = bh >> 3, h = bh & 7;
    int t = threadIdx.x;
    int w = t >> 6, lane = t & 63;
    int lr = lane & 15, g = lane >> 4;

    const unsigned short* Qb = Q + (size_t)bh * LQ * DH;
    const unsigned short* Kb = K + (size_t)bh * LQ * DH;
    const unsigned short* Vb = V + (size_t)bh * LQ * DH;

    unsigned short* Ks = sK[w];
    unsigned short* Vt = sV[w];
    unsigned short* Ps = (unsigned short*)sPO[w];

    bf8_t qf[4];
#pragma unroll
    for (int nt = 0; nt < 4; ++nt) {
        int qg = min(qc * 64 + nt * 16 + lr, LQ - 1);
        qf[nt] = *(const bf8_t*)(Qb + (size_t)qg * DH + g * 8);
    }

    float m[4], l[4];
    f4_t acc[2][4];
#pragma unroll
    for (int nt = 0; nt < 4; ++nt) {
        m[nt] = -3e38f; l[nt] = 0.f;
        acc[0][nt] = (f4_t)0.f; acc[1][nt] = (f4_t)0.f;
    }

    for (int ci = 0; ci < 4; ++ci) {
        int k0 = ci * 256 + w * 64;
        if (k0 >= LQ) break;
        int kgl = min(k0 + lane, LQ - 1);
        const unsigned short* kr = Kb + (size_t)kgl * DH;
        const unsigned short* vr = Vb + (size_t)kgl * DH;
#pragma unroll
        for (int i = 0; i < 4; ++i)
            *(us8_t*)&Ks[lane * 72 + i * 8] = *(const us8_t*)(kr + i * 8);
#pragma unroll
        for (int i = 0; i < 4; ++i) {
            us8_t v8 = *(const us8_t*)(vr + i * 8);
#pragma unroll
            for (int j = 0; j < 8; ++j)
                Vt[(i * 8 + j) * 72 + lane] = v8[j];
        }
        // ---- QK^T: S^T[64k][64q] ----
        bf8_t ka[4];
#pragma unroll
        for (int mt = 0; mt < 4; ++mt)
            ka[mt] = *(const bf8_t*)&Ks[(mt * 16 + lr) * 72 + g * 8];
        f4_t st[4][4];
#pragma unroll
        for (int mt = 0; mt < 4; ++mt)
#pragma unroll
            for (int nt = 0; nt < 4; ++nt)
                st[mt][nt] = __builtin_amdgcn_mfma_f32_16x16x32_bf16(ka[mt], qf[nt], (f4_t)0.f, 0, 0, 0);
        // ---- online softmax + P write ----
#pragma unroll
        for (int nt = 0; nt < 4; ++nt) {
            float sv[4][4];
            float cm = -3e38f;
#pragma unroll
            for (int mt = 0; mt < 4; ++mt)
#pragma unroll
                for (int rr = 0; rr < 4; ++rr) {
                    bool valid = (k0 + mt * 16 + g * 4 + rr) < LQ;
                    float s = valid ? st[mt][nt][rr] : -3e38f;
                    sv[mt][rr] = s;
                    cm = fmaxf(cm, s);
                }
            cm = fmaxf(cm, __shfl_xor(cm, 16, 64));
            cm = fmaxf(cm, __shfl_xor(cm, 32, 64));
            float mn = fmaxf(m[nt], cm);
            float sc = __expf(m[nt] - mn);
            float cs = 0.f;
#pragma unroll
            for (int mt = 0; mt < 4; ++mt) {
                float pv0 = (sv[mt][0] > -1e37f) ? __expf(sv[mt][0] - mn) : 0.f;
                float pv1 = (sv[mt][1] > -1e37f) ? __expf(sv[mt][1] - mn) : 0.f;
                float pv2 = (sv[mt][2] > -1e37f) ? __expf(sv[mt][2] - mn) : 0.f;
                float pv3 = (sv[mt][3] > -1e37f) ? __expf(sv[mt][3] - mn) : 0.f;
                cs += (pv0 + pv1) + (pv2 + pv3);
                U4 pk;
                pk.u[0] = cvtpk(pv0, pv1);
                pk.u[1] = cvtpk(pv2, pv3);
                *(us4_t*)&Ps[(nt * 16 + lr) * 72 + mt * 16 + g * 4] = pk.v;
            }
            cs += __shfl_xor(cs, 16, 64);
            cs += __shfl_xor(cs, 32, 64);
            l[nt] = l[nt] * sc + cs;
            m[nt] = mn;
            acc[0][nt] *= sc;
            acc[1][nt] *= sc;
        }
        // ---- PV: O^T[32d][64q] ----
        bf8_t va[2][2];
#pragma unroll
        for (int md = 0; md < 2; ++md)
#pragma unroll
            for (int kt = 0; kt < 2; ++kt)
                va[md][kt] = *(const bf8_t*)&Vt[(md * 16 + lr) * 72 + kt * 32 + g * 8];
#pragma unroll
        for (int nt = 0; nt < 4; ++nt)
#pragma unroll
            for (int kt = 0; kt < 2; ++kt) {
                bf8_t pb = *(const bf8_t*)&Ps[(nt * 16 + lr) * 72 + kt * 32 + g * 8];
                acc[0][nt] = __builtin_amdgcn_mfma_f32_16x16x32_bf16(va[0][kt], pb, acc[0][nt], 0, 0, 0);
                acc[1][nt] = __builtin_amdgcn_mfma_f32_16x16x32_bf16(va[1][kt], pb, acc[1][nt], 0, 0, 0);
            }
    }

    // ---- wave combine ----
    if (g == 0) {
#pragma unroll
        for (int nt = 0; nt < 4; ++nt) {
            sWm[w][nt * 16 + lr] = m[nt];
            sWl[w][nt * 16 + lr] = l[nt];
        }
    }
    __syncthreads();
    float* ob = sPO[w];
#pragma unroll
    for (int nt = 0; nt < 4; ++nt) {
        int q = nt * 16 + lr;
        float M = fmaxf(fmaxf(sWm[0][q], sWm[1][q]), fmaxf(sWm[2][q], sWm[3][q]));
        float fac = __expf(m[nt] - M);
        f4_t v0 = acc[0][nt] * fac;
        f4_t v1 = acc[1][nt] * fac;
        *(f4_t*)&ob[q * 36 + g * 4] = v0;
        *(f4_t*)&ob[q * 36 + 16 + g * 4] = v1;
    }
    __syncthreads();
    {
        int q = t >> 2, d0 = (t & 3) * 8;
        int qglob = qc * 64 + q;
        if (qglob < LQ) {
            float M = fmaxf(fmaxf(sWm[0][q], sWm[1][q]), fmaxf(sWm[2][q], sWm[3][q]));
            float L = 0.f;
#pragma unroll
            for (int w2 = 0; w2 < 4; ++w2) L += sWl[w2][q] * __expf(sWm[w2][q] - M);
            float inv = 1.0f / L;
            f4_t r0 = (f4_t)0.f, r1 = (f4_t)0.f;
#pragma unroll
            for (int w2 = 0; w2 < 4; ++w2) {
                r0 += *(f4_t*)&sPO[w2][q * 36 + d0];
                r1 += *(f4_t*)&sPO[w2][q * 36 + d0 + 4];
            }
            r0 *= inv; r1 *= inv;
            U8 u;
            u.u[0] = cvtpk(r0[0], r0[1]);
            u.u[1] = cvtpk(r0[2], r0[3]);
            u.u[2] = cvtpk(r1[0], r1[1]);
            u.u[3] = cvtpk(r1[2], r1[3]);
            *(us8_t*)(O + ((size_t)(qglob * BQ + b)) * C + h * 32 + d0) = u.v;
        }
    }
}

// ---------------- launch ----------------
extern "C" void kernel_launch(void* const* d_in, const int* in_sizes, int n_in,
                              void* d_out, int out_size, void* d_ws, size_t ws_size,
                              hipStream_t stream) {
    const float* tgt      = (const float*)d_in[0];
    const float* trp      = (const float*)d_in[1];
    const float* memory   = (const float*)d_in[2];
    const float* vproj_w  = (const float*)d_in[5];  const float* vproj_b  = (const float*)d_in[6];
    const float* off_w    = (const float*)d_in[7];  const float* off_b    = (const float*)d_in[8];
    const float* aw_w     = (const float*)d_in[9];  const float* aw_b     = (const float*)d_in[10];
    const float* oproj_w  = (const float*)d_in[11]; const float* oproj_b  = (const float*)d_in[12];
    const float* ln1_g    = (const float*)d_in[13]; const float* ln1_b    = (const float*)d_in[14];
    const float* sa_in_w  = (const float*)d_in[15]; const float* sa_in_b  = (const float*)d_in[16];
    const float* sa_out_w = (const float*)d_in[17]; const float* sa_out_b = (const float*)d_in[18];
    const float* ln2_g    = (const float*)d_in[19]; const float* ln2_b    = (const float*)d_in[20];
    const float* l1_w     = (const float*)d_in[21]; const float* l1_b     = (const float*)d_in[22];
    const float* l2_w     = (const float*)d_in[23]; const float* l2_b     = (const float*)d_in[24];
    const float* ln3_g    = (const float*)d_in[25]; const float* ln3_b    = (const float*)d_in[26];
    const float* sa3_in_w = (const float*)d_in[27]; const float* sa3_in_b = (const float*)d_in[28];
    const float* sa3_out_w= (const float*)d_in[29]; const float* sa3_out_b= (const float*)d_in[30];
    const float* ln5_g    = (const float*)d_in[31]; const float* ln5_b    = (const float*)d_in[32];
    const float* l31_w    = (const float*)d_in[33]; const float* l31_b    = (const float*)d_in[34];
    const float* l32_w    = (const float*)d_in[35]; const float* l32_b    = (const float*)d_in[36];
    const float* ln33_g   = (const float*)d_in[37]; const float* ln33_b   = (const float*)d_in[38];

    float* ws = (float*)d_ws;
    float* X              = ws;                                    // 921,600 f32
    unsigned short* valueU= (unsigned short*)(ws + 921600);        // 18,248,704 bf16
    float* offaw          = ws + 10045952;                         // 1,382,400 f32 [3600][384]
    unsigned short* accU  = (unsigned short*)(ws + 11428352);      // 921,600 bf16
    unsigned short* QKVu  = (unsigned short*)(ws + 12349952);      // 2,764,800 bf16
    unsigned short* Ou    = (unsigned short*)(ws + 13732352);      // 921,600 bf16
    unsigned short* H1u   = (unsigned short*)(ws + 14193152);      // 7,372,800 bf16
    float* Y              = ws + 17879552;                         // 921,600 f32
    float* Y2             = ws + 18801152;                         // 921,600 f32
    float* T1             = ws + 19722752;                         // 921,600 f32
    unsigned short* Wbf   = (unsigned short*)(ws + 20644352);      // 2,850,816 bf16
    float* bias384        = ws + 22069760;                         // 384 f32
    unsigned short* XU    = (unsigned short*)(ws + 22070144);      // 921,600 bf16
    unsigned short* tgtU  = (unsigned short*)(ws + 22530944);      // 921,600 bf16

    const int NVROWS = BQ * LVTOT;           // 71,284 -> 558 row-blocks -> 70 supergroups
    dim3 blk(256);
    dim3 gTok(29, 4);
    void* nullv = nullptr;

    // ---- pre-conversions (weights + tgt) ----
    k_prep<<<(PTOT + 255) / 256, blk, 0, stream>>>(off_w, aw_w, vproj_w, oproj_w, sa_in_w, sa_out_w,
                                                   l1_w, l2_w, sa3_in_w, sa3_out_w, l31_w, l32_w,
                                                   off_b, aw_b, tgt, Wbf, bias384, tgtU);

    // ---- ca: MSDeformAttn ----
    k_mgemm<256, 256, 256, MODE_VALUE, 0, 1, 4, 0><<<70 * 32, blk, 0, stream>>>(memory, Wbf + WOFF_VPROJ, vproj_b, valueU, nullv, NVROWS);
    k_mgemm<256, 256, 384, MODE_NORMAL, 1, 0, 0, 0><<<dim3(29, 6), blk, 0, stream>>>(tgtU, Wbf + WOFF_OFFAW, bias384, offaw, nullv, NTOK);
    k_sample<<<NTOK, blk, 0, stream>>>(trp, offaw, valueU, accU);
    k_mgemm<256, 256, 256, MODE_NORMAL, 1, 0, 0, 0><<<gTok, blk, 0, stream>>>(accU, Wbf + WOFF_OPROJ, oproj_b, T1, nullv, NTOK);
    k_res_ln<<<NTOK / 4, blk, 0, stream>>>(T1, nullptr, tgt, ln1_g, ln1_b, X, XU);

    // ---- sa ----
    k_mgemm<256, 256, 768, MODE_QKV, 1, 1, 0, 0><<<dim3(29, 12), blk, 0, stream>>>(XU, Wbf + WOFF_SAIN, sa_in_b, QKVu, nullv, NTOK);
    k_attn3<<<32 * NQC3, blk, 0, stream>>>(QKVu, QKVu + 921600, QKVu + 1843200, Ou);
    k_mgemm<256, 256, 256, MODE_NORMAL, 1, 0, 0, 0><<<gTok, blk, 0, stream>>>(Ou, Wbf + WOFF_SAOUT, sa_out_b, T1, nullv, NTOK);
    k_res_ln<<<NTOK / 4, blk, 0, stream>>>(T1, nullptr, X, ln2_g, ln2_b, X, XU);

    // ---- ffn ----
    k_mgemm<256, 256, 2048, MODE_RELU, 1, 1, 0, 0><<<dim3(29, 32), blk, 0, stream>>>(XU, Wbf + WOFF_L1, l1_b, H1u, nullv, NTOK);
    k_mgemm<1024, 2048, 256, MODE_NORMAL, 1, 0, 0, 1><<<4 * 64, blk, 0, stream>>>(H1u, Wbf + WOFF_L2, l2_b, Y, Y2, NTOK);
    k_res_ln<<<NTOK / 4, blk, 0, stream>>>(Y, Y2, X, ln3_g, ln3_b, X, XU);

    // ---- sa3 ----
    k_mgemm<256, 256, 768, MODE_QKV, 1, 1, 0, 0><<<dim3(29, 12), blk, 0, stream>>>(XU, Wbf + WOFF_SA3IN, sa3_in_b, QKVu, nullv, NTOK);
    k_attn3<<<32 * NQC3, blk, 0, stream>>>(QKVu, QKVu + 921600, QKVu + 1843200, Ou);
    k_mgemm<256, 256, 256, MODE_NORMAL, 1, 0, 0, 0><<<gTok, blk, 0, stream>>>(Ou, Wbf + WOFF_SA3OUT, sa3_out_b, T1, nullv, NTOK);
    k_res_ln<<<NTOK / 4, blk, 0, stream>>>(T1, nullptr, X, ln5_g, ln5_b, X, XU);

    // ---- ffn3 ----
    k_mgemm<256, 256, 2048, MODE_RELU, 1, 1, 0, 0><<<dim3(29, 32), blk, 0, stream>>>(XU, Wbf + WOFF_L31, l31_b, H1u, nullv, NTOK);
    k_mgemm<1024, 2048, 256, MODE_NORMAL, 1, 0, 0, 1><<<4 * 64, blk, 0, stream>>>(H1u, Wbf + WOFF_L32, l32_b, Y, Y2, NTOK);
    k_res_ln<<<NTOK / 4, blk, 0, stream>>>(Y, Y2, X, ln33_g, ln33_b, (float*)d_out, nullptr);
}

// Round 19
// 255.976 us; speedup vs baseline: 1.3228x; 1.0336x over previous
//
#include <hip/hip_runtime.h>
#include <math.h>

#define C 256
#define DH 32
#define NH 8
#define NL 4
#define NP 4
#define BQ 4
#define LQ 900
#define LVTOT 17821
#define DFFN 2048
#define NTOK (BQ*LQ)          // 3600 token rows, token index t = lq*B + b

typedef __attribute__((ext_vector_type(8))) short bf8_t;    // 8 bf16 (4 VGPRs)
typedef __attribute__((ext_vector_type(4))) float f4_t;     // MFMA acc
typedef __attribute__((ext_vector_type(8))) unsigned short us8_t;
typedef __attribute__((ext_vector_type(4))) unsigned short us4_t;

union U8 { us8_t v; unsigned int u[4]; };
union U4 { us4_t v; unsigned int u[2]; };

// ---------------- helpers ----------------
__device__ __forceinline__ unsigned short f2bf(float f) {
    unsigned int u = __float_as_uint(f);
    u += 0x7fffu + ((u >> 16) & 1u);   // round-to-nearest-even
    return (unsigned short)(u >> 16);
}
__device__ __forceinline__ float b2f(unsigned short u) {
    return __uint_as_float(((unsigned int)u) << 16);
}
// packed fp32x2 -> bf16x2 (RNE), 1 instruction
__device__ __forceinline__ unsigned int cvtpk(float lo, float hi) {
    unsigned int r;
    asm("v_cvt_pk_bf16_f32 %0, %1, %2" : "=v"(r) : "v"(lo), "v"(hi));
    return r;
}

// ---------------- one-time conversions: weights fp32->bf16, tgt fp32->bf16 ----------------
#define WOFF_OFFAW   0         // off_w 65536 | aw_w 32768  (fused 384x256)
#define WOFF_VPROJ   98304
#define WOFF_OPROJ   163840
#define WOFF_SAIN    229376
#define WOFF_SAOUT   425984
#define WOFF_L1      491520
#define WOFF_L2      1015808
#define WOFF_SA3IN   1540096
#define WOFF_SA3OUT  1736704
#define WOFF_L31     1802240
#define WOFF_L32     2326528
#define WTOT         2850816
#define PTOT         (WTOT + 921600)   // + tgt

__global__ void k_prep(const float* __restrict__ off_w, const float* __restrict__ aw_w,
                       const float* __restrict__ vproj_w, const float* __restrict__ oproj_w,
                       const float* __restrict__ sa_in_w, const float* __restrict__ sa_out_w,
                       const float* __restrict__ l1_w, const float* __restrict__ l2_w,
                       const float* __restrict__ sa3_in_w, const float* __restrict__ sa3_out_w,
                       const float* __restrict__ l31_w, const float* __restrict__ l32_w,
                       const float* __restrict__ off_b, const float* __restrict__ aw_b,
                       const float* __restrict__ tgt,
                       unsigned short* __restrict__ Wbf, float* __restrict__ bias384,
                       unsigned short* __restrict__ tgtU) {
    int i = blockIdx.x * 256 + threadIdx.x;
    if (i < 384) bias384[i] = (i < 256) ? off_b[i] : aw_b[i - 256];
    if (i >= PTOT) return;
    if (i >= WTOT) { int j = i - WTOT; tgtU[j] = f2bf(tgt[j]); return; }
    const float* src; int rel;
    if      (i < WOFF_VPROJ)  { if (i < 65536) { src = off_w; rel = i; } else { src = aw_w; rel = i - 65536; } }
    else if (i < WOFF_OPROJ)  { src = vproj_w;  rel = i - WOFF_VPROJ; }
    else if (i < WOFF_SAIN)   { src = oproj_w;  rel = i - WOFF_OPROJ; }
    else if (i < WOFF_SAOUT)  { src = sa_in_w;  rel = i - WOFF_SAIN; }
    else if (i < WOFF_L1)     { src = sa_out_w; rel = i - WOFF_SAOUT; }
    else if (i < WOFF_L2)     { src = l1_w;     rel = i - WOFF_L1; }
    else if (i < WOFF_SA3IN)  { src = l2_w;     rel = i - WOFF_L2; }
    else if (i < WOFF_SA3OUT) { src = sa3_in_w; rel = i - WOFF_SA3IN; }
    else if (i < WOFF_L31)    { src = sa3_out_w; rel = i - WOFF_SA3OUT; }
    else if (i < WOFF_L32)    { src = l31_w;    rel = i - WOFF_L31; }
    else                      { src = l32_w;    rel = i - WOFF_L32; }
    Wbf[i] = f2bf(src[rel]);
}

// ---------------- bf16 MFMA GEMM: Y = act(A @ W^T + b) ----------------
// A: [nrows][KS] fp32 (AB=0) or bf16 (AB=1); W: bf16. Output f32/bf16 per OB.
// Tile 128x64, 4 waves 2x2, K-step 32, DOUBLE-buffered LDS, ONE barrier/step.
// Prefetch depth 2 (named sets; depth 4 spills to scratch: R17 WRITE 37->147MB).
// XCDG=4: blk=32G+8cb+x -> rb=8G+x (4 col-tiles of a row-slab share an XCD).
// SPLITK=1: both K-halves of FFN2 in ONE dispatch (half 1 -> Y2, no bias).
enum { MODE_NORMAL = 0, MODE_RELU = 1, MODE_VALUE = 2, MODE_QKV = 3 };

#define LDP 40   // 80B row stride: frag reads 2-way (free), 16B-aligned

template<int K, int KS, int NTOT, int MODE, int AB, int OB, int XCDG, int SPLITK>
__global__ void k_mgemm(const void* __restrict__ A_, const unsigned short* __restrict__ Wbf,
                        const float* __restrict__ bias, void* __restrict__ Y_,
                        void* __restrict__ Y2_, int nrows) {
    __shared__ unsigned short Ash[2][128 * LDP];
    __shared__ unsigned short Bsh[2][64 * LDP];
    int t = threadIdx.x;
    int lane = t & 63, w = t >> 6;
    int wm = w & 1, wn = w >> 1;
    int rbx, cbx, khoff = 0;
    if (SPLITK) {
        int blk = blockIdx.x;
        rbx = (blk >> 6) * 8 + (blk & 7);
        cbx = (blk >> 3) & 3;
        int half = (blk >> 5) & 1;
        khoff = half * K;             // K = 1024, KS = 2048
        if (half) { Y_ = Y2_; bias = nullptr; }
        if (rbx * 128 >= nrows) return;
    } else if (XCDG) {
        int blk = blockIdx.x;
        rbx = (blk >> 5) * 8 + (blk & 7);
        cbx = (blk >> 3) & 3;
        if (rbx * 128 >= nrows) return;
    } else {
        rbx = blockIdx.x;
        cbx = blockIdx.y;
    }
    int r0 = rbx * 128;
    int c0 = cbx * 64;

    f4_t acc[4][2];
#pragma unroll
    for (int mt = 0; mt < 4; ++mt)
#pragma unroll
        for (int nt = 0; nt < 2; ++nt) acc[mt][nt] = (f4_t)0.f;

    int arow = t >> 1;
    int akoff = (t & 1) * 16;
    int asrc = min(r0 + arow, nrows - 1);
    const float* aptrf = (const float*)A_ + (size_t)asrc * KS + akoff + khoff;
    const unsigned short* aptrh = (const unsigned short*)A_ + (size_t)asrc * KS + akoff + khoff;
    unsigned short* adst0 = &Ash[0][arow * LDP + akoff];
    unsigned short* adst1 = &Ash[1][arow * LDP + akoff];

    int brow = t >> 2;
    int bkoff = (t & 3) * 8;
    const unsigned short* bptr = Wbf + (size_t)(c0 + brow) * KS + bkoff + khoff;
    unsigned short* bdst0 = &Bsh[0][brow * LDP + bkoff];
    unsigned short* bdst1 = &Bsh[1][brow * LDP + bkoff];

    int lr = lane & 15, kg = lane >> 4;

    float4 fA_0, fA_1, fA_2, fA_3, gA_0, gA_1, gA_2, gA_3;  // fp32 A sets (AB=0)
    us8_t hA_0, hA_1, hB_0, hB_1;                            // bf16 A sets (AB=1)
    us8_t wA, wB;

#define ISSUE_A(k0) do { \
        if (AB) { hA_0 = *(const us8_t*)(aptrh + (k0)); hA_1 = *(const us8_t*)(aptrh + (k0) + 8); } \
        else { fA_0 = *(const float4*)(aptrf + (k0)); fA_1 = *(const float4*)(aptrf + (k0) + 4); \
               fA_2 = *(const float4*)(aptrf + (k0) + 8); fA_3 = *(const float4*)(aptrf + (k0) + 12); } \
        wA = *(const us8_t*)(bptr + (k0)); } while (0)
#define ISSUE_B(k0) do { \
        if (AB) { hB_0 = *(const us8_t*)(aptrh + (k0)); hB_1 = *(const us8_t*)(aptrh + (k0) + 8); } \
        else { gA_0 = *(const float4*)(aptrf + (k0)); gA_1 = *(const float4*)(aptrf + (k0) + 4); \
               gA_2 = *(const float4*)(aptrf + (k0) + 8); gA_3 = *(const float4*)(aptrf + (k0) + 12); } \
        wB = *(const us8_t*)(bptr + (k0)); } while (0)
#define STORE_A(buf) do { \
        if (AB) { *(us8_t*)(adst##buf) = hA_0; *(us8_t*)(adst##buf + 8) = hA_1; } \
        else { U8 x, y; \
               x.u[0] = cvtpk(fA_0.x, fA_0.y); x.u[1] = cvtpk(fA_0.z, fA_0.w); \
               x.u[2] = cvtpk(fA_1.x, fA_1.y); x.u[3] = cvtpk(fA_1.z, fA_1.w); \
               y.u[0] = cvtpk(fA_2.x, fA_2.y); y.u[1] = cvtpk(fA_2.z, fA_2.w); \
               y.u[2] = cvtpk(fA_3.x, fA_3.y); y.u[3] = cvtpk(fA_3.z, fA_3.w); \
               *(us8_t*)(adst##buf) = x.v; *(us8_t*)(adst##buf + 8) = y.v; } \
        *(us8_t*)(bdst##buf) = wA; } while (0)
#define STORE_B(buf) do { \
        if (AB) { *(us8_t*)(adst##buf) = hB_0; *(us8_t*)(adst##buf + 8) = hB_1; } \
        else { U8 x, y; \
               x.u[0] = cvtpk(gA_0.x, gA_0.y); x.u[1] = cvtpk(gA_0.z, gA_0.w); \
               x.u[2] = cvtpk(gA_1.x, gA_1.y); x.u[3] = cvtpk(gA_1.z, gA_1.w); \
               y.u[0] = cvtpk(gA_2.x, gA_2.y); y.u[1] = cvtpk(gA_2.z, gA_2.w); \
               y.u[2] = cvtpk(gA_3.x, gA_3.y); y.u[3] = cvtpk(gA_3.z, gA_3.w); \
               *(us8_t*)(adst##buf) = x.v; *(us8_t*)(adst##buf + 8) = y.v; } \
        *(us8_t*)(bdst##buf) = wB; } while (0)
#define COMPUTE(buf) do { \
        bf8_t afr[4], bfr[2]; \
        _Pragma("unroll") \
        for (int mt = 0; mt < 4; ++mt) \
            afr[mt] = *(const bf8_t*)&Ash[buf][(wm * 64 + mt * 16 + lr) * LDP + kg * 8]; \
        _Pragma("unroll") \
        for (int nt = 0; nt < 2; ++nt) \
            bfr[nt] = *(const bf8_t*)&Bsh[buf][(wn * 32 + nt * 16 + lr) * LDP + kg * 8]; \
        _Pragma("unroll") \
        for (int mt = 0; mt < 4; ++mt) \
            _Pragma("unroll") \
            for (int nt = 0; nt < 2; ++nt) \
                acc[mt][nt] = __builtin_amdgcn_mfma_f32_16x16x32_bf16(afr[mt], bfr[nt], acc[mt][nt], 0, 0, 0); \
    } while (0)

    ISSUE_A(0);
#pragma unroll 1
    for (int k0 = 0; k0 < K; k0 += 64) {
        STORE_A(0);
        ISSUE_B(k0 + 32);           // K multiple of 64 -> always valid
        __syncthreads();
        COMPUTE(0);
        STORE_B(1);
        if (k0 + 64 < K) ISSUE_A(k0 + 64);
        __syncthreads();
        COMPUTE(1);
    }
#undef ISSUE_A
#undef ISSUE_B
#undef STORE_A
#undef STORE_B
#undef COMPUTE

#pragma unroll
    for (int mt = 0; mt < 4; ++mt) {
#pragma unroll
        for (int nt = 0; nt < 2; ++nt) {
            int col = c0 + wn * 32 + nt * 16 + lr;
            float b0s = bias ? bias[col] : 0.f;
#pragma unroll
            for (int rr = 0; rr < 4; ++rr) {
                int row = r0 + wm * 64 + mt * 16 + kg * 4 + rr;
                if (row >= nrows) continue;
                float v = acc[mt][nt][rr] + b0s;
                size_t idx;
                if (MODE == MODE_NORMAL) {
                    idx = (size_t)row * NTOT + col;
                } else if (MODE == MODE_RELU) {
                    v = fmaxf(v, 0.f);
                    idx = (size_t)row * NTOT + col;
                } else if (MODE == MODE_VALUE) {
                    int lv = row >> 2, b = row & 3;
                    int h = col >> 5, d = col & 31;
                    idx = (((size_t)b * NH + h) * LVTOT + lv) * DH + d;
                } else { // MODE_QKV
                    int lq = row >> 2, b = row & 3;
                    int part = col >> 8, cc = col & 255;
                    int h = cc >> 5, d = cc & 31;
                    if (part == 0) v *= 0.17677669529663687f;  // 1/sqrt(32)
                    idx = (size_t)part * (BQ * NH * LQ * DH) + (((size_t)b * NH + h) * LQ + lq) * DH + d;
                }
                if (OB) ((unsigned short*)Y_)[idx] = f2bf(v);
                else    ((float*)Y_)[idx] = v;
            }
        }
    }
}

// ---------------- vproj-dedicated GEMM: 64x64 tile, 8 blocks/CU (full occupancy) ----------------
// memory [NVROWS][256] fp32 -> valueU (MODE_VALUE scatter, bf16). Same dbuf
// one-barrier pipeline; LDS 20.5 KB -> 8 blocks/CU = 32 waves (was 5 blk, 20 w):
// 1.6x in-flight load bytes for the latency-bound fetch. Waves 2x2 of 32x32.
__global__ void k_vproj64(const float* __restrict__ A, const unsigned short* __restrict__ Wbf,
                          const float* __restrict__ bias, unsigned short* __restrict__ Y,
                          int nrows) {
    __shared__ unsigned short Ash[2][64 * LDP];
    __shared__ unsigned short Bsh[2][64 * LDP];
    int t = threadIdx.x;
    int lane = t & 63, w = t >> 6;
    int wm = w & 1, wn = w >> 1;
    int blk = blockIdx.x;
    int rbx = (blk >> 5) * 8 + (blk & 7);
    int cbx = (blk >> 3) & 3;
    if (rbx * 64 >= nrows) return;
    int r0 = rbx * 64;
    int c0 = cbx * 64;

    f4_t acc[2][2];
#pragma unroll
    for (int mt = 0; mt < 2; ++mt)
#pragma unroll
        for (int nt = 0; nt < 2; ++nt) acc[mt][nt] = (f4_t)0.f;

    int arow = t >> 2;                 // 0..63
    int akoff = (t & 3) * 8;           // 0,8,16,24
    int asrc = min(r0 + arow, nrows - 1);
    const float* aptrf = A + (size_t)asrc * 256 + akoff;
    unsigned short* adst0 = &Ash[0][arow * LDP + akoff];
    unsigned short* adst1 = &Ash[1][arow * LDP + akoff];

    const unsigned short* bptr = Wbf + (size_t)(c0 + arow) * 256 + akoff;
    unsigned short* bdst0 = &Bsh[0][arow * LDP + akoff];
    unsigned short* bdst1 = &Bsh[1][arow * LDP + akoff];

    int lr = lane & 15, kg = lane >> 4;

    float4 fA_0, fA_1, gA_0, gA_1;
    us8_t wA, wB;

#define ISSUE_A(k0) do { fA_0 = *(const float4*)(aptrf + (k0)); fA_1 = *(const float4*)(aptrf + (k0) + 4); \
                         wA = *(const us8_t*)(bptr + (k0)); } while (0)
#define ISSUE_B(k0) do { gA_0 = *(const float4*)(aptrf + (k0)); gA_1 = *(const float4*)(aptrf + (k0) + 4); \
                         wB = *(const us8_t*)(bptr + (k0)); } while (0)
#define STORE_A(buf) do { U4 x0, x1; \
        x0.u[0] = cvtpk(fA_0.x, fA_0.y); x0.u[1] = cvtpk(fA_0.z, fA_0.w); \
        x1.u[0] = cvtpk(fA_1.x, fA_1.y); x1.u[1] = cvtpk(fA_1.z, fA_1.w); \
        *(us4_t*)(adst##buf) = x0.v; *(us4_t*)(adst##buf + 4) = x1.v; \
        *(us8_t*)(bdst##buf) = wA; } while (0)
#define STORE_B(buf) do { U4 x0, x1; \
        x0.u[0] = cvtpk(gA_0.x, gA_0.y); x0.u[1] = cvtpk(gA_0.z, gA_0.w); \
        x1.u[0] = cvtpk(gA_1.x, gA_1.y); x1.u[1] = cvtpk(gA_1.z, gA_1.w); \
        *(us4_t*)(adst##buf) = x0.v; *(us4_t*)(adst##buf + 4) = x1.v; \
        *(us8_t*)(bdst##buf) = wB; } while (0)
#define COMPUTE(buf) do { \
        bf8_t afr[2], bfr[2]; \
        _Pragma("unroll") \
        for (int mt = 0; mt < 2; ++mt) \
            afr[mt] = *(const bf8_t*)&Ash[buf][(wm * 32 + mt * 16 + lr) * LDP + kg * 8]; \
        _Pragma("unroll") \
        for (int nt = 0; nt < 2; ++nt) \
            bfr[nt] = *(const bf8_t*)&Bsh[buf][(wn * 32 + nt * 16 + lr) * LDP + kg * 8]; \
        _Pragma("unroll") \
        for (int mt = 0; mt < 2; ++mt) \
            _Pragma("unroll") \
            for (int nt = 0; nt < 2; ++nt) \
                acc[mt][nt] = __builtin_amdgcn_mfma_f32_16x16x32_bf16(afr[mt], bfr[nt], acc[mt][nt], 0, 0, 0); \
    } while (0)

    ISSUE_A(0);
#pragma unroll 1
    for (int k0 = 0; k0 < 256; k0 += 64) {
        STORE_A(0);
        ISSUE_B(k0 + 32);
        __syncthreads();
        COMPUTE(0);
        STORE_B(1);
        if (k0 + 64 < 256) ISSUE_A(k0 + 64);
        __syncthreads();
        COMPUTE(1);
    }
#undef ISSUE_A
#undef ISSUE_B
#undef STORE_A
#undef STORE_B
#undef COMPUTE

#pragma unroll
    for (int mt = 0; mt < 2; ++mt) {
#pragma unroll
        for (int nt = 0; nt < 2; ++nt) {
            int col = c0 + wn * 32 + nt * 16 + lr;
            float b0s = bias[col];
#pragma unroll
            for (int rr = 0; rr < 4; ++rr) {
                int row = r0 + wm * 32 + mt * 16 + kg * 4 + rr;
                if (row >= nrows) continue;
                float v = acc[mt][nt][rr] + b0s;
                int lv = row >> 2, b = row & 3;
                int h = col >> 5, d = col & 31;
                Y[(((size_t)b * NH + h) * LVTOT + lv) * DH + d] = f2bf(v);
            }
        }
    }
}

// ---------------- deformable sampling ----------------
__global__ void k_sample(const float* __restrict__ trp, const float* __restrict__ offaw,
                         const unsigned short* __restrict__ value,
                         unsigned short* __restrict__ accU) {
    int r = blockIdx.x;
    int b = r & 3;
    int t = threadIdx.x;
    int h = t >> 5;
    int lane32 = t & 31;
    int l = lane32 >> 3;               // level-group
    int dl = lane32 & 7;               // d-quad: d0 = dl*4
    int d0 = dl * 4;
    const unsigned short* vb = value + ((size_t)b * NH + h) * (size_t)LVTOT * DH;

    const float* lg = offaw + (size_t)r * 384 + 256 + h * 16;
    float e0,e1,e2,e3,e4,e5,e6,e7,e8,e9,e10,e11,e12,e13,e14,e15;
    {
        float4 q0 = *(const float4*)(lg);
        float4 q1 = *(const float4*)(lg + 4);
        float4 q2 = *(const float4*)(lg + 8);
        float4 q3 = *(const float4*)(lg + 12);
        float mx = fmaxf(fmaxf(fmaxf(q0.x,q0.y),fmaxf(q0.z,q0.w)),
                   fmaxf(fmaxf(fmaxf(q1.x,q1.y),fmaxf(q1.z,q1.w)),
                   fmaxf(fmaxf(fmaxf(q2.x,q2.y),fmaxf(q2.z,q2.w)),
                         fmaxf(fmaxf(q3.x,q3.y),fmaxf(q3.z,q3.w)))));
        e0=__expf(q0.x-mx); e1=__expf(q0.y-mx); e2=__expf(q0.z-mx); e3=__expf(q0.w-mx);
        e4=__expf(q1.x-mx); e5=__expf(q1.y-mx); e6=__expf(q1.z-mx); e7=__expf(q1.w-mx);
        e8=__expf(q2.x-mx); e9=__expf(q2.y-mx); e10=__expf(q2.z-mx); e11=__expf(q2.w-mx);
        e12=__expf(q3.x-mx); e13=__expf(q3.y-mx); e14=__expf(q3.z-mx); e15=__expf(q3.w-mx);
    }
    float ssum = ((e0+e1)+(e2+e3)) + ((e4+e5)+(e6+e7)) + ((e8+e9)+(e10+e11)) + ((e12+e13)+(e14+e15));
    float sinv = 1.0f / ssum;
    float w0 = (l==0) ? e0 : (l==1) ? e4 : (l==2) ? e8  : e12;
    float w1 = (l==0) ? e1 : (l==1) ? e5 : (l==2) ? e9  : e13;
    float w2 = (l==0) ? e2 : (l==1) ? e6 : (l==2) ? e10 : e14;
    float w3 = (l==0) ? e3 : (l==1) ? e7 : (l==2) ? e11 : e15;
    w0 *= sinv; w1 *= sinv; w2 *= sinv; w3 *= sinv;

    int Hl = (l==0) ? 100 : (l==1) ? 50 : (l==2) ? 25 : 13;
    int Wl = (l==0) ? 134 : (l==1) ? 67 : (l==2) ? 34 : 17;
    int s  = (l==0) ? 0 : (l==1) ? 13400 : (l==2) ? 16750 : 17600;
    float fW = (float)Wl, fH = (float)Hl;

    float rx = trp[((size_t)r * NL + l) * 2 + 0];
    float ry = trp[((size_t)r * NL + l) * 2 + 1];
    const float* offr = offaw + (size_t)r * 384 + h * 32 + l * 8;

    float o0 = 0.f, o1 = 0.f, o2 = 0.f, o3 = 0.f;
#pragma unroll
    for (int p = 0; p < 4; ++p) {
        float ox = offr[p * 2 + 0];
        float oy = offr[p * 2 + 1];
        float wq = (p==0) ? w0 : (p==1) ? w1 : (p==2) ? w2 : w3;
        float x = (rx + ox / fW) * fW - 0.5f;
        float y = (ry + oy / fH) * fH - 0.5f;
        float x0 = floorf(x), y0 = floorf(y);
#pragma unroll
        for (int dy = 0; dy < 2; ++dy) {
#pragma unroll
            for (int dx = 0; dx < 2; ++dx) {
                float xi = x0 + dx, yi = y0 + dy;
                float wgt = (1.0f - fabsf(x - xi)) * (1.0f - fabsf(y - yi));
                bool valid = (xi >= 0.f) && (xi < fW) && (yi >= 0.f) && (yi < fH);
                int xic = min(max((int)xi, 0), Wl - 1);
                int yic = min(max((int)yi, 0), Hl - 1);
                float cw = (valid ? wgt : 0.f) * wq;
                us4_t v4 = *(const us4_t*)&vb[((size_t)(s + yic * Wl + xic)) * DH + d0];
                o0 += cw * b2f(v4[0]);
                o1 += cw * b2f(v4[1]);
                o2 += cw * b2f(v4[2]);
                o3 += cw * b2f(v4[3]);
            }
        }
    }
    o0 += __shfl_xor(o0, 8, 32); o0 += __shfl_xor(o0, 16, 32);
    o1 += __shfl_xor(o1, 8, 32); o1 += __shfl_xor(o1, 16, 32);
    o2 += __shfl_xor(o2, 8, 32); o2 += __shfl_xor(o2, 16, 32);
    o3 += __shfl_xor(o3, 8, 32); o3 += __shfl_xor(o3, 16, 32);
    if (l == 0) {
        U4 u;
        u.u[0] = cvtpk(o0, o1);
        u.u[1] = cvtpk(o2, o3);
        *(us4_t*)&accU[(size_t)r * C + h * 32 + d0] = u.v;
    }
}

// ---------------- residual + LN: wave-per-row; dual f32 + bf16 output ----------------
__global__ void k_res_ln(const float* __restrict__ Y0, const float* __restrict__ Y1,
                         const float* __restrict__ Xres, const float* __restrict__ g,
                         const float* __restrict__ be, float* __restrict__ out,
                         unsigned short* __restrict__ outU) {
    int t = threadIdx.x, wv = t >> 6, lane = t & 63;
    int r = blockIdx.x * 4 + wv;
    float4 v = ((const float4*)(Y0 + (size_t)r * C))[lane];
    float4 x = ((const float4*)(Xres + (size_t)r * C))[lane];
    v.x += x.x; v.y += x.y; v.z += x.z; v.w += x.w;
    if (Y1) {
        float4 y1 = ((const float4*)(Y1 + (size_t)r * C))[lane];
        v.x += y1.x; v.y += y1.y; v.z += y1.z; v.w += y1.w;
    }
    float s = (v.x + v.y) + (v.z + v.w);
#pragma unroll
    for (int o = 32; o > 0; o >>= 1) s += __shfl_xor(s, o, 64);
    float mean = s * (1.0f / C);
    float4 dv = make_float4(v.x - mean, v.y - mean, v.z - mean, v.w - mean);
    float q = (dv.x * dv.x + dv.y * dv.y) + (dv.z * dv.z + dv.w * dv.w);
#pragma unroll
    for (int o = 32; o > 0; o >>= 1) q += __shfl_xor(q, o, 64);
    float rstd = rsqrtf(q * (1.0f / C) + 1e-5f);
    float4 g4 = ((const float4*)g)[lane];
    float4 b4 = ((const float4*)be)[lane];
    float4 o4 = make_float4(dv.x * rstd * g4.x + b4.x, dv.y * rstd * g4.y + b4.y,
                            dv.z * rstd * g4.z + b4.z, dv.w * rstd * g4.w + b4.w);
    ((float4*)(out + (size_t)r * C))[lane] = o4;
    if (outU) {
        U4 u;
        u.u[0] = cvtpk(o4.x, o4.y);
        u.u[1] = cvtpk(o4.z, o4.w);
        *(us4_t*)(outU + (size_t)r * C + lane * 4) = u.v;
    }
}

// ---------------- MFMA flash attention (bf16 Q/K/V/O) ----------------
#define NQC3 15   // ceil(900/64)

__global__ __launch_bounds__(256, 1)
void k_attn3(const unsigned short* __restrict__ Q, const unsigned short* __restrict__ K,
             const unsigned short* __restrict__ V, unsigned short* __restrict__ O) {
    __shared__ unsigned short sK[4][64 * 72];   // K rows [key][d]
    __shared__ unsigned short sV[4][32 * 72];   // V^T [d][key]
    __shared__ float sPO[4][64 * 36];           // P bf16 [64q][72k] overlaid, then Obuf f32 [64q][36d]
    __shared__ float sWm[4][64], sWl[4][64];

    int blk = blockIdx.x;
    int bh = blk & 31;                 // XCD locality
    int qc = blk >> 5;
    int b = bh >> 3, h = bh & 7;
    int t = threadIdx.x;
    int w = t >> 6, lane = t & 63;
    int lr = lane & 15, g = lane >> 4;

    const unsigned short* Qb = Q + (size_t)bh * LQ * DH;
    const unsigned short* Kb = K + (size_t)bh * LQ * DH;
    const unsigned short* Vb = V + (size_t)bh * LQ * DH;

    unsigned short* Ks = sK[w];
    unsigned short* Vt = sV[w];
    unsigned short* Ps = (unsigned short*)sPO[w];

    bf8_t qf[4];
#pragma unroll
    for (int nt = 0; nt < 4; ++nt) {
        int qg = min(qc * 64 + nt * 16 + lr, LQ - 1);
        qf[nt] = *(const bf8_t*)(Qb + (size_t)qg * DH + g * 8);
    }

    float m[4], l[4];
    f4_t acc[2][4];
#pragma unroll
    for (int nt = 0; nt < 4; ++nt) {
        m[nt] = -3e38f; l[nt] = 0.f;
        acc[0][nt] = (f4_t)0.f; acc[1][nt] = (f4_t)0.f;
    }

    for (int ci = 0; ci < 4; ++ci) {
        int k0 = ci * 256 + w * 64;
        if (k0 >= LQ) break;
        int kgl = min(k0 + lane, LQ - 1);
        const unsigned short* kr = Kb + (size_t)kgl * DH;
        const unsigned short* vr = Vb + (size_t)kgl * DH;
#pragma unroll
        for (int i = 0; i < 4; ++i)
            *(us8_t*)&Ks[lane * 72 + i * 8] = *(const us8_t*)(kr + i * 8);
#pragma unroll
        for (int i = 0; i < 4; ++i) {
            us8_t v8 = *(const us8_t*)(vr + i * 8);
#pragma unroll
            for (int j = 0; j < 8; ++j)
                Vt[(i * 8 + j) * 72 + lane] = v8[j];
        }
        // ---- QK^T: S^T[64k][64q] ----
        bf8_t ka[4];
#pragma unroll
        for (int mt = 0; mt < 4; ++mt)
            ka[mt] = *(const bf8_t*)&Ks[(mt * 16 + lr) * 72 + g * 8];
        f4_t st[4][4];
#pragma unroll
        for (int mt = 0; mt < 4; ++mt)
#pragma unroll
            for (int nt = 0; nt < 4; ++nt)
                st[mt][nt] = __builtin_amdgcn_mfma_f32_16x16x32_bf16(ka[mt], qf[nt], (f4_t)0.f, 0, 0, 0);
        // ---- online softmax + P write ----
#pragma unroll
        for (int nt = 0; nt < 4; ++nt) {
            float sv[4][4];
            float cm = -3e38f;
#pragma unroll
            for (int mt = 0; mt < 4; ++mt)
#pragma unroll
                for (int rr = 0; rr < 4; ++rr) {
                    bool valid = (k0 + mt * 16 + g * 4 + rr) < LQ;
                    float s = valid ? st[mt][nt][rr] : -3e38f;
                    sv[mt][rr] = s;
                    cm = fmaxf(cm, s);
                }
            cm = fmaxf(cm, __shfl_xor(cm, 16, 64));
            cm = fmaxf(cm, __shfl_xor(cm, 32, 64));
            float mn = fmaxf(m[nt], cm);
            float sc = __expf(m[nt] - mn);
            float cs = 0.f;
#pragma unroll
            for (int mt = 0; mt < 4; ++mt) {
                float pv0 = (sv[mt][0] > -1e37f) ? __expf(sv[mt][0] - mn) : 0.f;
                float pv1 = (sv[mt][1] > -1e37f) ? __expf(sv[mt][1] - mn) : 0.f;
                float pv2 = (sv[mt][2] > -1e37f) ? __expf(sv[mt][2] - mn) : 0.f;
                float pv3 = (sv[mt][3] > -1e37f) ? __expf(sv[mt][3] - mn) : 0.f;
                cs += (pv0 + pv1) + (pv2 + pv3);
                U4 pk;
                pk.u[0] = cvtpk(pv0, pv1);
                pk.u[1] = cvtpk(pv2, pv3);
                *(us4_t*)&Ps[(nt * 16 + lr) * 72 + mt * 16 + g * 4] = pk.v;
            }
            cs += __shfl_xor(cs, 16, 64);
            cs += __shfl_xor(cs, 32, 64);
            l[nt] = l[nt] * sc + cs;
            m[nt] = mn;
            acc[0][nt] *= sc;
            acc[1][nt] *= sc;
        }
        // ---- PV: O^T[32d][64q] ----
        bf8_t va[2][2];
#pragma unroll
        for (int md = 0; md < 2; ++md)
#pragma unroll
            for (int kt = 0; kt < 2; ++kt)
                va[md][kt] = *(const bf8_t*)&Vt[(md * 16 + lr) * 72 + kt * 32 + g * 8];
#pragma unroll
        for (int nt = 0; nt < 4; ++nt)
#pragma unroll
            for (int kt = 0; kt < 2; ++kt) {
                bf8_t pb = *(const bf8_t*)&Ps[(nt * 16 + lr) * 72 + kt * 32 + g * 8];
                acc[0][nt] = __builtin_amdgcn_mfma_f32_16x16x32_bf16(va[0][kt], pb, acc[0][nt], 0, 0, 0);
                acc[1][nt] = __builtin_amdgcn_mfma_f32_16x16x32_bf16(va[1][kt], pb, acc[1][nt], 0, 0, 0);
            }
    }

    // ---- wave combine ----
    if (g == 0) {
#pragma unroll
        for (int nt = 0; nt < 4; ++nt) {
            sWm[w][nt * 16 + lr] = m[nt];
            sWl[w][nt * 16 + lr] = l[nt];
        }
    }
    __syncthreads();
    float* ob = sPO[w];
#pragma unroll
    for (int nt = 0; nt < 4; ++nt) {
        int q = nt * 16 + lr;
        float M = fmaxf(fmaxf(sWm[0][q], sWm[1][q]), fmaxf(sWm[2][q], sWm[3][q]));
        float fac = __expf(m[nt] - M);
        f4_t v0 = acc[0][nt] * fac;
        f4_t v1 = acc[1][nt] * fac;
        *(f4_t*)&ob[q * 36 + g * 4] = v0;
        *(f4_t*)&ob[q * 36 + 16 + g * 4] = v1;
    }
    __syncthreads();
    {
        int q = t >> 2, d0 = (t & 3) * 8;
        int qglob = qc * 64 + q;
        if (qglob < LQ) {
            float M = fmaxf(fmaxf(sWm[0][q], sWm[1][q]), fmaxf(sWm[2][q], sWm[3][q]));
            float L = 0.f;
#pragma unroll
            for (int w2 = 0; w2 < 4; ++w2) L += sWl[w2][q] * __expf(sWm[w2][q] - M);
            float inv = 1.0f / L;
            f4_t r0 = (f4_t)0.f, r1 = (f4_t)0.f;
#pragma unroll
            for (int w2 = 0; w2 < 4; ++w2) {
                r0 += *(f4_t*)&sPO[w2][q * 36 + d0];
                r1 += *(f4_t*)&sPO[w2][q * 36 + d0 + 4];
            }
            r0 *= inv; r1 *= inv;
            U8 u;
            u.u[0] = cvtpk(r0[0], r0[1]);
            u.u[1] = cvtpk(r0[2], r0[3]);
            u.u[2] = cvtpk(r1[0], r1[1]);
            u.u[3] = cvtpk(r1[2], r1[3]);
            *(us8_t*)(O + ((size_t)(qglob * BQ + b)) * C + h * 32 + d0) = u.v;
        }
    }
}

// ---------------- launch ----------------
extern "C" void kernel_launch(void* const* d_in, const int* in_sizes, int n_in,
                              void* d_out, int out_size, void* d_ws, size_t ws_size,
                              hipStream_t stream) {
    const float* tgt      = (const float*)d_in[0];
    const float* trp      = (const float*)d_in[1];
    const float* memory   = (const float*)d_in[2];
    const float* vproj_w  = (const float*)d_in[5];  const float* vproj_b  = (const float*)d_in[6];
    const float* off_w    = (const float*)d_in[7];  const float* off_b    = (const float*)d_in[8];
    const float* aw_w     = (const float*)d_in[9];  const float* aw_b     = (const float*)d_in[10];
    const float* oproj_w  = (const float*)d_in[11]; const float* oproj_b  = (const float*)d_in[12];
    const float* ln1_g    = (const float*)d_in[13]; const float* ln1_b    = (const float*)d_in[14];
    const float* sa_in_w  = (const float*)d_in[15]; const float* sa_in_b  = (const float*)d_in[16];
    const float* sa_out_w = (const float*)d_in[17]; const float* sa_out_b = (const float*)d_in[18];
    const float* ln2_g    = (const float*)d_in[19]; const float* ln2_b    = (const float*)d_in[20];
    const float* l1_w     = (const float*)d_in[21]; const float* l1_b     = (const float*)d_in[22];
    const float* l2_w     = (const float*)d_in[23]; const float* l2_b     = (const float*)d_in[24];
    const float* ln3_g    = (const float*)d_in[25]; const float* ln3_b    = (const float*)d_in[26];
    const float* sa3_in_w = (const float*)d_in[27]; const float* sa3_in_b = (const float*)d_in[28];
    const float* sa3_out_w= (const float*)d_in[29]; const float* sa3_out_b= (const float*)d_in[30];
    const float* ln5_g    = (const float*)d_in[31]; const float* ln5_b    = (const float*)d_in[32];
    const float* l31_w    = (const float*)d_in[33]; const float* l31_b    = (const float*)d_in[34];
    const float* l32_w    = (const float*)d_in[35]; const float* l32_b    = (const float*)d_in[36];
    const float* ln33_g   = (const float*)d_in[37]; const float* ln33_b   = (const float*)d_in[38];

    float* ws = (float*)d_ws;
    float* X              = ws;                                    // 921,600 f32
    unsigned short* valueU= (unsigned short*)(ws + 921600);        // 18,248,704 bf16
    float* offaw          = ws + 10045952;                         // 1,382,400 f32 [3600][384]
    unsigned short* accU  = (unsigned short*)(ws + 11428352);      // 921,600 bf16
    unsigned short* QKVu  = (unsigned short*)(ws + 12349952);      // 2,764,800 bf16
    unsigned short* Ou    = (unsigned short*)(ws + 13732352);      // 921,600 bf16
    unsigned short* H1u   = (unsigned short*)(ws + 14193152);      // 7,372,800 bf16
    float* Y              = ws + 17879552;                         // 921,600 f32
    float* Y2             = ws + 18801152;                         // 921,600 f32
    float* T1             = ws + 19722752;                         // 921,600 f32
    unsigned short* Wbf   = (unsigned short*)(ws + 20644352);      // 2,850,816 bf16
    float* bias384        = ws + 22069760;                         // 384 f32
    unsigned short* XU    = (unsigned short*)(ws + 22070144);      // 921,600 bf16
    unsigned short* tgtU  = (unsigned short*)(ws + 22530944);      // 921,600 bf16

    const int NVROWS = BQ * LVTOT;           // 71,284 -> 1114 64-row blocks -> 140 supergroups
    dim3 blk(256);
    dim3 gTok(29, 4);
    void* nullv = nullptr;

    // ---- pre-conversions (weights + tgt) ----
    k_prep<<<(PTOT + 255) / 256, blk, 0, stream>>>(off_w, aw_w, vproj_w, oproj_w, sa_in_w, sa_out_w,
                                                   l1_w, l2_w, sa3_in_w, sa3_out_w, l31_w, l32_w,
                                                   off_b, aw_b, tgt, Wbf, bias384, tgtU);

    // ---- ca: MSDeformAttn ----
    k_vproj64<<<140 * 32, blk, 0, stream>>>(memory, Wbf + WOFF_VPROJ, vproj_b, valueU, NVROWS);
    k_mgemm<256, 256, 384, MODE_NORMAL, 1, 0, 0, 0><<<dim3(29, 6), blk, 0, stream>>>(tgtU, Wbf + WOFF_OFFAW, bias384, offaw, nullv, NTOK);
    k_sample<<<NTOK, blk, 0, stream>>>(trp, offaw, valueU, accU);
    k_mgemm<256, 256, 256, MODE_NORMAL, 1, 0, 0, 0><<<gTok, blk, 0, stream>>>(accU, Wbf + WOFF_OPROJ, oproj_b, T1, nullv, NTOK);
    k_res_ln<<<NTOK / 4, blk, 0, stream>>>(T1, nullptr, tgt, ln1_g, ln1_b, X, XU);

    // ---- sa ----
    k_mgemm<256, 256, 768, MODE_QKV, 1, 1, 0, 0><<<dim3(29, 12), blk, 0, stream>>>(XU, Wbf + WOFF_SAIN, sa_in_b, QKVu, nullv, NTOK);
    k_attn3<<<32 * NQC3, blk, 0, stream>>>(QKVu, QKVu + 921600, QKVu + 1843200, Ou);
    k_mgemm<256, 256, 256, MODE_NORMAL, 1, 0, 0, 0><<<gTok, blk, 0, stream>>>(Ou, Wbf + WOFF_SAOUT, sa_out_b, T1, nullv, NTOK);
    k_res_ln<<<NTOK / 4, blk, 0, stream>>>(T1, nullptr, X, ln2_g, ln2_b, X, XU);

    // ---- ffn ----
    k_mgemm<256, 256, 2048, MODE_RELU, 1, 1, 0, 0><<<dim3(29, 32), blk, 0, stream>>>(XU, Wbf + WOFF_L1, l1_b, H1u, nullv, NTOK);
    k_mgemm<1024, 2048, 256, MODE_NORMAL, 1, 0, 0, 1><<<4 * 64, blk, 0, stream>>>(H1u, Wbf + WOFF_L2, l2_b, Y, Y2, NTOK);
    k_res_ln<<<NTOK / 4, blk, 0, stream>>>(Y, Y2, X, ln3_g, ln3_b, X, XU);

    // ---- sa3 ----
    k_mgemm<256, 256, 768, MODE_QKV, 1, 1, 0, 0><<<dim3(29, 12), blk, 0, stream>>>(XU, Wbf + WOFF_SA3IN, sa3_in_b, QKVu, nullv, NTOK);
    k_attn3<<<32 * NQC3, blk, 0, stream>>>(QKVu, QKVu + 921600, QKVu + 1843200, Ou);
    k_mgemm<256, 256, 256, MODE_NORMAL, 1, 0, 0, 0><<<gTok, blk, 0, stream>>>(Ou, Wbf + WOFF_SA3OUT, sa3_out_b, T1, nullv, NTOK);
    k_res_ln<<<NTOK / 4, blk, 0, stream>>>(T1, nullptr, X, ln5_g, ln5_b, X, XU);

    // ---- ffn3 ----
    k_mgemm<256, 256, 2048, MODE_RELU, 1, 1, 0, 0><<<dim3(29, 32), blk, 0, stream>>>(XU, Wbf + WOFF_L31, l31_b, H1u, nullv, NTOK);
    k_mgemm<1024, 2048, 256, MODE_NORMAL, 1, 0, 0, 1><<<4 * 64, blk, 0, stream>>>(H1u, Wbf + WOFF_L32, l32_b, Y, Y2, NTOK);
    k_res_ln<<<NTOK / 4, blk, 0, stream>>>(Y, Y2, X, ln33_g, ln33_b, (float*)d_out, nullptr);
}

// Round 20
// 239.659 us; speedup vs baseline: 1.4129x; 1.0681x over previous
//
#include <hip/hip_runtime.h>
#include <math.h>

#define C 256
#define DH 32
#define NH 8
#define NL 4
#define NP 4
#define BQ 4
#define LQ 900
#define LVTOT 17821
#define DFFN 2048
#define NTOK (BQ*LQ)          // 3600 token rows, token index t = lq*B + b

typedef __attribute__((ext_vector_type(8))) short bf8_t;    // 8 bf16 (4 VGPRs)
typedef __attribute__((ext_vector_type(4))) float f4_t;     // MFMA acc
typedef __attribute__((ext_vector_type(8))) unsigned short us8_t;
typedef __attribute__((ext_vector_type(4))) unsigned short us4_t;

union U8 { us8_t v; unsigned int u[4]; };
union U4 { us4_t v; unsigned int u[2]; };

// ---------------- helpers ----------------
__device__ __forceinline__ unsigned short f2bf(float f) {
    unsigned int u = __float_as_uint(f);
    u += 0x7fffu + ((u >> 16) & 1u);   // round-to-nearest-even
    return (unsigned short)(u >> 16);
}
__device__ __forceinline__ float b2f(unsigned short u) {
    return __uint_as_float(((unsigned int)u) << 16);
}
// packed fp32x2 -> bf16x2 (RNE), 1 instruction
__device__ __forceinline__ unsigned int cvtpk(float lo, float hi) {
    unsigned int r;
    asm("v_cvt_pk_bf16_f32 %0, %1, %2" : "=v"(r) : "v"(lo), "v"(hi));
    return r;
}

// ---------------- one-time conversions: weights fp32->bf16, tgt fp32->bf16 ----------------
#define WOFF_OFFAW   0         // off_w 65536 | aw_w 32768  (fused 384x256)
#define WOFF_VPROJ   98304
#define WOFF_OPROJ   163840
#define WOFF_SAIN    229376
#define WOFF_SAOUT   425984
#define WOFF_L1      491520
#define WOFF_L2      1015808
#define WOFF_SA3IN   1540096
#define WOFF_SA3OUT  1736704
#define WOFF_L31     1802240
#define WOFF_L32     2326528
#define WTOT         2850816
#define PTOT         (WTOT + 921600)   // + tgt

__global__ void k_prep(const float* __restrict__ off_w, const float* __restrict__ aw_w,
                       const float* __restrict__ vproj_w, const float* __restrict__ oproj_w,
                       const float* __restrict__ sa_in_w, const float* __restrict__ sa_out_w,
                       const float* __restrict__ l1_w, const float* __restrict__ l2_w,
                       const float* __restrict__ sa3_in_w, const float* __restrict__ sa3_out_w,
                       const float* __restrict__ l31_w, const float* __restrict__ l32_w,
                       const float* __restrict__ off_b, const float* __restrict__ aw_b,
                       const float* __restrict__ tgt,
                       unsigned short* __restrict__ Wbf, float* __restrict__ bias384,
                       unsigned short* __restrict__ tgtU) {
    int i = blockIdx.x * 256 + threadIdx.x;
    if (i < 384) bias384[i] = (i < 256) ? off_b[i] : aw_b[i - 256];
    if (i >= PTOT) return;
    if (i >= WTOT) { int j = i - WTOT; tgtU[j] = f2bf(tgt[j]); return; }
    const float* src; int rel;
    if      (i < WOFF_VPROJ)  { if (i < 65536) { src = off_w; rel = i; } else { src = aw_w; rel = i - 65536; } }
    else if (i < WOFF_OPROJ)  { src = vproj_w;  rel = i - WOFF_VPROJ; }
    else if (i < WOFF_SAIN)   { src = oproj_w;  rel = i - WOFF_OPROJ; }
    else if (i < WOFF_SAOUT)  { src = sa_in_w;  rel = i - WOFF_SAIN; }
    else if (i < WOFF_L1)     { src = sa_out_w; rel = i - WOFF_SAOUT; }
    else if (i < WOFF_L2)     { src = l1_w;     rel = i - WOFF_L1; }
    else if (i < WOFF_SA3IN)  { src = l2_w;     rel = i - WOFF_L2; }
    else if (i < WOFF_SA3OUT) { src = sa3_in_w; rel = i - WOFF_SA3IN; }
    else if (i < WOFF_L31)    { src = sa3_out_w; rel = i - WOFF_SA3OUT; }
    else if (i < WOFF_L32)    { src = l31_w;    rel = i - WOFF_L31; }
    else                      { src = l32_w;    rel = i - WOFF_L32; }
    Wbf[i] = f2bf(src[rel]);
}

// ---------------- bf16 MFMA GEMM: Y = act(A @ W^T + b) ----------------
// A: [nrows][KS] fp32 (AB=0) or bf16 (AB=1); W: bf16. Output f32/bf16 per OB.
// Tile 128x64, 4 waves 2x2, K-step 32, DOUBLE-buffered LDS, ONE barrier/step.
// Prefetch depth 2 (named sets; depth 4 spills to scratch: R17 WRITE 37->147MB).
// XCDG=4: blk=32G+8cb+x -> rb=8G+x (4 col-tiles of a row-slab share an XCD).
// SPLITK=1: both K-halves of FFN2 in ONE dispatch (half 1 -> Y2, no bias).
enum { MODE_NORMAL = 0, MODE_RELU = 1, MODE_VALUE = 2, MODE_QKV = 3 };

#define LDP 40   // 80B row stride: frag reads 2-way (free), 16B-aligned

template<int K, int KS, int NTOT, int MODE, int AB, int OB, int XCDG, int SPLITK>
__global__ void k_mgemm(const void* __restrict__ A_, const unsigned short* __restrict__ Wbf,
                        const float* __restrict__ bias, void* __restrict__ Y_,
                        void* __restrict__ Y2_, int nrows) {
    __shared__ unsigned short Ash[2][128 * LDP];
    __shared__ unsigned short Bsh[2][64 * LDP];
    int t = threadIdx.x;
    int lane = t & 63, w = t >> 6;
    int wm = w & 1, wn = w >> 1;
    int rbx, cbx, khoff = 0;
    if (SPLITK) {
        int blk = blockIdx.x;
        rbx = (blk >> 6) * 8 + (blk & 7);
        cbx = (blk >> 3) & 3;
        int half = (blk >> 5) & 1;
        khoff = half * K;             // K = 1024, KS = 2048
        if (half) { Y_ = Y2_; bias = nullptr; }
        if (rbx * 128 >= nrows) return;
    } else if (XCDG) {
        int blk = blockIdx.x;
        rbx = (blk >> 5) * 8 + (blk & 7);
        cbx = (blk >> 3) & 3;
        if (rbx * 128 >= nrows) return;
    } else {
        rbx = blockIdx.x;
        cbx = blockIdx.y;
    }
    int r0 = rbx * 128;
    int c0 = cbx * 64;

    f4_t acc[4][2];
#pragma unroll
    for (int mt = 0; mt < 4; ++mt)
#pragma unroll
        for (int nt = 0; nt < 2; ++nt) acc[mt][nt] = (f4_t)0.f;

    int arow = t >> 1;
    int akoff = (t & 1) * 16;
    int asrc = min(r0 + arow, nrows - 1);
    const float* aptrf = (const float*)A_ + (size_t)asrc * KS + akoff + khoff;
    const unsigned short* aptrh = (const unsigned short*)A_ + (size_t)asrc * KS + akoff + khoff;
    unsigned short* adst0 = &Ash[0][arow * LDP + akoff];
    unsigned short* adst1 = &Ash[1][arow * LDP + akoff];

    int brow = t >> 2;
    int bkoff = (t & 3) * 8;
    const unsigned short* bptr = Wbf + (size_t)(c0 + brow) * KS + bkoff + khoff;
    unsigned short* bdst0 = &Bsh[0][brow * LDP + bkoff];
    unsigned short* bdst1 = &Bsh[1][brow * LDP + bkoff];

    int lr = lane & 15, kg = lane >> 4;

    float4 fA_0, fA_1, fA_2, fA_3, gA_0, gA_1, gA_2, gA_3;  // fp32 A sets (AB=0)
    us8_t hA_0, hA_1, hB_0, hB_1;                            // bf16 A sets (AB=1)
    us8_t wA, wB;

#define ISSUE_A(k0) do { \
        if (AB) { hA_0 = *(const us8_t*)(aptrh + (k0)); hA_1 = *(const us8_t*)(aptrh + (k0) + 8); } \
        else { fA_0 = *(const float4*)(aptrf + (k0)); fA_1 = *(const float4*)(aptrf + (k0) + 4); \
               fA_2 = *(const float4*)(aptrf + (k0) + 8); fA_3 = *(const float4*)(aptrf + (k0) + 12); } \
        wA = *(const us8_t*)(bptr + (k0)); } while (0)
#define ISSUE_B(k0) do { \
        if (AB) { hB_0 = *(const us8_t*)(aptrh + (k0)); hB_1 = *(const us8_t*)(aptrh + (k0) + 8); } \
        else { gA_0 = *(const float4*)(aptrf + (k0)); gA_1 = *(const float4*)(aptrf + (k0) + 4); \
               gA_2 = *(const float4*)(aptrf + (k0) + 8); gA_3 = *(const float4*)(aptrf + (k0) + 12); } \
        wB = *(const us8_t*)(bptr + (k0)); } while (0)
#define STORE_A(buf) do { \
        if (AB) { *(us8_t*)(adst##buf) = hA_0; *(us8_t*)(adst##buf + 8) = hA_1; } \
        else { U8 x, y; \
               x.u[0] = cvtpk(fA_0.x, fA_0.y); x.u[1] = cvtpk(fA_0.z, fA_0.w); \
               x.u[2] = cvtpk(fA_1.x, fA_1.y); x.u[3] = cvtpk(fA_1.z, fA_1.w); \
               y.u[0] = cvtpk(fA_2.x, fA_2.y); y.u[1] = cvtpk(fA_2.z, fA_2.w); \
               y.u[2] = cvtpk(fA_3.x, fA_3.y); y.u[3] = cvtpk(fA_3.z, fA_3.w); \
               *(us8_t*)(adst##buf) = x.v; *(us8_t*)(adst##buf + 8) = y.v; } \
        *(us8_t*)(bdst##buf) = wA; } while (0)
#define STORE_B(buf) do { \
        if (AB) { *(us8_t*)(adst##buf) = hB_0; *(us8_t*)(adst##buf + 8) = hB_1; } \
        else { U8 x, y; \
               x.u[0] = cvtpk(gA_0.x, gA_0.y); x.u[1] = cvtpk(gA_0.z, gA_0.w); \
               x.u[2] = cvtpk(gA_1.x, gA_1.y); x.u[3] = cvtpk(gA_1.z, gA_1.w); \
               y.u[0] = cvtpk(gA_2.x, gA_2.y); y.u[1] = cvtpk(gA_2.z, gA_2.w); \
               y.u[2] = cvtpk(gA_3.x, gA_3.y); y.u[3] = cvtpk(gA_3.z, gA_3.w); \
               *(us8_t*)(adst##buf) = x.v; *(us8_t*)(adst##buf + 8) = y.v; } \
        *(us8_t*)(bdst##buf) = wB; } while (0)
#define COMPUTE(buf) do { \
        bf8_t afr[4], bfr[2]; \
        _Pragma("unroll") \
        for (int mt = 0; mt < 4; ++mt) \
            afr[mt] = *(const bf8_t*)&Ash[buf][(wm * 64 + mt * 16 + lr) * LDP + kg * 8]; \
        _Pragma("unroll") \
        for (int nt = 0; nt < 2; ++nt) \
            bfr[nt] = *(const bf8_t*)&Bsh[buf][(wn * 32 + nt * 16 + lr) * LDP + kg * 8]; \
        _Pragma("unroll") \
        for (int mt = 0; mt < 4; ++mt) \
            _Pragma("unroll") \
            for (int nt = 0; nt < 2; ++nt) \
                acc[mt][nt] = __builtin_amdgcn_mfma_f32_16x16x32_bf16(afr[mt], bfr[nt], acc[mt][nt], 0, 0, 0); \
    } while (0)

    ISSUE_A(0);
#pragma unroll 1
    for (int k0 = 0; k0 < K; k0 += 64) {
        STORE_A(0);
        ISSUE_B(k0 + 32);           // K multiple of 64 -> always valid
        __syncthreads();
        COMPUTE(0);
        STORE_B(1);
        if (k0 + 64 < K) ISSUE_A(k0 + 64);
        __syncthreads();
        COMPUTE(1);
    }
#undef ISSUE_A
#undef ISSUE_B
#undef STORE_A
#undef STORE_B
#undef COMPUTE

#pragma unroll
    for (int mt = 0; mt < 4; ++mt) {
#pragma unroll
        for (int nt = 0; nt < 2; ++nt) {
            int col = c0 + wn * 32 + nt * 16 + lr;
            float b0s = bias ? bias[col] : 0.f;
#pragma unroll
            for (int rr = 0; rr < 4; ++rr) {
                int row = r0 + wm * 64 + mt * 16 + kg * 4 + rr;
                if (row >= nrows) continue;
                float v = acc[mt][nt][rr] + b0s;
                size_t idx;
                if (MODE == MODE_NORMAL) {
                    idx = (size_t)row * NTOT + col;
                } else if (MODE == MODE_RELU) {
                    v = fmaxf(v, 0.f);
                    idx = (size_t)row * NTOT + col;
                } else if (MODE == MODE_VALUE) {
                    int lv = row >> 2, b = row & 3;
                    int h = col >> 5, d = col & 31;
                    idx = (((size_t)b * NH + h) * LVTOT + lv) * DH + d;
                } else { // MODE_QKV
                    int lq = row >> 2, b = row & 3;
                    int part = col >> 8, cc = col & 255;
                    int h = cc >> 5, d = cc & 31;
                    if (part == 0) v *= 0.17677669529663687f;  // 1/sqrt(32)
                    idx = (size_t)part * (BQ * NH * LQ * DH) + (((size_t)b * NH + h) * LQ + lq) * DH + d;
                }
                if (OB) ((unsigned short*)Y_)[idx] = f2bf(v);
                else    ((float*)Y_)[idx] = v;
            }
        }
    }
}

// ---------------- vproj-dedicated GEMM: 64x64 tile (R19: 59->53 us, occ 63%) ----------------
__global__ void k_vproj64(const float* __restrict__ A, const unsigned short* __restrict__ Wbf,
                          const float* __restrict__ bias, unsigned short* __restrict__ Y,
                          int nrows) {
    __shared__ unsigned short Ash[2][64 * LDP];
    __shared__ unsigned short Bsh[2][64 * LDP];
    int t = threadIdx.x;
    int lane = t & 63, w = t >> 6;
    int wm = w & 1, wn = w >> 1;
    int blk = blockIdx.x;
    int rbx = (blk >> 5) * 8 + (blk & 7);
    int cbx = (blk >> 3) & 3;
    if (rbx * 64 >= nrows) return;
    int r0 = rbx * 64;
    int c0 = cbx * 64;

    f4_t acc[2][2];
#pragma unroll
    for (int mt = 0; mt < 2; ++mt)
#pragma unroll
        for (int nt = 0; nt < 2; ++nt) acc[mt][nt] = (f4_t)0.f;

    int arow = t >> 2;                 // 0..63
    int akoff = (t & 3) * 8;           // 0,8,16,24
    int asrc = min(r0 + arow, nrows - 1);
    const float* aptrf = A + (size_t)asrc * 256 + akoff;
    unsigned short* adst0 = &Ash[0][arow * LDP + akoff];
    unsigned short* adst1 = &Ash[1][arow * LDP + akoff];

    const unsigned short* bptr = Wbf + (size_t)(c0 + arow) * 256 + akoff;
    unsigned short* bdst0 = &Bsh[0][arow * LDP + akoff];
    unsigned short* bdst1 = &Bsh[1][arow * LDP + akoff];

    int lr = lane & 15, kg = lane >> 4;

    float4 fA_0, fA_1, gA_0, gA_1;
    us8_t wA, wB;

#define ISSUE_A(k0) do { fA_0 = *(const float4*)(aptrf + (k0)); fA_1 = *(const float4*)(aptrf + (k0) + 4); \
                         wA = *(const us8_t*)(bptr + (k0)); } while (0)
#define ISSUE_B(k0) do { gA_0 = *(const float4*)(aptrf + (k0)); gA_1 = *(const float4*)(aptrf + (k0) + 4); \
                         wB = *(const us8_t*)(bptr + (k0)); } while (0)
#define STORE_A(buf) do { U4 x0, x1; \
        x0.u[0] = cvtpk(fA_0.x, fA_0.y); x0.u[1] = cvtpk(fA_0.z, fA_0.w); \
        x1.u[0] = cvtpk(fA_1.x, fA_1.y); x1.u[1] = cvtpk(fA_1.z, fA_1.w); \
        *(us4_t*)(adst##buf) = x0.v; *(us4_t*)(adst##buf + 4) = x1.v; \
        *(us8_t*)(bdst##buf) = wA; } while (0)
#define STORE_B(buf) do { U4 x0, x1; \
        x0.u[0] = cvtpk(gA_0.x, gA_0.y); x0.u[1] = cvtpk(gA_0.z, gA_0.w); \
        x1.u[0] = cvtpk(gA_1.x, gA_1.y); x1.u[1] = cvtpk(gA_1.z, gA_1.w); \
        *(us4_t*)(adst##buf) = x0.v; *(us4_t*)(adst##buf + 4) = x1.v; \
        *(us8_t*)(bdst##buf) = wB; } while (0)
#define COMPUTE(buf) do { \
        bf8_t afr[2], bfr[2]; \
        _Pragma("unroll") \
        for (int mt = 0; mt < 2; ++mt) \
            afr[mt] = *(const bf8_t*)&Ash[buf][(wm * 32 + mt * 16 + lr) * LDP + kg * 8]; \
        _Pragma("unroll") \
        for (int nt = 0; nt < 2; ++nt) \
            bfr[nt] = *(const bf8_t*)&Bsh[buf][(wn * 32 + nt * 16 + lr) * LDP + kg * 8]; \
        _Pragma("unroll") \
        for (int mt = 0; mt < 2; ++mt) \
            _Pragma("unroll") \
            for (int nt = 0; nt < 2; ++nt) \
                acc[mt][nt] = __builtin_amdgcn_mfma_f32_16x16x32_bf16(afr[mt], bfr[nt], acc[mt][nt], 0, 0, 0); \
    } while (0)

    ISSUE_A(0);
#pragma unroll 1
    for (int k0 = 0; k0 < 256; k0 += 64) {
        STORE_A(0);
        ISSUE_B(k0 + 32);
        __syncthreads();
        COMPUTE(0);
        STORE_B(1);
        if (k0 + 64 < 256) ISSUE_A(k0 + 64);
        __syncthreads();
        COMPUTE(1);
    }
#undef ISSUE_A
#undef ISSUE_B
#undef STORE_A
#undef STORE_B
#undef COMPUTE

#pragma unroll
    for (int mt = 0; mt < 2; ++mt) {
#pragma unroll
        for (int nt = 0; nt < 2; ++nt) {
            int col = c0 + wn * 32 + nt * 16 + lr;
            float b0s = bias[col];
#pragma unroll
            for (int rr = 0; rr < 4; ++rr) {
                int row = r0 + wm * 32 + mt * 16 + kg * 4 + rr;
                if (row >= nrows) continue;
                float v = acc[mt][nt][rr] + b0s;
                int lv = row >> 2, b = row & 3;
                int h = col >> 5, d = col & 31;
                Y[(((size_t)b * NH + h) * LVTOT + lv) * DH + d] = f2bf(v);
            }
        }
    }
}

// ---------------- deformable sampling ----------------
__global__ void k_sample(const float* __restrict__ trp, const float* __restrict__ offaw,
                         const unsigned short* __restrict__ value,
                         unsigned short* __restrict__ accU) {
    int r = blockIdx.x;
    int b = r & 3;
    int t = threadIdx.x;
    int h = t >> 5;
    int lane32 = t & 31;
    int l = lane32 >> 3;               // level-group
    int dl = lane32 & 7;               // d-quad: d0 = dl*4
    int d0 = dl * 4;
    const unsigned short* vb = value + ((size_t)b * NH + h) * (size_t)LVTOT * DH;

    const float* lg = offaw + (size_t)r * 384 + 256 + h * 16;
    float e0,e1,e2,e3,e4,e5,e6,e7,e8,e9,e10,e11,e12,e13,e14,e15;
    {
        float4 q0 = *(const float4*)(lg);
        float4 q1 = *(const float4*)(lg + 4);
        float4 q2 = *(const float4*)(lg + 8);
        float4 q3 = *(const float4*)(lg + 12);
        float mx = fmaxf(fmaxf(fmaxf(q0.x,q0.y),fmaxf(q0.z,q0.w)),
                   fmaxf(fmaxf(fmaxf(q1.x,q1.y),fmaxf(q1.z,q1.w)),
                   fmaxf(fmaxf(fmaxf(q2.x,q2.y),fmaxf(q2.z,q2.w)),
                         fmaxf(fmaxf(q3.x,q3.y),fmaxf(q3.z,q3.w)))));
        e0=__expf(q0.x-mx); e1=__expf(q0.y-mx); e2=__expf(q0.z-mx); e3=__expf(q0.w-mx);
        e4=__expf(q1.x-mx); e5=__expf(q1.y-mx); e6=__expf(q1.z-mx); e7=__expf(q1.w-mx);
        e8=__expf(q2.x-mx); e9=__expf(q2.y-mx); e10=__expf(q2.z-mx); e11=__expf(q2.w-mx);
        e12=__expf(q3.x-mx); e13=__expf(q3.y-mx); e14=__expf(q3.z-mx); e15=__expf(q3.w-mx);
    }
    float ssum = ((e0+e1)+(e2+e3)) + ((e4+e5)+(e6+e7)) + ((e8+e9)+(e10+e11)) + ((e12+e13)+(e14+e15));
    float sinv = 1.0f / ssum;
    float w0 = (l==0) ? e0 : (l==1) ? e4 : (l==2) ? e8  : e12;
    float w1 = (l==0) ? e1 : (l==1) ? e5 : (l==2) ? e9  : e13;
    float w2 = (l==0) ? e2 : (l==1) ? e6 : (l==2) ? e10 : e14;
    float w3 = (l==0) ? e3 : (l==1) ? e7 : (l==2) ? e11 : e15;
    w0 *= sinv; w1 *= sinv; w2 *= sinv; w3 *= sinv;

    int Hl = (l==0) ? 100 : (l==1) ? 50 : (l==2) ? 25 : 13;
    int Wl = (l==0) ? 134 : (l==1) ? 67 : (l==2) ? 34 : 17;
    int s  = (l==0) ? 0 : (l==1) ? 13400 : (l==2) ? 16750 : 17600;
    float fW = (float)Wl, fH = (float)Hl;

    float rx = trp[((size_t)r * NL + l) * 2 + 0];
    float ry = trp[((size_t)r * NL + l) * 2 + 1];
    const float* offr = offaw + (size_t)r * 384 + h * 32 + l * 8;

    float o0 = 0.f, o1 = 0.f, o2 = 0.f, o3 = 0.f;
#pragma unroll
    for (int p = 0; p < 4; ++p) {
        float ox = offr[p * 2 + 0];
        float oy = offr[p * 2 + 1];
        float wq = (p==0) ? w0 : (p==1) ? w1 : (p==2) ? w2 : w3;
        float x = (rx + ox / fW) * fW - 0.5f;
        float y = (ry + oy / fH) * fH - 0.5f;
        float x0 = floorf(x), y0 = floorf(y);
#pragma unroll
        for (int dy = 0; dy < 2; ++dy) {
#pragma unroll
            for (int dx = 0; dx < 2; ++dx) {
                float xi = x0 + dx, yi = y0 + dy;
                float wgt = (1.0f - fabsf(x - xi)) * (1.0f - fabsf(y - yi));
                bool valid = (xi >= 0.f) && (xi < fW) && (yi >= 0.f) && (yi < fH);
                int xic = min(max((int)xi, 0), Wl - 1);
                int yic = min(max((int)yi, 0), Hl - 1);
                float cw = (valid ? wgt : 0.f) * wq;
                us4_t v4 = *(const us4_t*)&vb[((size_t)(s + yic * Wl + xic)) * DH + d0];
                o0 += cw * b2f(v4[0]);
                o1 += cw * b2f(v4[1]);
                o2 += cw * b2f(v4[2]);
                o3 += cw * b2f(v4[3]);
            }
        }
    }
    o0 += __shfl_xor(o0, 8, 32); o0 += __shfl_xor(o0, 16, 32);
    o1 += __shfl_xor(o1, 8, 32); o1 += __shfl_xor(o1, 16, 32);
    o2 += __shfl_xor(o2, 8, 32); o2 += __shfl_xor(o2, 16, 32);
    o3 += __shfl_xor(o3, 8, 32); o3 += __shfl_xor(o3, 16, 32);
    if (l == 0) {
        U4 u;
        u.u[0] = cvtpk(o0, o1);
        u.u[1] = cvtpk(o2, o3);
        *(us4_t*)&accU[(size_t)r * C + h * 32 + d0] = u.v;
    }
}

// ---------------- residual + LN: wave-per-row; dual f32 + bf16 output ----------------
__global__ void k_res_ln(const float* __restrict__ Y0, const float* __restrict__ Y1,
                         const float* __restrict__ Xres, const float* __restrict__ g,
                         const float* __restrict__ be, float* __restrict__ out,
                         unsigned short* __restrict__ outU) {
    int t = threadIdx.x, wv = t >> 6, lane = t & 63;
    int r = blockIdx.x * 4 + wv;
    float4 v = ((const float4*)(Y0 + (size_t)r * C))[lane];
    float4 x = ((const float4*)(Xres + (size_t)r * C))[lane];
    v.x += x.x; v.y += x.y; v.z += x.z; v.w += x.w;
    if (Y1) {
        float4 y1 = ((const float4*)(Y1 + (size_t)r * C))[lane];
        v.x += y1.x; v.y += y1.y; v.z += y1.z; v.w += y1.w;
    }
    float s = (v.x + v.y) + (v.z + v.w);
#pragma unroll
    for (int o = 32; o > 0; o >>= 1) s += __shfl_xor(s, o, 64);
    float mean = s * (1.0f / C);
    float4 dv = make_float4(v.x - mean, v.y - mean, v.z - mean, v.w - mean);
    float q = (dv.x * dv.x + dv.y * dv.y) + (dv.z * dv.z + dv.w * dv.w);
#pragma unroll
    for (int o = 32; o > 0; o >>= 1) q += __shfl_xor(q, o, 64);
    float rstd = rsqrtf(q * (1.0f / C) + 1e-5f);
    float4 g4 = ((const float4*)g)[lane];
    float4 b4 = ((const float4*)be)[lane];
    float4 o4 = make_float4(dv.x * rstd * g4.x + b4.x, dv.y * rstd * g4.y + b4.y,
                            dv.z * rstd * g4.z + b4.z, dv.w * rstd * g4.w + b4.w);
    ((float4*)(out + (size_t)r * C))[lane] = o4;
    if (outU) {
        U4 u;
        u.u[0] = cvtpk(o4.x, o4.y);
        u.u[1] = cvtpk(o4.z, o4.w);
        *(us4_t*)(outU + (size_t)r * C + lane * 4) = u.v;
    }
}

// ---------------- MFMA flash attention (bf16 Q/K/V/O) ----------------
// LDS slimmed: P overlays each wave's K region (dead after QK^T frag loads);
// final O-combine buffer overlays the same region after the loop. 94->57 KB
// -> 2 blocks/CU (launch_bounds(256,2)) for 2x resident waves.
#define NQC3 15   // ceil(900/64)

__global__ __launch_bounds__(256, 2)
void k_attn3(const unsigned short* __restrict__ Q, const unsigned short* __restrict__ K,
             const unsigned short* __restrict__ V, unsigned short* __restrict__ O) {
    __shared__ unsigned short sK[4][64 * 72];   // K rows [key][d]; P overlays; Obuf overlays after loop
    __shared__ unsigned short sV[4][32 * 72];   // V^T [d][key]
    __shared__ float sWm[4][64], sWl[4][64];

    int blk = blockIdx.x;
    int bh = blk & 31;                 // XCD locality
    int qc = blk >> 5;
    int b = bh >> 3, h = bh & 7;
    int t = threadIdx.x;
    int w = t >> 6, lane = t & 63;
    int lr = lane & 15, g = lane >> 4;

    const unsigned short* Qb = Q + (size_t)bh * LQ * DH;
    const unsigned short* Kb = K + (size_t)bh * LQ * DH;
    const unsigned short* Vb = V + (size_t)bh * LQ * DH;

    unsigned short* Ks = sK[w];
    unsigned short* Vt = sV[w];
    unsigned short* Ps = sK[w];        // P overlays K (wave-private, program-ordered)

    bf8_t qf[4];
#pragma unroll
    for (int nt = 0; nt < 4; ++nt) {
        int qg = min(qc * 64 + nt * 16 + lr, LQ - 1);
        qf[nt] = *(const bf8_t*)(Qb + (size_t)qg * DH + g * 8);
    }

    float m[4], l[4];
    f4_t acc[2][4];
#pragma unroll
    for (int nt = 0; nt < 4; ++nt) {
        m[nt] = -3e38f; l[nt] = 0.f;
        acc[0][nt] = (f4_t)0.f; acc[1][nt] = (f4_t)0.f;
    }

    for (int ci = 0; ci < 4; ++ci) {
        int k0 = ci * 256 + w * 64;
        if (k0 >= LQ) break;
        int kgl = min(k0 + lane, LQ - 1);
        const unsigned short* kr = Kb + (size_t)kgl * DH;
        const unsigned short* vr = Vb + (size_t)kgl * DH;
#pragma unroll
        for (int i = 0; i < 4; ++i)
            *(us8_t*)&Ks[lane * 72 + i * 8] = *(const us8_t*)(kr + i * 8);
#pragma unroll
        for (int i = 0; i < 4; ++i) {
            us8_t v8 = *(const us8_t*)(vr + i * 8);
#pragma unroll
            for (int j = 0; j < 8; ++j)
                Vt[(i * 8 + j) * 72 + lane] = v8[j];
        }
        // ---- QK^T: S^T[64k][64q] ---- (K frags to registers first; Ks dead after)
        bf8_t ka[4];
#pragma unroll
        for (int mt = 0; mt < 4; ++mt)
            ka[mt] = *(const bf8_t*)&Ks[(mt * 16 + lr) * 72 + g * 8];
        f4_t st[4][4];
#pragma unroll
        for (int mt = 0; mt < 4; ++mt)
#pragma unroll
            for (int nt = 0; nt < 4; ++nt)
                st[mt][nt] = __builtin_amdgcn_mfma_f32_16x16x32_bf16(ka[mt], qf[nt], (f4_t)0.f, 0, 0, 0);
        // ---- online softmax + P write (into Ks region) ----
#pragma unroll
        for (int nt = 0; nt < 4; ++nt) {
            float sv[4][4];
            float cm = -3e38f;
#pragma unroll
            for (int mt = 0; mt < 4; ++mt)
#pragma unroll
                for (int rr = 0; rr < 4; ++rr) {
                    bool valid = (k0 + mt * 16 + g * 4 + rr) < LQ;
                    float s = valid ? st[mt][nt][rr] : -3e38f;
                    sv[mt][rr] = s;
                    cm = fmaxf(cm, s);
                }
            cm = fmaxf(cm, __shfl_xor(cm, 16, 64));
            cm = fmaxf(cm, __shfl_xor(cm, 32, 64));
            float mn = fmaxf(m[nt], cm);
            float sc = __expf(m[nt] - mn);
            float cs = 0.f;
#pragma unroll
            for (int mt = 0; mt < 4; ++mt) {
                float pv0 = (sv[mt][0] > -1e37f) ? __expf(sv[mt][0] - mn) : 0.f;
                float pv1 = (sv[mt][1] > -1e37f) ? __expf(sv[mt][1] - mn) : 0.f;
                float pv2 = (sv[mt][2] > -1e37f) ? __expf(sv[mt][2] - mn) : 0.f;
                float pv3 = (sv[mt][3] > -1e37f) ? __expf(sv[mt][3] - mn) : 0.f;
                cs += (pv0 + pv1) + (pv2 + pv3);
                U4 pk;
                pk.u[0] = cvtpk(pv0, pv1);
                pk.u[1] = cvtpk(pv2, pv3);
                *(us4_t*)&Ps[(nt * 16 + lr) * 72 + mt * 16 + g * 4] = pk.v;
            }
            cs += __shfl_xor(cs, 16, 64);
            cs += __shfl_xor(cs, 32, 64);
            l[nt] = l[nt] * sc + cs;
            m[nt] = mn;
            acc[0][nt] *= sc;
            acc[1][nt] *= sc;
        }
        // ---- PV: O^T[32d][64q] ----
        bf8_t va[2][2];
#pragma unroll
        for (int md = 0; md < 2; ++md)
#pragma unroll
            for (int kt = 0; kt < 2; ++kt)
                va[md][kt] = *(const bf8_t*)&Vt[(md * 16 + lr) * 72 + kt * 32 + g * 8];
#pragma unroll
        for (int nt = 0; nt < 4; ++nt)
#pragma unroll
            for (int kt = 0; kt < 2; ++kt) {
                bf8_t pb = *(const bf8_t*)&Ps[(nt * 16 + lr) * 72 + kt * 32 + g * 8];
                acc[0][nt] = __builtin_amdgcn_mfma_f32_16x16x32_bf16(va[0][kt], pb, acc[0][nt], 0, 0, 0);
                acc[1][nt] = __builtin_amdgcn_mfma_f32_16x16x32_bf16(va[1][kt], pb, acc[1][nt], 0, 0, 0);
            }
    }

    // ---- wave combine (Obuf overlays sK[w], 64q x 36d f32 = 9216 B fits exactly) ----
    if (g == 0) {
#pragma unroll
        for (int nt = 0; nt < 4; ++nt) {
            sWm[w][nt * 16 + lr] = m[nt];
            sWl[w][nt * 16 + lr] = l[nt];
        }
    }
    __syncthreads();
    float* ob = (float*)sK[w];
#pragma unroll
    for (int nt = 0; nt < 4; ++nt) {
        int q = nt * 16 + lr;
        float M = fmaxf(fmaxf(sWm[0][q], sWm[1][q]), fmaxf(sWm[2][q], sWm[3][q]));
        float fac = __expf(m[nt] - M);
        f4_t v0 = acc[0][nt] * fac;
        f4_t v1 = acc[1][nt] * fac;
        *(f4_t*)&ob[q * 36 + g * 4] = v0;
        *(f4_t*)&ob[q * 36 + 16 + g * 4] = v1;
    }
    __syncthreads();
    {
        int q = t >> 2, d0 = (t & 3) * 8;
        int qglob = qc * 64 + q;
        if (qglob < LQ) {
            float M = fmaxf(fmaxf(sWm[0][q], sWm[1][q]), fmaxf(sWm[2][q], sWm[3][q]));
            float L = 0.f;
#pragma unroll
            for (int w2 = 0; w2 < 4; ++w2) L += sWl[w2][q] * __expf(sWm[w2][q] - M);
            float inv = 1.0f / L;
            f4_t r0 = (f4_t)0.f, r1 = (f4_t)0.f;
#pragma unroll
            for (int w2 = 0; w2 < 4; ++w2) {
                const float* obw = (const float*)sK[w2];
                r0 += *(const f4_t*)&obw[q * 36 + d0];
                r1 += *(const f4_t*)&obw[q * 36 + d0 + 4];
            }
            r0 *= inv; r1 *= inv;
            U8 u;
            u.u[0] = cvtpk(r0[0], r0[1]);
            u.u[1] = cvtpk(r0[2], r0[3]);
            u.u[2] = cvtpk(r1[0], r1[1]);
            u.u[3] = cvtpk(r1[2], r1[3]);
            *(us8_t*)(O + ((size_t)(qglob * BQ + b)) * C + h * 32 + d0) = u.v;
        }
    }
}

// ---------------- launch ----------------
extern "C" void kernel_launch(void* const* d_in, const int* in_sizes, int n_in,
                              void* d_out, int out_size, void* d_ws, size_t ws_size,
                              hipStream_t stream) {
    const float* tgt      = (const float*)d_in[0];
    const float* trp      = (const float*)d_in[1];
    const float* memory   = (const float*)d_in[2];
    const float* vproj_w  = (const float*)d_in[5];  const float* vproj_b  = (const float*)d_in[6];
    const float* off_w    = (const float*)d_in[7];  const float* off_b    = (const float*)d_in[8];
    const float* aw_w     = (const float*)d_in[9];  const float* aw_b     = (const float*)d_in[10];
    const float* oproj_w  = (const float*)d_in[11]; const float* oproj_b  = (const float*)d_in[12];
    const float* ln1_g    = (const float*)d_in[13]; const float* ln1_b    = (const float*)d_in[14];
    const float* sa_in_w  = (const float*)d_in[15]; const float* sa_in_b  = (const float*)d_in[16];
    const float* sa_out_w = (const float*)d_in[17]; const float* sa_out_b = (const float*)d_in[18];
    const float* ln2_g    = (const float*)d_in[19]; const float* ln2_b    = (const float*)d_in[20];
    const float* l1_w     = (const float*)d_in[21]; const float* l1_b     = (const float*)d_in[22];
    const float* l2_w     = (const float*)d_in[23]; const float* l2_b     = (const float*)d_in[24];
    const float* ln3_g    = (const float*)d_in[25]; const float* ln3_b    = (const float*)d_in[26];
    const float* sa3_in_w = (const float*)d_in[27]; const float* sa3_in_b = (const float*)d_in[28];
    const float* sa3_out_w= (const float*)d_in[29]; const float* sa3_out_b= (const float*)d_in[30];
    const float* ln5_g    = (const float*)d_in[31]; const float* ln5_b    = (const float*)d_in[32];
    const float* l31_w    = (const float*)d_in[33]; const float* l31_b    = (const float*)d_in[34];
    const float* l32_w    = (const float*)d_in[35]; const float* l32_b    = (const float*)d_in[36];
    const float* ln33_g   = (const float*)d_in[37]; const float* ln33_b   = (const float*)d_in[38];

    float* ws = (float*)d_ws;
    float* X              = ws;                                    // 921,600 f32
    unsigned short* valueU= (unsigned short*)(ws + 921600);        // 18,248,704 bf16
    float* offaw          = ws + 10045952;                         // 1,382,400 f32 [3600][384]
    unsigned short* accU  = (unsigned short*)(ws + 11428352);      // 921,600 bf16
    unsigned short* QKVu  = (unsigned short*)(ws + 12349952);      // 2,764,800 bf16
    unsigned short* Ou    = (unsigned short*)(ws + 13732352);      // 921,600 bf16
    unsigned short* H1u   = (unsigned short*)(ws + 14193152);      // 7,372,800 bf16
    float* Y              = ws + 17879552;                         // 921,600 f32
    float* Y2             = ws + 18801152;                         // 921,600 f32
    float* T1             = ws + 19722752;                         // 921,600 f32
    unsigned short* Wbf   = (unsigned short*)(ws + 20644352);      // 2,850,816 bf16
    float* bias384        = ws + 22069760;                         // 384 f32
    unsigned short* XU    = (unsigned short*)(ws + 22070144);      // 921,600 bf16
    unsigned short* tgtU  = (unsigned short*)(ws + 22530944);      // 921,600 bf16

    const int NVROWS = BQ * LVTOT;           // 71,284 -> 1114 64-row blocks -> 140 supergroups
    dim3 blk(256);
    dim3 gTok(29, 4);
    void* nullv = nullptr;

    // ---- pre-conversions (weights + tgt) ----
    k_prep<<<(PTOT + 255) / 256, blk, 0, stream>>>(off_w, aw_w, vproj_w, oproj_w, sa_in_w, sa_out_w,
                                                   l1_w, l2_w, sa3_in_w, sa3_out_w, l31_w, l32_w,
                                                   off_b, aw_b, tgt, Wbf, bias384, tgtU);

    // ---- ca: MSDeformAttn ----
    k_vproj64<<<140 * 32, blk, 0, stream>>>(memory, Wbf + WOFF_VPROJ, vproj_b, valueU, NVROWS);
    k_mgemm<256, 256, 384, MODE_NORMAL, 1, 0, 0, 0><<<dim3(29, 6), blk, 0, stream>>>(tgtU, Wbf + WOFF_OFFAW, bias384, offaw, nullv, NTOK);
    k_sample<<<NTOK, blk, 0, stream>>>(trp, offaw, valueU, accU);
    k_mgemm<256, 256, 256, MODE_NORMAL, 1, 0, 0, 0><<<gTok, blk, 0, stream>>>(accU, Wbf + WOFF_OPROJ, oproj_b, T1, nullv, NTOK);
    k_res_ln<<<NTOK / 4, blk, 0, stream>>>(T1, nullptr, tgt, ln1_g, ln1_b, X, XU);

    // ---- sa ----
    k_mgemm<256, 256, 768, MODE_QKV, 1, 1, 0, 0><<<dim3(29, 12), blk, 0, stream>>>(XU, Wbf + WOFF_SAIN, sa_in_b, QKVu, nullv, NTOK);
    k_attn3<<<32 * NQC3, blk, 0, stream>>>(QKVu, QKVu + 921600, QKVu + 1843200, Ou);
    k_mgemm<256, 256, 256, MODE_NORMAL, 1, 0, 0, 0><<<gTok, blk, 0, stream>>>(Ou, Wbf + WOFF_SAOUT, sa_out_b, T1, nullv, NTOK);
    k_res_ln<<<NTOK / 4, blk, 0, stream>>>(T1, nullptr, X, ln2_g, ln2_b, X, XU);

    // ---- ffn ----
    k_mgemm<256, 256, 2048, MODE_RELU, 1, 1, 0, 0><<<dim3(29, 32), blk, 0, stream>>>(XU, Wbf + WOFF_L1, l1_b, H1u, nullv, NTOK);
    k_mgemm<1024, 2048, 256, MODE_NORMAL, 1, 0, 0, 1><<<4 * 64, blk, 0, stream>>>(H1u, Wbf + WOFF_L2, l2_b, Y, Y2, NTOK);
    k_res_ln<<<NTOK / 4, blk, 0, stream>>>(Y, Y2, X, ln3_g, ln3_b, X, XU);

    // ---- sa3 ----
    k_mgemm<256, 256, 768, MODE_QKV, 1, 1, 0, 0><<<dim3(29, 12), blk, 0, stream>>>(XU, Wbf + WOFF_SA3IN, sa3_in_b, QKVu, nullv, NTOK);
    k_attn3<<<32 * NQC3, blk, 0, stream>>>(QKVu, QKVu + 921600, QKVu + 1843200, Ou);
    k_mgemm<256, 256, 256, MODE_NORMAL, 1, 0, 0, 0><<<gTok, blk, 0, stream>>>(Ou, Wbf + WOFF_SA3OUT, sa_out_b == sa3_out_b ? sa_out_b : sa3_out_b, T1, nullv, NTOK);
    k_res_ln<<<NTOK / 4, blk, 0, stream>>>(T1, nullptr, X, ln5_g, ln5_b, X, XU);

    // ---- ffn3 ----
    k_mgemm<256, 256, 2048, MODE_RELU, 1, 1, 0, 0><<<dim3(29, 32), blk, 0, stream>>>(XU, Wbf + WOFF_L31, l31_b, H1u, nullv, NTOK);
    k_mgemm<1024, 2048, 256, MODE_NORMAL, 1, 0, 0, 1><<<4 * 64, blk, 0, stream>>>(H1u, Wbf + WOFF_L32, l32_b, Y, Y2, NTOK);
    k_res_ln<<<NTOK / 4, blk, 0, stream>>>(Y, Y2, X, ln33_g, ln33_b, (float*)d_out, nullptr);
}

// Round 21
// 239.615 us; speedup vs baseline: 1.4132x; 1.0002x over previous
//
#include <hip/hip_runtime.h>
#include <math.h>

#define C 256
#define DH 32
#define NH 8
#define NL 4
#define NP 4
#define BQ 4
#define LQ 900
#define LVTOT 17821
#define DFFN 2048
#define NTOK (BQ*LQ)          // 3600 token rows, token index t = lq*B + b

typedef __attribute__((ext_vector_type(8))) short bf8_t;    // 8 bf16 (4 VGPRs)
typedef __attribute__((ext_vector_type(4))) float f4_t;     // MFMA acc
typedef __attribute__((ext_vector_type(8))) unsigned short us8_t;
typedef __attribute__((ext_vector_type(4))) unsigned short us4_t;

union U8 { us8_t v; unsigned int u[4]; };
union U4 { us4_t v; unsigned int u[2]; };

// ---------------- helpers ----------------
__device__ __forceinline__ unsigned short f2bf(float f) {
    unsigned int u = __float_as_uint(f);
    u += 0x7fffu + ((u >> 16) & 1u);   // round-to-nearest-even
    return (unsigned short)(u >> 16);
}
__device__ __forceinline__ float b2f(unsigned short u) {
    return __uint_as_float(((unsigned int)u) << 16);
}
// packed fp32x2 -> bf16x2 (RNE), 1 instruction
__device__ __forceinline__ unsigned int cvtpk(float lo, float hi) {
    unsigned int r;
    asm("v_cvt_pk_bf16_f32 %0, %1, %2" : "=v"(r) : "v"(lo), "v"(hi));
    return r;
}

// ---------------- one-time conversions: weights fp32->bf16, tgt fp32->bf16 ----------------
#define WOFF_OFFAW   0         // off_w 65536 | aw_w 32768  (fused 384x256)
#define WOFF_VPROJ   98304
#define WOFF_OPROJ   163840
#define WOFF_SAIN    229376
#define WOFF_SAOUT   425984
#define WOFF_L1      491520
#define WOFF_L2      1015808
#define WOFF_SA3IN   1540096
#define WOFF_SA3OUT  1736704
#define WOFF_L31     1802240
#define WOFF_L32     2326528
#define WTOT         2850816
#define PTOT         (WTOT + 921600)   // + tgt

__global__ void k_prep(const float* __restrict__ off_w, const float* __restrict__ aw_w,
                       const float* __restrict__ vproj_w, const float* __restrict__ oproj_w,
                       const float* __restrict__ sa_in_w, const float* __restrict__ sa_out_w,
                       const float* __restrict__ l1_w, const float* __restrict__ l2_w,
                       const float* __restrict__ sa3_in_w, const float* __restrict__ sa3_out_w,
                       const float* __restrict__ l31_w, const float* __restrict__ l32_w,
                       const float* __restrict__ off_b, const float* __restrict__ aw_b,
                       const float* __restrict__ tgt,
                       unsigned short* __restrict__ Wbf, float* __restrict__ bias384,
                       unsigned short* __restrict__ tgtU) {
    int i = blockIdx.x * 256 + threadIdx.x;
    if (i < 384) bias384[i] = (i < 256) ? off_b[i] : aw_b[i - 256];
    if (i >= PTOT) return;
    if (i >= WTOT) { int j = i - WTOT; tgtU[j] = f2bf(tgt[j]); return; }
    const float* src; int rel;
    if      (i < WOFF_VPROJ)  { if (i < 65536) { src = off_w; rel = i; } else { src = aw_w; rel = i - 65536; } }
    else if (i < WOFF_OPROJ)  { src = vproj_w;  rel = i - WOFF_VPROJ; }
    else if (i < WOFF_SAIN)   { src = oproj_w;  rel = i - WOFF_OPROJ; }
    else if (i < WOFF_SAOUT)  { src = sa_in_w;  rel = i - WOFF_SAIN; }
    else if (i < WOFF_L1)     { src = sa_out_w; rel = i - WOFF_SAOUT; }
    else if (i < WOFF_L2)     { src = l1_w;     rel = i - WOFF_L1; }
    else if (i < WOFF_SA3IN)  { src = l2_w;     rel = i - WOFF_L2; }
    else if (i < WOFF_SA3OUT) { src = sa3_in_w; rel = i - WOFF_SA3IN; }
    else if (i < WOFF_L31)    { src = sa3_out_w; rel = i - WOFF_SA3OUT; }
    else if (i < WOFF_L32)    { src = l31_w;    rel = i - WOFF_L31; }
    else                      { src = l32_w;    rel = i - WOFF_L32; }
    Wbf[i] = f2bf(src[rel]);
}

// ---------------- bf16 MFMA GEMM: Y = act(A @ W^T + b) ----------------
// A: [nrows][KS] fp32 (AB=0) or bf16 (AB=1); W: bf16. Output f32/bf16 per OB.
// Tile 128x64, 4 waves 2x2, K-step 32, DOUBLE-buffered LDS, ONE barrier/step.
// Prefetch depth 2 (named sets; depth 4 spills to scratch: R17 WRITE 37->147MB).
// XCDG=4: blk=32G+8cb+x -> rb=8G+x (4 col-tiles of a row-slab share an XCD).
// SPLITK=1: both K-halves of FFN2 in ONE dispatch (half 1 -> Y2, no bias).
enum { MODE_NORMAL = 0, MODE_RELU = 1, MODE_VALUE = 2, MODE_QKV = 3 };

#define LDP 40   // 80B row stride: frag reads 2-way (free), 16B-aligned

template<int K, int KS, int NTOT, int MODE, int AB, int OB, int XCDG, int SPLITK>
__global__ void k_mgemm(const void* __restrict__ A_, const unsigned short* __restrict__ Wbf,
                        const float* __restrict__ bias, void* __restrict__ Y_,
                        void* __restrict__ Y2_, int nrows) {
    __shared__ unsigned short Ash[2][128 * LDP];
    __shared__ unsigned short Bsh[2][64 * LDP];
    int t = threadIdx.x;
    int lane = t & 63, w = t >> 6;
    int wm = w & 1, wn = w >> 1;
    int rbx, cbx, khoff = 0;
    if (SPLITK) {
        int blk = blockIdx.x;
        rbx = (blk >> 6) * 8 + (blk & 7);
        cbx = (blk >> 3) & 3;
        int half = (blk >> 5) & 1;
        khoff = half * K;             // K = 1024, KS = 2048
        if (half) { Y_ = Y2_; bias = nullptr; }
        if (rbx * 128 >= nrows) return;
    } else if (XCDG) {
        int blk = blockIdx.x;
        rbx = (blk >> 5) * 8 + (blk & 7);
        cbx = (blk >> 3) & 3;
        if (rbx * 128 >= nrows) return;
    } else {
        rbx = blockIdx.x;
        cbx = blockIdx.y;
    }
    int r0 = rbx * 128;
    int c0 = cbx * 64;

    f4_t acc[4][2];
#pragma unroll
    for (int mt = 0; mt < 4; ++mt)
#pragma unroll
        for (int nt = 0; nt < 2; ++nt) acc[mt][nt] = (f4_t)0.f;

    int arow = t >> 1;
    int akoff = (t & 1) * 16;
    int asrc = min(r0 + arow, nrows - 1);
    const float* aptrf = (const float*)A_ + (size_t)asrc * KS + akoff + khoff;
    const unsigned short* aptrh = (const unsigned short*)A_ + (size_t)asrc * KS + akoff + khoff;
    unsigned short* adst0 = &Ash[0][arow * LDP + akoff];
    unsigned short* adst1 = &Ash[1][arow * LDP + akoff];

    int brow = t >> 2;
    int bkoff = (t & 3) * 8;
    const unsigned short* bptr = Wbf + (size_t)(c0 + brow) * KS + bkoff + khoff;
    unsigned short* bdst0 = &Bsh[0][brow * LDP + bkoff];
    unsigned short* bdst1 = &Bsh[1][brow * LDP + bkoff];

    int lr = lane & 15, kg = lane >> 4;

    float4 fA_0, fA_1, fA_2, fA_3, gA_0, gA_1, gA_2, gA_3;  // fp32 A sets (AB=0)
    us8_t hA_0, hA_1, hB_0, hB_1;                            // bf16 A sets (AB=1)
    us8_t wA, wB;

#define ISSUE_A(k0) do { \
        if (AB) { hA_0 = *(const us8_t*)(aptrh + (k0)); hA_1 = *(const us8_t*)(aptrh + (k0) + 8); } \
        else { fA_0 = *(const float4*)(aptrf + (k0)); fA_1 = *(const float4*)(aptrf + (k0) + 4); \
               fA_2 = *(const float4*)(aptrf + (k0) + 8); fA_3 = *(const float4*)(aptrf + (k0) + 12); } \
        wA = *(const us8_t*)(bptr + (k0)); } while (0)
#define ISSUE_B(k0) do { \
        if (AB) { hB_0 = *(const us8_t*)(aptrh + (k0)); hB_1 = *(const us8_t*)(aptrh + (k0) + 8); } \
        else { gA_0 = *(const float4*)(aptrf + (k0)); gA_1 = *(const float4*)(aptrf + (k0) + 4); \
               gA_2 = *(const float4*)(aptrf + (k0) + 8); gA_3 = *(const float4*)(aptrf + (k0) + 12); } \
        wB = *(const us8_t*)(bptr + (k0)); } while (0)
#define STORE_A(buf) do { \
        if (AB) { *(us8_t*)(adst##buf) = hA_0; *(us8_t*)(adst##buf + 8) = hA_1; } \
        else { U8 x, y; \
               x.u[0] = cvtpk(fA_0.x, fA_0.y); x.u[1] = cvtpk(fA_0.z, fA_0.w); \
               x.u[2] = cvtpk(fA_1.x, fA_1.y); x.u[3] = cvtpk(fA_1.z, fA_1.w); \
               y.u[0] = cvtpk(fA_2.x, fA_2.y); y.u[1] = cvtpk(fA_2.z, fA_2.w); \
               y.u[2] = cvtpk(fA_3.x, fA_3.y); y.u[3] = cvtpk(fA_3.z, fA_3.w); \
               *(us8_t*)(adst##buf) = x.v; *(us8_t*)(adst##buf + 8) = y.v; } \
        *(us8_t*)(bdst##buf) = wA; } while (0)
#define STORE_B(buf) do { \
        if (AB) { *(us8_t*)(adst##buf) = hB_0; *(us8_t*)(adst##buf + 8) = hB_1; } \
        else { U8 x, y; \
               x.u[0] = cvtpk(gA_0.x, gA_0.y); x.u[1] = cvtpk(gA_0.z, gA_0.w); \
               x.u[2] = cvtpk(gA_1.x, gA_1.y); x.u[3] = cvtpk(gA_1.z, gA_1.w); \
               y.u[0] = cvtpk(gA_2.x, gA_2.y); y.u[1] = cvtpk(gA_2.z, gA_2.w); \
               y.u[2] = cvtpk(gA_3.x, gA_3.y); y.u[3] = cvtpk(gA_3.z, gA_3.w); \
               *(us8_t*)(adst##buf) = x.v; *(us8_t*)(adst##buf + 8) = y.v; } \
        *(us8_t*)(bdst##buf) = wB; } while (0)
#define COMPUTE(buf) do { \
        bf8_t afr[4], bfr[2]; \
        _Pragma("unroll") \
        for (int mt = 0; mt < 4; ++mt) \
            afr[mt] = *(const bf8_t*)&Ash[buf][(wm * 64 + mt * 16 + lr) * LDP + kg * 8]; \
        _Pragma("unroll") \
        for (int nt = 0; nt < 2; ++nt) \
            bfr[nt] = *(const bf8_t*)&Bsh[buf][(wn * 32 + nt * 16 + lr) * LDP + kg * 8]; \
        _Pragma("unroll") \
        for (int mt = 0; mt < 4; ++mt) \
            _Pragma("unroll") \
            for (int nt = 0; nt < 2; ++nt) \
                acc[mt][nt] = __builtin_amdgcn_mfma_f32_16x16x32_bf16(afr[mt], bfr[nt], acc[mt][nt], 0, 0, 0); \
    } while (0)

    ISSUE_A(0);
#pragma unroll 1
    for (int k0 = 0; k0 < K; k0 += 64) {
        STORE_A(0);
        ISSUE_B(k0 + 32);           // K multiple of 64 -> always valid
        __syncthreads();
        COMPUTE(0);
        STORE_B(1);
        if (k0 + 64 < K) ISSUE_A(k0 + 64);
        __syncthreads();
        COMPUTE(1);
    }
#undef ISSUE_A
#undef ISSUE_B
#undef STORE_A
#undef STORE_B
#undef COMPUTE

#pragma unroll
    for (int mt = 0; mt < 4; ++mt) {
#pragma unroll
        for (int nt = 0; nt < 2; ++nt) {
            int col = c0 + wn * 32 + nt * 16 + lr;
            float b0s = bias ? bias[col] : 0.f;
#pragma unroll
            for (int rr = 0; rr < 4; ++rr) {
                int row = r0 + wm * 64 + mt * 16 + kg * 4 + rr;
                if (row >= nrows) continue;
                float v = acc[mt][nt][rr] + b0s;
                size_t idx;
                if (MODE == MODE_NORMAL) {
                    idx = (size_t)row * NTOT + col;
                } else if (MODE == MODE_RELU) {
                    v = fmaxf(v, 0.f);
                    idx = (size_t)row * NTOT + col;
                } else if (MODE == MODE_VALUE) {
                    int lv = row >> 2, b = row & 3;
                    int h = col >> 5, d = col & 31;
                    idx = (((size_t)b * NH + h) * LVTOT + lv) * DH + d;
                } else { // MODE_QKV
                    int lq = row >> 2, b = row & 3;
                    int part = col >> 8, cc = col & 255;
                    int h = cc >> 5, d = cc & 31;
                    if (part == 0) v *= 0.17677669529663687f;  // 1/sqrt(32)
                    idx = (size_t)part * (BQ * NH * LQ * DH) + (((size_t)b * NH + h) * LQ + lq) * DH + d;
                }
                if (OB) ((unsigned short*)Y_)[idx] = f2bf(v);
                else    ((float*)Y_)[idx] = v;
            }
        }
    }
}

// ---------------- vproj-dedicated GEMM: 64x64 tile (R19: 59->53 us, occ 63%) ----------------
__global__ void k_vproj64(const float* __restrict__ A, const unsigned short* __restrict__ Wbf,
                          const float* __restrict__ bias, unsigned short* __restrict__ Y,
                          int nrows) {
    __shared__ unsigned short Ash[2][64 * LDP];
    __shared__ unsigned short Bsh[2][64 * LDP];
    int t = threadIdx.x;
    int lane = t & 63, w = t >> 6;
    int wm = w & 1, wn = w >> 1;
    int blk = blockIdx.x;
    int rbx = (blk >> 5) * 8 + (blk & 7);
    int cbx = (blk >> 3) & 3;
    if (rbx * 64 >= nrows) return;
    int r0 = rbx * 64;
    int c0 = cbx * 64;

    f4_t acc[2][2];
#pragma unroll
    for (int mt = 0; mt < 2; ++mt)
#pragma unroll
        for (int nt = 0; nt < 2; ++nt) acc[mt][nt] = (f4_t)0.f;

    int arow = t >> 2;                 // 0..63
    int akoff = (t & 3) * 8;           // 0,8,16,24
    int asrc = min(r0 + arow, nrows - 1);
    const float* aptrf = A + (size_t)asrc * 256 + akoff;
    unsigned short* adst0 = &Ash[0][arow * LDP + akoff];
    unsigned short* adst1 = &Ash[1][arow * LDP + akoff];

    const unsigned short* bptr = Wbf + (size_t)(c0 + arow) * 256 + akoff;
    unsigned short* bdst0 = &Bsh[0][arow * LDP + akoff];
    unsigned short* bdst1 = &Bsh[1][arow * LDP + akoff];

    int lr = lane & 15, kg = lane >> 4;

    float4 fA_0, fA_1, gA_0, gA_1;
    us8_t wA, wB;

#define ISSUE_A(k0) do { fA_0 = *(const float4*)(aptrf + (k0)); fA_1 = *(const float4*)(aptrf + (k0) + 4); \
                         wA = *(const us8_t*)(bptr + (k0)); } while (0)
#define ISSUE_B(k0) do { gA_0 = *(const float4*)(aptrf + (k0)); gA_1 = *(const float4*)(aptrf + (k0) + 4); \
                         wB = *(const us8_t*)(bptr + (k0)); } while (0)
#define STORE_A(buf) do { U4 x0, x1; \
        x0.u[0] = cvtpk(fA_0.x, fA_0.y); x0.u[1] = cvtpk(fA_0.z, fA_0.w); \
        x1.u[0] = cvtpk(fA_1.x, fA_1.y); x1.u[1] = cvtpk(fA_1.z, fA_1.w); \
        *(us4_t*)(adst##buf) = x0.v; *(us4_t*)(adst##buf + 4) = x1.v; \
        *(us8_t*)(bdst##buf) = wA; } while (0)
#define STORE_B(buf) do { U4 x0, x1; \
        x0.u[0] = cvtpk(gA_0.x, gA_0.y); x0.u[1] = cvtpk(gA_0.z, gA_0.w); \
        x1.u[0] = cvtpk(gA_1.x, gA_1.y); x1.u[1] = cvtpk(gA_1.z, gA_1.w); \
        *(us4_t*)(adst##buf) = x0.v; *(us4_t*)(adst##buf + 4) = x1.v; \
        *(us8_t*)(bdst##buf) = wB; } while (0)
#define COMPUTE(buf) do { \
        bf8_t afr[2], bfr[2]; \
        _Pragma("unroll") \
        for (int mt = 0; mt < 2; ++mt) \
            afr[mt] = *(const bf8_t*)&Ash[buf][(wm * 32 + mt * 16 + lr) * LDP + kg * 8]; \
        _Pragma("unroll") \
        for (int nt = 0; nt < 2; ++nt) \
            bfr[nt] = *(const bf8_t*)&Bsh[buf][(wn * 32 + nt * 16 + lr) * LDP + kg * 8]; \
        _Pragma("unroll") \
        for (int mt = 0; mt < 2; ++mt) \
            _Pragma("unroll") \
            for (int nt = 0; nt < 2; ++nt) \
                acc[mt][nt] = __builtin_amdgcn_mfma_f32_16x16x32_bf16(afr[mt], bfr[nt], acc[mt][nt], 0, 0, 0); \
    } while (0)

    ISSUE_A(0);
#pragma unroll 1
    for (int k0 = 0; k0 < 256; k0 += 64) {
        STORE_A(0);
        ISSUE_B(k0 + 32);
        __syncthreads();
        COMPUTE(0);
        STORE_B(1);
        if (k0 + 64 < 256) ISSUE_A(k0 + 64);
        __syncthreads();
        COMPUTE(1);
    }
#undef ISSUE_A
#undef ISSUE_B
#undef STORE_A
#undef STORE_B
#undef COMPUTE

#pragma unroll
    for (int mt = 0; mt < 2; ++mt) {
#pragma unroll
        for (int nt = 0; nt < 2; ++nt) {
            int col = c0 + wn * 32 + nt * 16 + lr;
            float b0s = bias[col];
#pragma unroll
            for (int rr = 0; rr < 4; ++rr) {
                int row = r0 + wm * 32 + mt * 16 + kg * 4 + rr;
                if (row >= nrows) continue;
                float v = acc[mt][nt][rr] + b0s;
                int lv = row >> 2, b = row & 3;
                int h = col >> 5, d = col & 31;
                Y[(((size_t)b * NH + h) * LVTOT + lv) * DH + d] = f2bf(v);
            }
        }
    }
}

// ---------------- deformable sampling ----------------
__global__ void k_sample(const float* __restrict__ trp, const float* __restrict__ offaw,
                         const unsigned short* __restrict__ value,
                         unsigned short* __restrict__ accU) {
    int r = blockIdx.x;
    int b = r & 3;
    int t = threadIdx.x;
    int h = t >> 5;
    int lane32 = t & 31;
    int l = lane32 >> 3;               // level-group
    int dl = lane32 & 7;               // d-quad: d0 = dl*4
    int d0 = dl * 4;
    const unsigned short* vb = value + ((size_t)b * NH + h) * (size_t)LVTOT * DH;

    const float* lg = offaw + (size_t)r * 384 + 256 + h * 16;
    float e0,e1,e2,e3,e4,e5,e6,e7,e8,e9,e10,e11,e12,e13,e14,e15;
    {
        float4 q0 = *(const float4*)(lg);
        float4 q1 = *(const float4*)(lg + 4);
        float4 q2 = *(const float4*)(lg + 8);
        float4 q3 = *(const float4*)(lg + 12);
        float mx = fmaxf(fmaxf(fmaxf(q0.x,q0.y),fmaxf(q0.z,q0.w)),
                   fmaxf(fmaxf(fmaxf(q1.x,q1.y),fmaxf(q1.z,q1.w)),
                   fmaxf(fmaxf(fmaxf(q2.x,q2.y),fmaxf(q2.z,q2.w)),
                         fmaxf(fmaxf(q3.x,q3.y),fmaxf(q3.z,q3.w)))));
        e0=__expf(q0.x-mx); e1=__expf(q0.y-mx); e2=__expf(q0.z-mx); e3=__expf(q0.w-mx);
        e4=__expf(q1.x-mx); e5=__expf(q1.y-mx); e6=__expf(q1.z-mx); e7=__expf(q1.w-mx);
        e8=__expf(q2.x-mx); e9=__expf(q2.y-mx); e10=__expf(q2.z-mx); e11=__expf(q2.w-mx);
        e12=__expf(q3.x-mx); e13=__expf(q3.y-mx); e14=__expf(q3.z-mx); e15=__expf(q3.w-mx);
    }
    float ssum = ((e0+e1)+(e2+e3)) + ((e4+e5)+(e6+e7)) + ((e8+e9)+(e10+e11)) + ((e12+e13)+(e14+e15));
    float sinv = 1.0f / ssum;
    float w0 = (l==0) ? e0 : (l==1) ? e4 : (l==2) ? e8  : e12;
    float w1 = (l==0) ? e1 : (l==1) ? e5 : (l==2) ? e9  : e13;
    float w2 = (l==0) ? e2 : (l==1) ? e6 : (l==2) ? e10 : e14;
    float w3 = (l==0) ? e3 : (l==1) ? e7 : (l==2) ? e11 : e15;
    w0 *= sinv; w1 *= sinv; w2 *= sinv; w3 *= sinv;

    int Hl = (l==0) ? 100 : (l==1) ? 50 : (l==2) ? 25 : 13;
    int Wl = (l==0) ? 134 : (l==1) ? 67 : (l==2) ? 34 : 17;
    int s  = (l==0) ? 0 : (l==1) ? 13400 : (l==2) ? 16750 : 17600;
    float fW = (float)Wl, fH = (float)Hl;

    float rx = trp[((size_t)r * NL + l) * 2 + 0];
    float ry = trp[((size_t)r * NL + l) * 2 + 1];
    const float* offr = offaw + (size_t)r * 384 + h * 32 + l * 8;

    float o0 = 0.f, o1 = 0.f, o2 = 0.f, o3 = 0.f;
#pragma unroll
    for (int p = 0; p < 4; ++p) {
        float ox = offr[p * 2 + 0];
        float oy = offr[p * 2 + 1];
        float wq = (p==0) ? w0 : (p==1) ? w1 : (p==2) ? w2 : w3;
        float x = (rx + ox / fW) * fW - 0.5f;
        float y = (ry + oy / fH) * fH - 0.5f;
        float x0 = floorf(x), y0 = floorf(y);
#pragma unroll
        for (int dy = 0; dy < 2; ++dy) {
#pragma unroll
            for (int dx = 0; dx < 2; ++dx) {
                float xi = x0 + dx, yi = y0 + dy;
                float wgt = (1.0f - fabsf(x - xi)) * (1.0f - fabsf(y - yi));
                bool valid = (xi >= 0.f) && (xi < fW) && (yi >= 0.f) && (yi < fH);
                int xic = min(max((int)xi, 0), Wl - 1);
                int yic = min(max((int)yi, 0), Hl - 1);
                float cw = (valid ? wgt : 0.f) * wq;
                us4_t v4 = *(const us4_t*)&vb[((size_t)(s + yic * Wl + xic)) * DH + d0];
                o0 += cw * b2f(v4[0]);
                o1 += cw * b2f(v4[1]);
                o2 += cw * b2f(v4[2]);
                o3 += cw * b2f(v4[3]);
            }
        }
    }
    o0 += __shfl_xor(o0, 8, 32); o0 += __shfl_xor(o0, 16, 32);
    o1 += __shfl_xor(o1, 8, 32); o1 += __shfl_xor(o1, 16, 32);
    o2 += __shfl_xor(o2, 8, 32); o2 += __shfl_xor(o2, 16, 32);
    o3 += __shfl_xor(o3, 8, 32); o3 += __shfl_xor(o3, 16, 32);
    if (l == 0) {
        U4 u;
        u.u[0] = cvtpk(o0, o1);
        u.u[1] = cvtpk(o2, o3);
        *(us4_t*)&accU[(size_t)r * C + h * 32 + d0] = u.v;
    }
}

// ---------------- residual + LN: wave-per-row; bf16 Y inputs; dual f32 + bf16 output ----------------
__global__ void k_res_ln(const unsigned short* __restrict__ Y0U, const unsigned short* __restrict__ Y1U,
                         const float* __restrict__ Xres, const float* __restrict__ g,
                         const float* __restrict__ be, float* __restrict__ out,
                         unsigned short* __restrict__ outU) {
    int t = threadIdx.x, wv = t >> 6, lane = t & 63;
    int r = blockIdx.x * 4 + wv;
    us4_t y0 = *(const us4_t*)(Y0U + (size_t)r * C + lane * 4);
    float4 x = ((const float4*)(Xres + (size_t)r * C))[lane];
    float4 v = make_float4(x.x + b2f(y0[0]), x.y + b2f(y0[1]), x.z + b2f(y0[2]), x.w + b2f(y0[3]));
    if (Y1U) {
        us4_t y1 = *(const us4_t*)(Y1U + (size_t)r * C + lane * 4);
        v.x += b2f(y1[0]); v.y += b2f(y1[1]); v.z += b2f(y1[2]); v.w += b2f(y1[3]);
    }
    float s = (v.x + v.y) + (v.z + v.w);
#pragma unroll
    for (int o = 32; o > 0; o >>= 1) s += __shfl_xor(s, o, 64);
    float mean = s * (1.0f / C);
    float4 dv = make_float4(v.x - mean, v.y - mean, v.z - mean, v.w - mean);
    float q = (dv.x * dv.x + dv.y * dv.y) + (dv.z * dv.z + dv.w * dv.w);
#pragma unroll
    for (int o = 32; o > 0; o >>= 1) q += __shfl_xor(q, o, 64);
    float rstd = rsqrtf(q * (1.0f / C) + 1e-5f);
    float4 g4 = ((const float4*)g)[lane];
    float4 b4 = ((const float4*)be)[lane];
    float4 o4 = make_float4(dv.x * rstd * g4.x + b4.x, dv.y * rstd * g4.y + b4.y,
                            dv.z * rstd * g4.z + b4.z, dv.w * rstd * g4.w + b4.w);
    ((float4*)(out + (size_t)r * C))[lane] = o4;
    if (outU) {
        U4 u;
        u.u[0] = cvtpk(o4.x, o4.y);
        u.u[1] = cvtpk(o4.z, o4.w);
        *(us4_t*)(outU + (size_t)r * C + lane * 4) = u.v;
    }
}

// ---------------- MFMA flash attention (bf16 Q/K/V/O) ----------------
// LDS slimmed: P overlays each wave's K region (dead after QK^T frag loads);
// final O-combine buffer overlays the same region after the loop. 94->57 KB
// -> 2 blocks/CU (launch_bounds(256,2)) for 2x resident waves.
#define NQC3 15   // ceil(900/64)

__global__ __launch_bounds__(256, 2)
void k_attn3(const unsigned short* __restrict__ Q, const unsigned short* __restrict__ K,
             const unsigned short* __restrict__ V, unsigned short* __restrict__ O) {
    __shared__ unsigned short sK[4][64 * 72];   // K rows [key][d]; P overlays; Obuf overlays after loop
    __shared__ unsigned short sV[4][32 * 72];   // V^T [d][key]
    __shared__ float sWm[4][64], sWl[4][64];

    int blk = blockIdx.x;
    int bh = blk & 31;                 // XCD locality
    int qc = blk >> 5;
    int b = bh >> 3, h = bh & 7;
    int t = threadIdx.x;
    int w = t >> 6, lane = t & 63;
    int lr = lane & 15, g = lane >> 4;

    const unsigned short* Qb = Q + (size_t)bh * LQ * DH;
    const unsigned short* Kb = K + (size_t)bh * LQ * DH;
    const unsigned short* Vb = V + (size_t)bh * LQ * DH;

    unsigned short* Ks = sK[w];
    unsigned short* Vt = sV[w];
    unsigned short* Ps = sK[w];        // P overlays K (wave-private, program-ordered)

    bf8_t qf[4];
#pragma unroll
    for (int nt = 0; nt < 4; ++nt) {
        int qg = min(qc * 64 + nt * 16 + lr, LQ - 1);
        qf[nt] = *(const bf8_t*)(Qb + (size_t)qg * DH + g * 8);
    }

    float m[4], l[4];
    f4_t acc[2][4];
#pragma unroll
    for (int nt = 0; nt < 4; ++nt) {
        m[nt] = -3e38f; l[nt] = 0.f;
        acc[0][nt] = (f4_t)0.f; acc[1][nt] = (f4_t)0.f;
    }

    for (int ci = 0; ci < 4; ++ci) {
        int k0 = ci * 256 + w * 64;
        if (k0 >= LQ) break;
        int kgl = min(k0 + lane, LQ - 1);
        const unsigned short* kr = Kb + (size_t)kgl * DH;
        const unsigned short* vr = Vb + (size_t)kgl * DH;
#pragma unroll
        for (int i = 0; i < 4; ++i)
            *(us8_t*)&Ks[lane * 72 + i * 8] = *(const us8_t*)(kr + i * 8);
#pragma unroll
        for (int i = 0; i < 4; ++i) {
            us8_t v8 = *(const us8_t*)(vr + i * 8);
#pragma unroll
            for (int j = 0; j < 8; ++j)
                Vt[(i * 8 + j) * 72 + lane] = v8[j];
        }
        // ---- QK^T: S^T[64k][64q] ---- (K frags to registers first; Ks dead after)
        bf8_t ka[4];
#pragma unroll
        for (int mt = 0; mt < 4; ++mt)
            ka[mt] = *(const bf8_t*)&Ks[(mt * 16 + lr) * 72 + g * 8];
        f4_t st[4][4];
#pragma unroll
        for (int mt = 0; mt < 4; ++mt)
#pragma unroll
            for (int nt = 0; nt < 4; ++nt)
                st[mt][nt] = __builtin_amdgcn_mfma_f32_16x16x32_bf16(ka[mt], qf[nt], (f4_t)0.f, 0, 0, 0);
        // ---- online softmax + P write (into Ks region) ----
#pragma unroll
        for (int nt = 0; nt < 4; ++nt) {
            float sv[4][4];
            float cm = -3e38f;
#pragma unroll
            for (int mt = 0; mt < 4; ++mt)
#pragma unroll
                for (int rr = 0; rr < 4; ++rr) {
                    bool valid = (k0 + mt * 16 + g * 4 + rr) < LQ;
                    float s = valid ? st[mt][nt][rr] : -3e38f;
                    sv[mt][rr] = s;
                    cm = fmaxf(cm, s);
                }
            cm = fmaxf(cm, __shfl_xor(cm, 16, 64));
            cm = fmaxf(cm, __shfl_xor(cm, 32, 64));
            float mn = fmaxf(m[nt], cm);
            float sc = __expf(m[nt] - mn);
            float cs = 0.f;
#pragma unroll
            for (int mt = 0; mt < 4; ++mt) {
                float pv0 = (sv[mt][0] > -1e37f) ? __expf(sv[mt][0] - mn) : 0.f;
                float pv1 = (sv[mt][1] > -1e37f) ? __expf(sv[mt][1] - mn) : 0.f;
                float pv2 = (sv[mt][2] > -1e37f) ? __expf(sv[mt][2] - mn) : 0.f;
                float pv3 = (sv[mt][3] > -1e37f) ? __expf(sv[mt][3] - mn) : 0.f;
                cs += (pv0 + pv1) + (pv2 + pv3);
                U4 pk;
                pk.u[0] = cvtpk(pv0, pv1);
                pk.u[1] = cvtpk(pv2, pv3);
                *(us4_t*)&Ps[(nt * 16 + lr) * 72 + mt * 16 + g * 4] = pk.v;
            }
            cs += __shfl_xor(cs, 16, 64);
            cs += __shfl_xor(cs, 32, 64);
            l[nt] = l[nt] * sc + cs;
            m[nt] = mn;
            acc[0][nt] *= sc;
            acc[1][nt] *= sc;
        }
        // ---- PV: O^T[32d][64q] ----
        bf8_t va[2][2];
#pragma unroll
        for (int md = 0; md < 2; ++md)
#pragma unroll
            for (int kt = 0; kt < 2; ++kt)
                va[md][kt] = *(const bf8_t*)&Vt[(md * 16 + lr) * 72 + kt * 32 + g * 8];
#pragma unroll
        for (int nt = 0; nt < 4; ++nt)
#pragma unroll
            for (int kt = 0; kt < 2; ++kt) {
                bf8_t pb = *(const bf8_t*)&Ps[(nt * 16 + lr) * 72 + kt * 32 + g * 8];
                acc[0][nt] = __builtin_amdgcn_mfma_f32_16x16x32_bf16(va[0][kt], pb, acc[0][nt], 0, 0, 0);
                acc[1][nt] = __builtin_amdgcn_mfma_f32_16x16x32_bf16(va[1][kt], pb, acc[1][nt], 0, 0, 0);
            }
    }

    // ---- wave combine (Obuf overlays sK[w], 64q x 36d f32 = 9216 B fits exactly) ----
    if (g == 0) {
#pragma unroll
        for (int nt = 0; nt < 4; ++nt) {
            sWm[w][nt * 16 + lr] = m[nt];
            sWl[w][nt * 16 + lr] = l[nt];
        }
    }
    __syncthreads();
    float* ob = (float*)sK[w];
#pragma unroll
    for (int nt = 0; nt < 4; ++nt) {
        int q = nt * 16 + lr;
        float M = fmaxf(fmaxf(sWm[0][q], sWm[1][q]), fmaxf(sWm[2][q], sWm[3][q]));
        float fac = __expf(m[nt] - M);
        f4_t v0 = acc[0][nt] * fac;
        f4_t v1 = acc[1][nt] * fac;
        *(f4_t*)&ob[q * 36 + g * 4] = v0;
        *(f4_t*)&ob[q * 36 + 16 + g * 4] = v1;
    }
    __syncthreads();
    {
        int q = t >> 2, d0 = (t & 3) * 8;
        int qglob = qc * 64 + q;
        if (qglob < LQ) {
            float M = fmaxf(fmaxf(sWm[0][q], sWm[1][q]), fmaxf(sWm[2][q], sWm[3][q]));
            float L = 0.f;
#pragma unroll
            for (int w2 = 0; w2 < 4; ++w2) L += sWl[w2][q] * __expf(sWm[w2][q] - M);
            float inv = 1.0f / L;
            f4_t r0 = (f4_t)0.f, r1 = (f4_t)0.f;
#pragma unroll
            for (int w2 = 0; w2 < 4; ++w2) {
                const float* obw = (const float*)sK[w2];
                r0 += *(const f4_t*)&obw[q * 36 + d0];
                r1 += *(const f4_t*)&obw[q * 36 + d0 + 4];
            }
            r0 *= inv; r1 *= inv;
            U8 u;
            u.u[0] = cvtpk(r0[0], r0[1]);
            u.u[1] = cvtpk(r0[2], r0[3]);
            u.u[2] = cvtpk(r1[0], r1[1]);
            u.u[3] = cvtpk(r1[2], r1[3]);
            *(us8_t*)(O + ((size_t)(qglob * BQ + b)) * C + h * 32 + d0) = u.v;
        }
    }
}

// ---------------- launch ----------------
extern "C" void kernel_launch(void* const* d_in, const int* in_sizes, int n_in,
                              void* d_out, int out_size, void* d_ws, size_t ws_size,
                              hipStream_t stream) {
    const float* tgt      = (const float*)d_in[0];
    const float* trp      = (const float*)d_in[1];
    const float* memory   = (const float*)d_in[2];
    const float* vproj_w  = (const float*)d_in[5];  const float* vproj_b  = (const float*)d_in[6];
    const float* off_w    = (const float*)d_in[7];  const float* off_b    = (const float*)d_in[8];
    const float* aw_w     = (const float*)d_in[9];  const float* aw_b     = (const float*)d_in[10];
    const float* oproj_w  = (const float*)d_in[11]; const float* oproj_b  = (const float*)d_in[12];
    const float* ln1_g    = (const float*)d_in[13]; const float* ln1_b    = (const float*)d_in[14];
    const float* sa_in_w  = (const float*)d_in[15]; const float* sa_in_b  = (const float*)d_in[16];
    const float* sa_out_w = (const float*)d_in[17]; const float* sa_out_b = (const float*)d_in[18];
    const float* ln2_g    = (const float*)d_in[19]; const float* ln2_b    = (const float*)d_in[20];
    const float* l1_w     = (const float*)d_in[21]; const float* l1_b     = (const float*)d_in[22];
    const float* l2_w     = (const float*)d_in[23]; const float* l2_b     = (const float*)d_in[24];
    const float* ln3_g    = (const float*)d_in[25]; const float* ln3_b    = (const float*)d_in[26];
    const float* sa3_in_w = (const float*)d_in[27]; const float* sa3_in_b = (const float*)d_in[28];
    const float* sa3_out_w= (const float*)d_in[29]; const float* sa3_out_b= (const float*)d_in[30];
    const float* ln5_g    = (const float*)d_in[31]; const float* ln5_b    = (const float*)d_in[32];
    const float* l31_w    = (const float*)d_in[33]; const float* l31_b    = (const float*)d_in[34];
    const float* l32_w    = (const float*)d_in[35]; const float* l32_b    = (const float*)d_in[36];
    const float* ln33_g   = (const float*)d_in[37]; const float* ln33_b   = (const float*)d_in[38];

    float* ws = (float*)d_ws;
    float* X              = ws;                                    // 921,600 f32
    unsigned short* valueU= (unsigned short*)(ws + 921600);        // 18,248,704 bf16
    float* offaw          = ws + 10045952;                         // 1,382,400 f32 [3600][384]
    unsigned short* accU  = (unsigned short*)(ws + 11428352);      // 921,600 bf16
    unsigned short* QKVu  = (unsigned short*)(ws + 12349952);      // 2,764,800 bf16
    unsigned short* Ou    = (unsigned short*)(ws + 13732352);      // 921,600 bf16
    unsigned short* H1u   = (unsigned short*)(ws + 14193152);      // 7,372,800 bf16
    unsigned short* Yu    = (unsigned short*)(ws + 17879552);      // 921,600 bf16
    unsigned short* Y2u   = (unsigned short*)(ws + 18801152);      // 921,600 bf16
    unsigned short* T1u   = (unsigned short*)(ws + 19722752);      // 921,600 bf16
    unsigned short* Wbf   = (unsigned short*)(ws + 20644352);      // 2,850,816 bf16
    float* bias384        = ws + 22069760;                         // 384 f32
    unsigned short* XU    = (unsigned short*)(ws + 22070144);      // 921,600 bf16
    unsigned short* tgtU  = (unsigned short*)(ws + 22530944);      // 921,600 bf16

    const int NVROWS = BQ * LVTOT;           // 71,284 -> 1114 64-row blocks -> 140 supergroups
    dim3 blk(256);
    dim3 gTok(29, 4);
    void* nullv = nullptr;

    // ---- pre-conversions (weights + tgt) ----
    k_prep<<<(PTOT + 255) / 256, blk, 0, stream>>>(off_w, aw_w, vproj_w, oproj_w, sa_in_w, sa_out_w,
                                                   l1_w, l2_w, sa3_in_w, sa3_out_w, l31_w, l32_w,
                                                   off_b, aw_b, tgt, Wbf, bias384, tgtU);

    // ---- ca: MSDeformAttn ----
    k_vproj64<<<140 * 32, blk, 0, stream>>>(memory, Wbf + WOFF_VPROJ, vproj_b, valueU, NVROWS);
    k_mgemm<256, 256, 384, MODE_NORMAL, 1, 0, 0, 0><<<dim3(29, 6), blk, 0, stream>>>(tgtU, Wbf + WOFF_OFFAW, bias384, offaw, nullv, NTOK);
    k_sample<<<NTOK, blk, 0, stream>>>(trp, offaw, valueU, accU);
    k_mgemm<256, 256, 256, MODE_NORMAL, 1, 1, 0, 0><<<gTok, blk, 0, stream>>>(accU, Wbf + WOFF_OPROJ, oproj_b, T1u, nullv, NTOK);
    k_res_ln<<<NTOK / 4, blk, 0, stream>>>(T1u, nullptr, tgt, ln1_g, ln1_b, X, XU);

    // ---- sa ----
    k_mgemm<256, 256, 768, MODE_QKV, 1, 1, 0, 0><<<dim3(29, 12), blk, 0, stream>>>(XU, Wbf + WOFF_SAIN, sa_in_b, QKVu, nullv, NTOK);
    k_attn3<<<32 * NQC3, blk, 0, stream>>>(QKVu, QKVu + 921600, QKVu + 1843200, Ou);
    k_mgemm<256, 256, 256, MODE_NORMAL, 1, 1, 0, 0><<<gTok, blk, 0, stream>>>(Ou, Wbf + WOFF_SAOUT, sa_out_b, T1u, nullv, NTOK);
    k_res_ln<<<NTOK / 4, blk, 0, stream>>>(T1u, nullptr, X, ln2_g, ln2_b, X, XU);

    // ---- ffn ----
    k_mgemm<256, 256, 2048, MODE_RELU, 1, 1, 0, 0><<<dim3(29, 32), blk, 0, stream>>>(XU, Wbf + WOFF_L1, l1_b, H1u, nullv, NTOK);
    k_mgemm<1024, 2048, 256, MODE_NORMAL, 1, 1, 0, 1><<<4 * 64, blk, 0, stream>>>(H1u, Wbf + WOFF_L2, l2_b, Yu, Y2u, NTOK);
    k_res_ln<<<NTOK / 4, blk, 0, stream>>>(Yu, Y2u, X, ln3_g, ln3_b, X, XU);

    // ---- sa3 ----
    k_mgemm<256, 256, 768, MODE_QKV, 1, 1, 0, 0><<<dim3(29, 12), blk, 0, stream>>>(XU, Wbf + WOFF_SA3IN, sa3_in_b, QKVu, nullv, NTOK);
    k_attn3<<<32 * NQC3, blk, 0, stream>>>(QKVu, QKVu + 921600, QKVu + 1843200, Ou);
    k_mgemm<256, 256, 256, MODE_NORMAL, 1, 1, 0, 0><<<gTok, blk, 0, stream>>>(Ou, Wbf + WOFF_SA3OUT, sa3_out_b, T1u, nullv, NTOK);
    k_res_ln<<<NTOK / 4, blk, 0, stream>>>(T1u, nullptr, X, ln5_g, ln5_b, X, XU);

    // ---- ffn3 ----
    k_mgemm<256, 256, 2048, MODE_RELU, 1, 1, 0, 0><<<dim3(29, 32), blk, 0, stream>>>(XU, Wbf + WOFF_L31, l31_b, H1u, nullv, NTOK);
    k_mgemm<1024, 2048, 256, MODE_NORMAL, 1, 1, 0, 1><<<4 * 64, blk, 0, stream>>>(H1u, Wbf + WOFF_L32, l32_b, Yu, Y2u, NTOK);
    k_res_ln<<<NTOK / 4, blk, 0, stream>>>(Yu, Y2u, X, ln33_g, ln33_b, (float*)d_out, nullptr);
}

// Round 22
// 237.895 us; speedup vs baseline: 1.4234x; 1.0072x over previous
//
#include <hip/hip_runtime.h>
#include <math.h>

#define C 256
#define DH 32
#define NH 8
#define NL 4
#define NP 4
#define BQ 4
#define LQ 900
#define LVTOT 17821
#define DFFN 2048
#define NTOK (BQ*LQ)          // 3600 token rows, token index t = lq*B + b

typedef __attribute__((ext_vector_type(8))) short bf8_t;    // 8 bf16 (4 VGPRs)
typedef __attribute__((ext_vector_type(4))) float f4_t;     // MFMA acc
typedef __attribute__((ext_vector_type(8))) unsigned short us8_t;
typedef __attribute__((ext_vector_type(4))) unsigned short us4_t;

union U8 { us8_t v; unsigned int u[4]; };
union U4 { us4_t v; unsigned int u[2]; };

// ---------------- helpers ----------------
__device__ __forceinline__ unsigned short f2bf(float f) {
    unsigned int u = __float_as_uint(f);
    u += 0x7fffu + ((u >> 16) & 1u);   // round-to-nearest-even
    return (unsigned short)(u >> 16);
}
__device__ __forceinline__ float b2f(unsigned short u) {
    return __uint_as_float(((unsigned int)u) << 16);
}
// packed fp32x2 -> bf16x2 (RNE), 1 instruction
__device__ __forceinline__ unsigned int cvtpk(float lo, float hi) {
    unsigned int r;
    asm("v_cvt_pk_bf16_f32 %0, %1, %2" : "=v"(r) : "v"(lo), "v"(hi));
    return r;
}

// ---------------- one-time conversions: weights fp32->bf16, tgt fp32->bf16 ----------------
#define WOFF_OFFAW   0         // off_w 65536 | aw_w 32768  (fused 384x256)
#define WOFF_VPROJ   98304
#define WOFF_OPROJ   163840
#define WOFF_SAIN    229376
#define WOFF_SAOUT   425984
#define WOFF_L1      491520
#define WOFF_L2      1015808
#define WOFF_SA3IN   1540096
#define WOFF_SA3OUT  1736704
#define WOFF_L31     1802240
#define WOFF_L32     2326528
#define WTOT         2850816
#define PTOT         (WTOT + 921600)   // + tgt

__global__ void k_prep(const float* __restrict__ off_w, const float* __restrict__ aw_w,
                       const float* __restrict__ vproj_w, const float* __restrict__ oproj_w,
                       const float* __restrict__ sa_in_w, const float* __restrict__ sa_out_w,
                       const float* __restrict__ l1_w, const float* __restrict__ l2_w,
                       const float* __restrict__ sa3_in_w, const float* __restrict__ sa3_out_w,
                       const float* __restrict__ l31_w, const float* __restrict__ l32_w,
                       const float* __restrict__ off_b, const float* __restrict__ aw_b,
                       const float* __restrict__ tgt,
                       unsigned short* __restrict__ Wbf, float* __restrict__ bias384,
                       unsigned short* __restrict__ tgtU) {
    int i = blockIdx.x * 256 + threadIdx.x;
    if (i < 384) bias384[i] = (i < 256) ? off_b[i] : aw_b[i - 256];
    if (i >= PTOT) return;
    if (i >= WTOT) { int j = i - WTOT; tgtU[j] = f2bf(tgt[j]); return; }
    const float* src; int rel;
    if      (i < WOFF_VPROJ)  { if (i < 65536) { src = off_w; rel = i; } else { src = aw_w; rel = i - 65536; } }
    else if (i < WOFF_OPROJ)  { src = vproj_w;  rel = i - WOFF_VPROJ; }
    else if (i < WOFF_SAIN)   { src = oproj_w;  rel = i - WOFF_OPROJ; }
    else if (i < WOFF_SAOUT)  { src = sa_in_w;  rel = i - WOFF_SAIN; }
    else if (i < WOFF_L1)     { src = sa_out_w; rel = i - WOFF_SAOUT; }
    else if (i < WOFF_L2)     { src = l1_w;     rel = i - WOFF_L1; }
    else if (i < WOFF_SA3IN)  { src = l2_w;     rel = i - WOFF_L2; }
    else if (i < WOFF_SA3OUT) { src = sa3_in_w; rel = i - WOFF_SA3IN; }
    else if (i < WOFF_L31)    { src = sa3_out_w; rel = i - WOFF_SA3OUT; }
    else if (i < WOFF_L32)    { src = l31_w;    rel = i - WOFF_L31; }
    else                      { src = l32_w;    rel = i - WOFF_L32; }
    Wbf[i] = f2bf(src[rel]);
}

// ---------------- bf16 MFMA GEMM: Y = act(A @ W^T + b) ----------------
// A: [nrows][KS] fp32 (AB=0) or bf16 (AB=1); W: bf16. Output f32/bf16 per OB.
// Tile 128x64, 4 waves 2x2, K-step 32, DOUBLE-buffered LDS, ONE barrier/step.
// Prefetch depth 2 (named sets; depth 4 spills to scratch: R17 WRITE 37->147MB).
// XCDG=4: blk=32G+8cb+x -> rb=8G+x (4 col-tiles of a row-slab share an XCD).
// SPLITK=1: both K-halves of FFN2 in ONE dispatch (half 1 -> Y2, no bias).
enum { MODE_NORMAL = 0, MODE_RELU = 1, MODE_VALUE = 2, MODE_QKV = 3 };

#define LDP 40   // 80B row stride: frag reads 2-way (free), 16B-aligned

template<int K, int KS, int NTOT, int MODE, int AB, int OB, int XCDG, int SPLITK>
__global__ void k_mgemm(const void* __restrict__ A_, const unsigned short* __restrict__ Wbf,
                        const float* __restrict__ bias, void* __restrict__ Y_,
                        void* __restrict__ Y2_, int nrows) {
    __shared__ unsigned short Ash[2][128 * LDP];
    __shared__ unsigned short Bsh[2][64 * LDP];
    int t = threadIdx.x;
    int lane = t & 63, w = t >> 6;
    int wm = w & 1, wn = w >> 1;
    int rbx, cbx, khoff = 0;
    if (SPLITK) {
        int blk = blockIdx.x;
        rbx = (blk >> 6) * 8 + (blk & 7);
        cbx = (blk >> 3) & 3;
        int half = (blk >> 5) & 1;
        khoff = half * K;             // K = 1024, KS = 2048
        if (half) { Y_ = Y2_; bias = nullptr; }
        if (rbx * 128 >= nrows) return;
    } else if (XCDG) {
        int blk = blockIdx.x;
        rbx = (blk >> 5) * 8 + (blk & 7);
        cbx = (blk >> 3) & 3;
        if (rbx * 128 >= nrows) return;
    } else {
        rbx = blockIdx.x;
        cbx = blockIdx.y;
    }
    int r0 = rbx * 128;
    int c0 = cbx * 64;

    f4_t acc[4][2];
#pragma unroll
    for (int mt = 0; mt < 4; ++mt)
#pragma unroll
        for (int nt = 0; nt < 2; ++nt) acc[mt][nt] = (f4_t)0.f;

    int arow = t >> 1;
    int akoff = (t & 1) * 16;
    int asrc = min(r0 + arow, nrows - 1);
    const float* aptrf = (const float*)A_ + (size_t)asrc * KS + akoff + khoff;
    const unsigned short* aptrh = (const unsigned short*)A_ + (size_t)asrc * KS + akoff + khoff;
    unsigned short* adst0 = &Ash[0][arow * LDP + akoff];
    unsigned short* adst1 = &Ash[1][arow * LDP + akoff];

    int brow = t >> 2;
    int bkoff = (t & 3) * 8;
    const unsigned short* bptr = Wbf + (size_t)(c0 + brow) * KS + bkoff + khoff;
    unsigned short* bdst0 = &Bsh[0][brow * LDP + bkoff];
    unsigned short* bdst1 = &Bsh[1][brow * LDP + bkoff];

    int lr = lane & 15, kg = lane >> 4;

    float4 fA_0, fA_1, fA_2, fA_3, gA_0, gA_1, gA_2, gA_3;  // fp32 A sets (AB=0)
    us8_t hA_0, hA_1, hB_0, hB_1;                            // bf16 A sets (AB=1)
    us8_t wA, wB;

#define ISSUE_A(k0) do { \
        if (AB) { hA_0 = *(const us8_t*)(aptrh + (k0)); hA_1 = *(const us8_t*)(aptrh + (k0) + 8); } \
        else { fA_0 = *(const float4*)(aptrf + (k0)); fA_1 = *(const float4*)(aptrf + (k0) + 4); \
               fA_2 = *(const float4*)(aptrf + (k0) + 8); fA_3 = *(const float4*)(aptrf + (k0) + 12); } \
        wA = *(const us8_t*)(bptr + (k0)); } while (0)
#define ISSUE_B(k0) do { \
        if (AB) { hB_0 = *(const us8_t*)(aptrh + (k0)); hB_1 = *(const us8_t*)(aptrh + (k0) + 8); } \
        else { gA_0 = *(const float4*)(aptrf + (k0)); gA_1 = *(const float4*)(aptrf + (k0) + 4); \
               gA_2 = *(const float4*)(aptrf + (k0) + 8); gA_3 = *(const float4*)(aptrf + (k0) + 12); } \
        wB = *(const us8_t*)(bptr + (k0)); } while (0)
#define STORE_A(buf) do { \
        if (AB) { *(us8_t*)(adst##buf) = hA_0; *(us8_t*)(adst##buf + 8) = hA_1; } \
        else { U8 x, y; \
               x.u[0] = cvtpk(fA_0.x, fA_0.y); x.u[1] = cvtpk(fA_0.z, fA_0.w); \
               x.u[2] = cvtpk(fA_1.x, fA_1.y); x.u[3] = cvtpk(fA_1.z, fA_1.w); \
               y.u[0] = cvtpk(fA_2.x, fA_2.y); y.u[1] = cvtpk(fA_2.z, fA_2.w); \
               y.u[2] = cvtpk(fA_3.x, fA_3.y); y.u[3] = cvtpk(fA_3.z, fA_3.w); \
               *(us8_t*)(adst##buf) = x.v; *(us8_t*)(adst##buf + 8) = y.v; } \
        *(us8_t*)(bdst##buf) = wA; } while (0)
#define STORE_B(buf) do { \
        if (AB) { *(us8_t*)(adst##buf) = hB_0; *(us8_t*)(adst##buf + 8) = hB_1; } \
        else { U8 x, y; \
               x.u[0] = cvtpk(gA_0.x, gA_0.y); x.u[1] = cvtpk(gA_0.z, gA_0.w); \
               x.u[2] = cvtpk(gA_1.x, gA_1.y); x.u[3] = cvtpk(gA_1.z, gA_1.w); \
               y.u[0] = cvtpk(gA_2.x, gA_2.y); y.u[1] = cvtpk(gA_2.z, gA_2.w); \
               y.u[2] = cvtpk(gA_3.x, gA_3.y); y.u[3] = cvtpk(gA_3.z, gA_3.w); \
               *(us8_t*)(adst##buf) = x.v; *(us8_t*)(adst##buf + 8) = y.v; } \
        *(us8_t*)(bdst##buf) = wB; } while (0)
#define COMPUTE(buf) do { \
        bf8_t afr[4], bfr[2]; \
        _Pragma("unroll") \
        for (int mt = 0; mt < 4; ++mt) \
            afr[mt] = *(const bf8_t*)&Ash[buf][(wm * 64 + mt * 16 + lr) * LDP + kg * 8]; \
        _Pragma("unroll") \
        for (int nt = 0; nt < 2; ++nt) \
            bfr[nt] = *(const bf8_t*)&Bsh[buf][(wn * 32 + nt * 16 + lr) * LDP + kg * 8]; \
        _Pragma("unroll") \
        for (int mt = 0; mt < 4; ++mt) \
            _Pragma("unroll") \
            for (int nt = 0; nt < 2; ++nt) \
                acc[mt][nt] = __builtin_amdgcn_mfma_f32_16x16x32_bf16(afr[mt], bfr[nt], acc[mt][nt], 0, 0, 0); \
    } while (0)

    ISSUE_A(0);
#pragma unroll 1
    for (int k0 = 0; k0 < K; k0 += 64) {
        STORE_A(0);
        ISSUE_B(k0 + 32);           // K multiple of 64 -> always valid
        __syncthreads();
        COMPUTE(0);
        STORE_B(1);
        if (k0 + 64 < K) ISSUE_A(k0 + 64);
        __syncthreads();
        COMPUTE(1);
    }
#undef ISSUE_A
#undef ISSUE_B
#undef STORE_A
#undef STORE_B
#undef COMPUTE

#pragma unroll
    for (int mt = 0; mt < 4; ++mt) {
#pragma unroll
        for (int nt = 0; nt < 2; ++nt) {
            int col = c0 + wn * 32 + nt * 16 + lr;
            float b0s = bias ? bias[col] : 0.f;
#pragma unroll
            for (int rr = 0; rr < 4; ++rr) {
                int row = r0 + wm * 64 + mt * 16 + kg * 4 + rr;
                if (row >= nrows) continue;
                float v = acc[mt][nt][rr] + b0s;
                size_t idx;
                if (MODE == MODE_NORMAL) {
                    idx = (size_t)row * NTOT + col;
                } else if (MODE == MODE_RELU) {
                    v = fmaxf(v, 0.f);
                    idx = (size_t)row * NTOT + col;
                } else if (MODE == MODE_VALUE) {
                    int lv = row >> 2, b = row & 3;
                    int h = col >> 5, d = col & 31;
                    idx = (((size_t)b * NH + h) * LVTOT + lv) * DH + d;
                } else { // MODE_QKV
                    int lq = row >> 2, b = row & 3;
                    int part = col >> 8, cc = col & 255;
                    int h = cc >> 5, d = cc & 31;
                    if (part == 0) v *= 0.17677669529663687f;  // 1/sqrt(32)
                    idx = (size_t)part * (BQ * NH * LQ * DH) + (((size_t)b * NH + h) * LQ + lq) * DH + d;
                }
                if (OB) ((unsigned short*)Y_)[idx] = f2bf(v);
                else    ((float*)Y_)[idx] = v;
            }
        }
    }
}

// ---------------- vproj-dedicated GEMM: 64 rows x 128 cols (2 col tiles/block) ----------------
// A k-slab staged ONCE feeds 16 MFMA/wave (was 8): latency stall amortized 2x,
// per-block A fetch halves. acc0/acc1 + B0sh/B1sh static (no runtime indexing,
// ~90 VGPR -> no spill; LDS 30.7KB -> 5 blocks/CU, same 20 waves/CU as R19).
// XCD: rbx=(blk>>4)*8+(blk&7), cbx=(blk>>3)&1 -> both col tiles of a row-slab
// on one XCD within a 16-block window.
__global__ void k_vproj128(const float* __restrict__ A, const unsigned short* __restrict__ Wbf,
                           const float* __restrict__ bias, unsigned short* __restrict__ Y,
                           int nrows) {
    __shared__ unsigned short Ash[2][64 * LDP];
    __shared__ unsigned short B0sh[2][64 * LDP];
    __shared__ unsigned short B1sh[2][64 * LDP];
    int t = threadIdx.x;
    int lane = t & 63, w = t >> 6;
    int wm = w & 1, wn = w >> 1;
    int blk = blockIdx.x;
    int rbx = (blk >> 4) * 8 + (blk & 7);
    int cbx = (blk >> 3) & 1;
    if (rbx * 64 >= nrows) return;
    int r0 = rbx * 64;
    int c0 = cbx * 128;

    f4_t acc0[2][2], acc1[2][2];
#pragma unroll
    for (int mt = 0; mt < 2; ++mt)
#pragma unroll
        for (int nt = 0; nt < 2; ++nt) { acc0[mt][nt] = (f4_t)0.f; acc1[mt][nt] = (f4_t)0.f; }

    int arow = t >> 2;                 // 0..63
    int akoff = (t & 3) * 8;           // 0,8,16,24
    int asrc = min(r0 + arow, nrows - 1);
    const float* aptrf = A + (size_t)asrc * 256 + akoff;
    unsigned short* adst0 = &Ash[0][arow * LDP + akoff];
    unsigned short* adst1 = &Ash[1][arow * LDP + akoff];

    const unsigned short* b0ptr = Wbf + (size_t)(c0 + arow) * 256 + akoff;
    const unsigned short* b1ptr = Wbf + (size_t)(c0 + 64 + arow) * 256 + akoff;
    unsigned short* b0dst0 = &B0sh[0][arow * LDP + akoff];
    unsigned short* b0dst1 = &B0sh[1][arow * LDP + akoff];
    unsigned short* b1dst0 = &B1sh[0][arow * LDP + akoff];
    unsigned short* b1dst1 = &B1sh[1][arow * LDP + akoff];

    int lr = lane & 15, kg = lane >> 4;

    float4 fA_0, fA_1, gA_0, gA_1;
    us8_t wA0, wA1, wB0, wB1;

#define ISSUE_A(k0) do { fA_0 = *(const float4*)(aptrf + (k0)); fA_1 = *(const float4*)(aptrf + (k0) + 4); \
                         wA0 = *(const us8_t*)(b0ptr + (k0)); wA1 = *(const us8_t*)(b1ptr + (k0)); } while (0)
#define ISSUE_B(k0) do { gA_0 = *(const float4*)(aptrf + (k0)); gA_1 = *(const float4*)(aptrf + (k0) + 4); \
                         wB0 = *(const us8_t*)(b0ptr + (k0)); wB1 = *(const us8_t*)(b1ptr + (k0)); } while (0)
#define STORE_A(buf) do { U4 x0, x1; \
        x0.u[0] = cvtpk(fA_0.x, fA_0.y); x0.u[1] = cvtpk(fA_0.z, fA_0.w); \
        x1.u[0] = cvtpk(fA_1.x, fA_1.y); x1.u[1] = cvtpk(fA_1.z, fA_1.w); \
        *(us4_t*)(adst##buf) = x0.v; *(us4_t*)(adst##buf + 4) = x1.v; \
        *(us8_t*)(b0dst##buf) = wA0; *(us8_t*)(b1dst##buf) = wA1; } while (0)
#define STORE_B(buf) do { U4 x0, x1; \
        x0.u[0] = cvtpk(gA_0.x, gA_0.y); x0.u[1] = cvtpk(gA_0.z, gA_0.w); \
        x1.u[0] = cvtpk(gA_1.x, gA_1.y); x1.u[1] = cvtpk(gA_1.z, gA_1.w); \
        *(us4_t*)(adst##buf) = x0.v; *(us4_t*)(adst##buf + 4) = x1.v; \
        *(us8_t*)(b0dst##buf) = wB0; *(us8_t*)(b1dst##buf) = wB1; } while (0)
#define COMPUTE(buf) do { \
        bf8_t afr[2], b0fr[2], b1fr[2]; \
        _Pragma("unroll") \
        for (int mt = 0; mt < 2; ++mt) \
            afr[mt] = *(const bf8_t*)&Ash[buf][(wm * 32 + mt * 16 + lr) * LDP + kg * 8]; \
        _Pragma("unroll") \
        for (int nt = 0; nt < 2; ++nt) { \
            b0fr[nt] = *(const bf8_t*)&B0sh[buf][(wn * 32 + nt * 16 + lr) * LDP + kg * 8]; \
            b1fr[nt] = *(const bf8_t*)&B1sh[buf][(wn * 32 + nt * 16 + lr) * LDP + kg * 8]; \
        } \
        _Pragma("unroll") \
        for (int mt = 0; mt < 2; ++mt) \
            _Pragma("unroll") \
            for (int nt = 0; nt < 2; ++nt) { \
                acc0[mt][nt] = __builtin_amdgcn_mfma_f32_16x16x32_bf16(afr[mt], b0fr[nt], acc0[mt][nt], 0, 0, 0); \
                acc1[mt][nt] = __builtin_amdgcn_mfma_f32_16x16x32_bf16(afr[mt], b1fr[nt], acc1[mt][nt], 0, 0, 0); \
            } \
    } while (0)

    ISSUE_A(0);
#pragma unroll 1
    for (int k0 = 0; k0 < 256; k0 += 64) {
        STORE_A(0);
        ISSUE_B(k0 + 32);
        __syncthreads();
        COMPUTE(0);
        STORE_B(1);
        if (k0 + 64 < 256) ISSUE_A(k0 + 64);
        __syncthreads();
        COMPUTE(1);
    }
#undef ISSUE_A
#undef ISSUE_B
#undef STORE_A
#undef STORE_B
#undef COMPUTE

#pragma unroll
    for (int mt = 0; mt < 2; ++mt) {
#pragma unroll
        for (int nt = 0; nt < 2; ++nt) {
            int col0 = c0 + wn * 32 + nt * 16 + lr;
            int col1 = col0 + 64;
            float bc0 = bias[col0];
            float bc1 = bias[col1];
#pragma unroll
            for (int rr = 0; rr < 4; ++rr) {
                int row = r0 + wm * 32 + mt * 16 + kg * 4 + rr;
                if (row >= nrows) continue;
                int lv = row >> 2, b = row & 3;
                {
                    float v = acc0[mt][nt][rr] + bc0;
                    int h = col0 >> 5, d = col0 & 31;
                    Y[(((size_t)b * NH + h) * LVTOT + lv) * DH + d] = f2bf(v);
                }
                {
                    float v = acc1[mt][nt][rr] + bc1;
                    int h = col1 >> 5, d = col1 & 31;
                    Y[(((size_t)b * NH + h) * LVTOT + lv) * DH + d] = f2bf(v);
                }
            }
        }
    }
}

// ---------------- deformable sampling ----------------
__global__ void k_sample(const float* __restrict__ trp, const float* __restrict__ offaw,
                         const unsigned short* __restrict__ value,
                         unsigned short* __restrict__ accU) {
    int r = blockIdx.x;
    int b = r & 3;
    int t = threadIdx.x;
    int h = t >> 5;
    int lane32 = t & 31;
    int l = lane32 >> 3;               // level-group
    int dl = lane32 & 7;               // d-quad: d0 = dl*4
    int d0 = dl * 4;
    const unsigned short* vb = value + ((size_t)b * NH + h) * (size_t)LVTOT * DH;

    const float* lg = offaw + (size_t)r * 384 + 256 + h * 16;
    float e0,e1,e2,e3,e4,e5,e6,e7,e8,e9,e10,e11,e12,e13,e14,e15;
    {
        float4 q0 = *(const float4*)(lg);
        float4 q1 = *(const float4*)(lg + 4);
        float4 q2 = *(const float4*)(lg + 8);
        float4 q3 = *(const float4*)(lg + 12);
        float mx = fmaxf(fmaxf(fmaxf(q0.x,q0.y),fmaxf(q0.z,q0.w)),
                   fmaxf(fmaxf(fmaxf(q1.x,q1.y),fmaxf(q1.z,q1.w)),
                   fmaxf(fmaxf(fmaxf(q2.x,q2.y),fmaxf(q2.z,q2.w)),
                         fmaxf(fmaxf(q3.x,q3.y),fmaxf(q3.z,q3.w)))));
        e0=__expf(q0.x-mx); e1=__expf(q0.y-mx); e2=__expf(q0.z-mx); e3=__expf(q0.w-mx);
        e4=__expf(q1.x-mx); e5=__expf(q1.y-mx); e6=__expf(q1.z-mx); e7=__expf(q1.w-mx);
        e8=__expf(q2.x-mx); e9=__expf(q2.y-mx); e10=__expf(q2.z-mx); e11=__expf(q2.w-mx);
        e12=__expf(q3.x-mx); e13=__expf(q3.y-mx); e14=__expf(q3.z-mx); e15=__expf(q3.w-mx);
    }
    float ssum = ((e0+e1)+(e2+e3)) + ((e4+e5)+(e6+e7)) + ((e8+e9)+(e10+e11)) + ((e12+e13)+(e14+e15));
    float sinv = 1.0f / ssum;
    float w0 = (l==0) ? e0 : (l==1) ? e4 : (l==2) ? e8  : e12;
    float w1 = (l==0) ? e1 : (l==1) ? e5 : (l==2) ? e9  : e13;
    float w2 = (l==0) ? e2 : (l==1) ? e6 : (l==2) ? e10 : e14;
    float w3 = (l==0) ? e3 : (l==1) ? e7 : (l==2) ? e11 : e15;
    w0 *= sinv; w1 *= sinv; w2 *= sinv; w3 *= sinv;

    int Hl = (l==0) ? 100 : (l==1) ? 50 : (l==2) ? 25 : 13;
    int Wl = (l==0) ? 134 : (l==1) ? 67 : (l==2) ? 34 : 17;
    int s  = (l==0) ? 0 : (l==1) ? 13400 : (l==2) ? 16750 : 17600;
    float fW = (float)Wl, fH = (float)Hl;

    float rx = trp[((size_t)r * NL + l) * 2 + 0];
    float ry = trp[((size_t)r * NL + l) * 2 + 1];
    const float* offr = offaw + (size_t)r * 384 + h * 32 + l * 8;

    float o0 = 0.f, o1 = 0.f, o2 = 0.f, o3 = 0.f;
#pragma unroll
    for (int p = 0; p < 4; ++p) {
        float ox = offr[p * 2 + 0];
        float oy = offr[p * 2 + 1];
        float wq = (p==0) ? w0 : (p==1) ? w1 : (p==2) ? w2 : w3;
        float x = (rx + ox / fW) * fW - 0.5f;
        float y = (ry + oy / fH) * fH - 0.5f;
        float x0 = floorf(x), y0 = floorf(y);
#pragma unroll
        for (int dy = 0; dy < 2; ++dy) {
#pragma unroll
            for (int dx = 0; dx < 2; ++dx) {
                float xi = x0 + dx, yi = y0 + dy;
                float wgt = (1.0f - fabsf(x - xi)) * (1.0f - fabsf(y - yi));
                bool valid = (xi >= 0.f) && (xi < fW) && (yi >= 0.f) && (yi < fH);
                int xic = min(max((int)xi, 0), Wl - 1);
                int yic = min(max((int)yi, 0), Hl - 1);
                float cw = (valid ? wgt : 0.f) * wq;
                us4_t v4 = *(const us4_t*)&vb[((size_t)(s + yic * Wl + xic)) * DH + d0];
                o0 += cw * b2f(v4[0]);
                o1 += cw * b2f(v4[1]);
                o2 += cw * b2f(v4[2]);
                o3 += cw * b2f(v4[3]);
            }
        }
    }
    o0 += __shfl_xor(o0, 8, 32); o0 += __shfl_xor(o0, 16, 32);
    o1 += __shfl_xor(o1, 8, 32); o1 += __shfl_xor(o1, 16, 32);
    o2 += __shfl_xor(o2, 8, 32); o2 += __shfl_xor(o2, 16, 32);
    o3 += __shfl_xor(o3, 8, 32); o3 += __shfl_xor(o3, 16, 32);
    if (l == 0) {
        U4 u;
        u.u[0] = cvtpk(o0, o1);
        u.u[1] = cvtpk(o2, o3);
        *(us4_t*)&accU[(size_t)r * C + h * 32 + d0] = u.v;
    }
}

// ---------------- residual + LN: wave-per-row; bf16 Y inputs; dual f32 + bf16 output ----------------
__global__ void k_res_ln(const unsigned short* __restrict__ Y0U, const unsigned short* __restrict__ Y1U,
                         const float* __restrict__ Xres, const float* __restrict__ g,
                         const float* __restrict__ be, float* __restrict__ out,
                         unsigned short* __restrict__ outU) {
    int t = threadIdx.x, wv = t >> 6, lane = t & 63;
    int r = blockIdx.x * 4 + wv;
    us4_t y0 = *(const us4_t*)(Y0U + (size_t)r * C + lane * 4);
    float4 x = ((const float4*)(Xres + (size_t)r * C))[lane];
    float4 v = make_float4(x.x + b2f(y0[0]), x.y + b2f(y0[1]), x.z + b2f(y0[2]), x.w + b2f(y0[3]));
    if (Y1U) {
        us4_t y1 = *(const us4_t*)(Y1U + (size_t)r * C + lane * 4);
        v.x += b2f(y1[0]); v.y += b2f(y1[1]); v.z += b2f(y1[2]); v.w += b2f(y1[3]);
    }
    float s = (v.x + v.y) + (v.z + v.w);
#pragma unroll
    for (int o = 32; o > 0; o >>= 1) s += __shfl_xor(s, o, 64);
    float mean = s * (1.0f / C);
    float4 dv = make_float4(v.x - mean, v.y - mean, v.z - mean, v.w - mean);
    float q = (dv.x * dv.x + dv.y * dv.y) + (dv.z * dv.z + dv.w * dv.w);
#pragma unroll
    for (int o = 32; o > 0; o >>= 1) q += __shfl_xor(q, o, 64);
    float rstd = rsqrtf(q * (1.0f / C) + 1e-5f);
    float4 g4 = ((const float4*)g)[lane];
    float4 b4 = ((const float4*)be)[lane];
    float4 o4 = make_float4(dv.x * rstd * g4.x + b4.x, dv.y * rstd * g4.y + b4.y,
                            dv.z * rstd * g4.z + b4.z, dv.w * rstd * g4.w + b4.w);
    ((float4*)(out + (size_t)r * C))[lane] = o4;
    if (outU) {
        U4 u;
        u.u[0] = cvtpk(o4.x, o4.y);
        u.u[1] = cvtpk(o4.z, o4.w);
        *(us4_t*)(outU + (size_t)r * C + lane * 4) = u.v;
    }
}

// ---------------- MFMA flash attention (bf16 Q/K/V/O) ----------------
// LDS slimmed: P overlays each wave's K region (dead after QK^T frag loads);
// final O-combine buffer overlays the same region after the loop. 94->57 KB
// -> 2 blocks/CU (launch_bounds(256,2)) for 2x resident waves.
#define NQC3 15   // ceil(900/64)

__global__ __launch_bounds__(256, 2)
void k_attn3(const unsigned short* __restrict__ Q, const unsigned short* __restrict__ K,
             const unsigned short* __restrict__ V, unsigned short* __restrict__ O) {
    __shared__ unsigned short sK[4][64 * 72];   // K rows [key][d]; P overlays; Obuf overlays after loop
    __shared__ unsigned short sV[4][32 * 72];   // V^T [d][key]
    __shared__ float sWm[4][64], sWl[4][64];

    int blk = blockIdx.x;
    int bh = blk & 31;                 // XCD locality
    int qc = blk >> 5;
    int b = bh >> 3, h = bh & 7;
    int t = threadIdx.x;
    int w = t >> 6, lane = t & 63;
    int lr = lane & 15, g = lane >> 4;

    const unsigned short* Qb = Q + (size_t)bh * LQ * DH;
    const unsigned short* Kb = K + (size_t)bh * LQ * DH;
    const unsigned short* Vb = V + (size_t)bh * LQ * DH;

    unsigned short* Ks = sK[w];
    unsigned short* Vt = sV[w];
    unsigned short* Ps = sK[w];        // P overlays K (wave-private, program-ordered)

    bf8_t qf[4];
#pragma unroll
    for (int nt = 0; nt < 4; ++nt) {
        int qg = min(qc * 64 + nt * 16 + lr, LQ - 1);
        qf[nt] = *(const bf8_t*)(Qb + (size_t)qg * DH + g * 8);
    }

    float m[4], l[4];
    f4_t acc[2][4];
#pragma unroll
    for (int nt = 0; nt < 4; ++nt) {
        m[nt] = -3e38f; l[nt] = 0.f;
        acc[0][nt] = (f4_t)0.f; acc[1][nt] = (f4_t)0.f;
    }

    for (int ci = 0; ci < 4; ++ci) {
        int k0 = ci * 256 + w * 64;
        if (k0 >= LQ) break;
        int kgl = min(k0 + lane, LQ - 1);
        const unsigned short* kr = Kb + (size_t)kgl * DH;
        const unsigned short* vr = Vb + (size_t)kgl * DH;
#pragma unroll
        for (int i = 0; i < 4; ++i)
            *(us8_t*)&Ks[lane * 72 + i * 8] = *(const us8_t*)(kr + i * 8);
#pragma unroll
        for (int i = 0; i < 4; ++i) {
            us8_t v8 = *(const us8_t*)(vr + i * 8);
#pragma unroll
            for (int j = 0; j < 8; ++j)
                Vt[(i * 8 + j) * 72 + lane] = v8[j];
        }
        // ---- QK^T: S^T[64k][64q] ---- (K frags to registers first; Ks dead after)
        bf8_t ka[4];
#pragma unroll
        for (int mt = 0; mt < 4; ++mt)
            ka[mt] = *(const bf8_t*)&Ks[(mt * 16 + lr) * 72 + g * 8];
        f4_t st[4][4];
#pragma unroll
        for (int mt = 0; mt < 4; ++mt)
#pragma unroll
            for (int nt = 0; nt < 4; ++nt)
                st[mt][nt] = __builtin_amdgcn_mfma_f32_16x16x32_bf16(ka[mt], qf[nt], (f4_t)0.f, 0, 0, 0);
        // ---- online softmax + P write (into Ks region) ----
#pragma unroll
        for (int nt = 0; nt < 4; ++nt) {
            float sv[4][4];
            float cm = -3e38f;
#pragma unroll
            for (int mt = 0; mt < 4; ++mt)
#pragma unroll
                for (int rr = 0; rr < 4; ++rr) {
                    bool valid = (k0 + mt * 16 + g * 4 + rr) < LQ;
                    float s = valid ? st[mt][nt][rr] : -3e38f;
                    sv[mt][rr] = s;
                    cm = fmaxf(cm, s);
                }
            cm = fmaxf(cm, __shfl_xor(cm, 16, 64));
            cm = fmaxf(cm, __shfl_xor(cm, 32, 64));
            float mn = fmaxf(m[nt], cm);
            float sc = __expf(m[nt] - mn);
            float cs = 0.f;
#pragma unroll
            for (int mt = 0; mt < 4; ++mt) {
                float pv0 = (sv[mt][0] > -1e37f) ? __expf(sv[mt][0] - mn) : 0.f;
                float pv1 = (sv[mt][1] > -1e37f) ? __expf(sv[mt][1] - mn) : 0.f;
                float pv2 = (sv[mt][2] > -1e37f) ? __expf(sv[mt][2] - mn) : 0.f;
                float pv3 = (sv[mt][3] > -1e37f) ? __expf(sv[mt][3] - mn) : 0.f;
                cs += (pv0 + pv1) + (pv2 + pv3);
                U4 pk;
                pk.u[0] = cvtpk(pv0, pv1);
                pk.u[1] = cvtpk(pv2, pv3);
                *(us4_t*)&Ps[(nt * 16 + lr) * 72 + mt * 16 + g * 4] = pk.v;
            }
            cs += __shfl_xor(cs, 16, 64);
            cs += __shfl_xor(cs, 32, 64);
            l[nt] = l[nt] * sc + cs;
            m[nt] = mn;
            acc[0][nt] *= sc;
            acc[1][nt] *= sc;
        }
        // ---- PV: O^T[32d][64q] ----
        bf8_t va[2][2];
#pragma unroll
        for (int md = 0; md < 2; ++md)
#pragma unroll
            for (int kt = 0; kt < 2; ++kt)
                va[md][kt] = *(const bf8_t*)&Vt[(md * 16 + lr) * 72 + kt * 32 + g * 8];
#pragma unroll
        for (int nt = 0; nt < 4; ++nt)
#pragma unroll
            for (int kt = 0; kt < 2; ++kt) {
                bf8_t pb = *(const bf8_t*)&Ps[(nt * 16 + lr) * 72 + kt * 32 + g * 8];
                acc[0][nt] = __builtin_amdgcn_mfma_f32_16x16x32_bf16(va[0][kt], pb, acc[0][nt], 0, 0, 0);
                acc[1][nt] = __builtin_amdgcn_mfma_f32_16x16x32_bf16(va[1][kt], pb, acc[1][nt], 0, 0, 0);
            }
    }

    // ---- wave combine (Obuf overlays sK[w], 64q x 36d f32 = 9216 B fits exactly) ----
    if (g == 0) {
#pragma unroll
        for (int nt = 0; nt < 4; ++nt) {
            sWm[w][nt * 16 + lr] = m[nt];
            sWl[w][nt * 16 + lr] = l[nt];
        }
    }
    __syncthreads();
    float* ob = (float*)sK[w];
#pragma unroll
    for (int nt = 0; nt < 4; ++nt) {
        int q = nt * 16 + lr;
        float M = fmaxf(fmaxf(sWm[0][q], sWm[1][q]), fmaxf(sWm[2][q], sWm[3][q]));
        float fac = __expf(m[nt] - M);
        f4_t v0 = acc[0][nt] * fac;
        f4_t v1 = acc[1][nt] * fac;
        *(f4_t*)&ob[q * 36 + g * 4] = v0;
        *(f4_t*)&ob[q * 36 + 16 + g * 4] = v1;
    }
    __syncthreads();
    {
        int q = t >> 2, d0 = (t & 3) * 8;
        int qglob = qc * 64 + q;
        if (qglob < LQ) {
            float M = fmaxf(fmaxf(sWm[0][q], sWm[1][q]), fmaxf(sWm[2][q], sWm[3][q]));
            float L = 0.f;
#pragma unroll
            for (int w2 = 0; w2 < 4; ++w2) L += sWl[w2][q] * __expf(sWm[w2][q] - M);
            float inv = 1.0f / L;
            f4_t r0 = (f4_t)0.f, r1 = (f4_t)0.f;
#pragma unroll
            for (int w2 = 0; w2 < 4; ++w2) {
                const float* obw = (const float*)sK[w2];
                r0 += *(const f4_t*)&obw[q * 36 + d0];
                r1 += *(const f4_t*)&obw[q * 36 + d0 + 4];
            }
            r0 *= inv; r1 *= inv;
            U8 u;
            u.u[0] = cvtpk(r0[0], r0[1]);
            u.u[1] = cvtpk(r0[2], r0[3]);
            u.u[2] = cvtpk(r1[0], r1[1]);
            u.u[3] = cvtpk(r1[2], r1[3]);
            *(us8_t*)(O + ((size_t)(qglob * BQ + b)) * C + h * 32 + d0) = u.v;
        }
    }
}

// ---------------- launch ----------------
extern "C" void kernel_launch(void* const* d_in, const int* in_sizes, int n_in,
                              void* d_out, int out_size, void* d_ws, size_t ws_size,
                              hipStream_t stream) {
    const float* tgt      = (const float*)d_in[0];
    const float* trp      = (const float*)d_in[1];
    const float* memory   = (const float*)d_in[2];
    const float* vproj_w  = (const float*)d_in[5];  const float* vproj_b  = (const float*)d_in[6];
    const float* off_w    = (const float*)d_in[7];  const float* off_b    = (const float*)d_in[8];
    const float* aw_w     = (const float*)d_in[9];  const float* aw_b     = (const float*)d_in[10];
    const float* oproj_w  = (const float*)d_in[11]; const float* oproj_b  = (const float*)d_in[12];
    const float* ln1_g    = (const float*)d_in[13]; const float* ln1_b    = (const float*)d_in[14];
    const float* sa_in_w  = (const float*)d_in[15]; const float* sa_in_b  = (const float*)d_in[16];
    const float* sa_out_w = (const float*)d_in[17]; const float* sa_out_b = (const float*)d_in[18];
    const float* ln2_g    = (const float*)d_in[19]; const float* ln2_b    = (const float*)d_in[20];
    const float* l1_w     = (const float*)d_in[21]; const float* l1_b     = (const float*)d_in[22];
    const float* l2_w     = (const float*)d_in[23]; const float* l2_b     = (const float*)d_in[24];
    const float* ln3_g    = (const float*)d_in[25]; const float* ln3_b    = (const float*)d_in[26];
    const float* sa3_in_w = (const float*)d_in[27]; const float* sa3_in_b = (const float*)d_in[28];
    const float* sa3_out_w= (const float*)d_in[29]; const float* sa3_out_b= (const float*)d_in[30];
    const float* ln5_g    = (const float*)d_in[31]; const float* ln5_b    = (const float*)d_in[32];
    const float* l31_w    = (const float*)d_in[33]; const float* l31_b    = (const float*)d_in[34];
    const float* l32_w    = (const float*)d_in[35]; const float* l32_b    = (const float*)d_in[36];
    const float* ln33_g   = (const float*)d_in[37]; const float* ln33_b   = (const float*)d_in[38];

    float* ws = (float*)d_ws;
    float* X              = ws;                                    // 921,600 f32
    unsigned short* valueU= (unsigned short*)(ws + 921600);        // 18,248,704 bf16
    float* offaw          = ws + 10045952;                         // 1,382,400 f32 [3600][384]
    unsigned short* accU  = (unsigned short*)(ws + 11428352);      // 921,600 bf16
    unsigned short* QKVu  = (unsigned short*)(ws + 12349952);      // 2,764,800 bf16
    unsigned short* Ou    = (unsigned short*)(ws + 13732352);      // 921,600 bf16
    unsigned short* H1u   = (unsigned short*)(ws + 14193152);      // 7,372,800 bf16
    unsigned short* Yu    = (unsigned short*)(ws + 17879552);      // 921,600 bf16
    unsigned short* Y2u   = (unsigned short*)(ws + 18801152);      // 921,600 bf16
    unsigned short* T1u   = (unsigned short*)(ws + 19722752);      // 921,600 bf16
    unsigned short* Wbf   = (unsigned short*)(ws + 20644352);      // 2,850,816 bf16
    float* bias384        = ws + 22069760;                         // 384 f32
    unsigned short* XU    = (unsigned short*)(ws + 22070144);      // 921,600 bf16
    unsigned short* tgtU  = (unsigned short*)(ws + 22530944);      // 921,600 bf16

    const int NVROWS = BQ * LVTOT;           // 71,284 -> 1114 64-row blocks -> 140 supergroups
    dim3 blk(256);
    dim3 gTok(29, 4);
    void* nullv = nullptr;

    // ---- pre-conversions (weights + tgt) ----
    k_prep<<<(PTOT + 255) / 256, blk, 0, stream>>>(off_w, aw_w, vproj_w, oproj_w, sa_in_w, sa_out_w,
                                                   l1_w, l2_w, sa3_in_w, sa3_out_w, l31_w, l32_w,
                                                   off_b, aw_b, tgt, Wbf, bias384, tgtU);

    // ---- ca: MSDeformAttn ----
    k_vproj128<<<140 * 16, blk, 0, stream>>>(memory, Wbf + WOFF_VPROJ, vproj_b, valueU, NVROWS);
    k_mgemm<256, 256, 384, MODE_NORMAL, 1, 0, 0, 0><<<dim3(29, 6), blk, 0, stream>>>(tgtU, Wbf + WOFF_OFFAW, bias384, offaw, nullv, NTOK);
    k_sample<<<NTOK, blk, 0, stream>>>(trp, offaw, valueU, accU);
    k_mgemm<256, 256, 256, MODE_NORMAL, 1, 1, 0, 0><<<gTok, blk, 0, stream>>>(accU, Wbf + WOFF_OPROJ, oproj_b, T1u, nullv, NTOK);
    k_res_ln<<<NTOK / 4, blk, 0, stream>>>(T1u, nullptr, tgt, ln1_g, ln1_b, X, XU);

    // ---- sa ----
    k_mgemm<256, 256, 768, MODE_QKV, 1, 1, 0, 0><<<dim3(29, 12), blk, 0, stream>>>(XU, Wbf + WOFF_SAIN, sa_in_b, QKVu, nullv, NTOK);
    k_attn3<<<32 * NQC3, blk, 0, stream>>>(QKVu, QKVu + 921600, QKVu + 1843200, Ou);
    k_mgemm<256, 256, 256, MODE_NORMAL, 1, 1, 0, 0><<<gTok, blk, 0, stream>>>(Ou, Wbf + WOFF_SAOUT, sa_out_b, T1u, nullv, NTOK);
    k_res_ln<<<NTOK / 4, blk, 0, stream>>>(T1u, nullptr, X, ln2_g, ln2_b, X, XU);

    // ---- ffn ----
    k_mgemm<256, 256, 2048, MODE_RELU, 1, 1, 0, 0><<<dim3(29, 32), blk, 0, stream>>>(XU, Wbf + WOFF_L1, l1_b, H1u, nullv, NTOK);
    k_mgemm<1024, 2048, 256, MODE_NORMAL, 1, 1, 0, 1><<<4 * 64, blk, 0, stream>>>(H1u, Wbf + WOFF_L2, l2_b, Yu, Y2u, NTOK);
    k_res_ln<<<NTOK / 4, blk, 0, stream>>>(Yu, Y2u, X, ln3_g, ln3_b, X, XU);

    // ---- sa3 ----
    k_mgemm<256, 256, 768, MODE_QKV, 1, 1, 0, 0><<<dim3(29, 12), blk, 0, stream>>>(XU, Wbf + WOFF_SA3IN, sa3_in_b, QKVu, nullv, NTOK);
    k_attn3<<<32 * NQC3, blk, 0, stream>>>(QKVu, QKVu + 921600, QKVu + 1843200, Ou);
    k_mgemm<256, 256, 256, MODE_NORMAL, 1, 1, 0, 0><<<gTok, blk, 0, stream>>>(Ou, Wbf + WOFF_SA3OUT, sa3_out_b, T1u, nullv, NTOK);
    k_res_ln<<<NTOK / 4, blk, 0, stream>>>(T1u, nullptr, X, ln5_g, ln5_b, X, XU);

    // ---- ffn3 ----
    k_mgemm<256, 256, 2048, MODE_RELU, 1, 1, 0, 0><<<dim3(29, 32), blk, 0, stream>>>(XU, Wbf + WOFF_L31, l31_b, H1u, nullv, NTOK);
    k_mgemm<1024, 2048, 256, MODE_NORMAL, 1, 1, 0, 1><<<4 * 64, blk, 0, stream>>>(H1u, Wbf + WOFF_L32, l32_b, Yu, Y2u, NTOK);
    k_res_ln<<<NTOK / 4, blk, 0, stream>>>(Yu, Y2u, X, ln33_g, ln33_b, (float*)d_out, nullptr);
}